// Round 15
// baseline (187.203 us; speedup 1.0000x reference)
//
#include <hip/hip_runtime.h>
#include <hip/hip_bf16.h>

typedef __attribute__((ext_vector_type(8))) short bf16x8;
typedef __attribute__((ext_vector_type(4))) float f32x4;
typedef unsigned short u16;

#define DIMC 1024
#define NHEAD 16
#define HDIM 64
#define NB 4
#define NQ 4096
#define NS 512

#define LOG2E 1.44269504f

#if __has_builtin(__builtin_amdgcn_exp2f)
#define EXP2F(x) __builtin_amdgcn_exp2f(x)
#else
#define EXP2F(x) __expf(0.69314718f * (x))
#endif

#if __has_builtin(__builtin_amdgcn_rcpf)
#define RCPF(x) __builtin_amdgcn_rcpf(x)
#else
#define RCPF(x) (1.0f / (x))
#endif

__device__ __forceinline__ u16 f2bf(float f) {
  __hip_bfloat16 h = __float2bfloat16(f);
  return *reinterpret_cast<u16*>(&h);
}

__device__ __forceinline__ unsigned pack_bf2(float a, float b) {
  __hip_bfloat162 h2 = __float22bfloat162_rn(make_float2(a, b));
  return *reinterpret_cast<unsigned*>(&h2);
}

__device__ __forceinline__ void gload_lds16(const void* g, void* s) {
  __builtin_amdgcn_global_load_lds(
      (const __attribute__((address_space(1))) void*)g,
      (__attribute__((address_space(3))) void*)s, 16, 0, 0);
}

// ---------------- fused preprocessing kernel ----------------

__device__ __forceinline__ void cvt_body(const float* __restrict__ in,
                                         u16* __restrict__ out, int base, int nblk,
                                         int n4) {
  const int stride = nblk * 256;
  for (int i = base * 256 + threadIdx.x; i < n4; i += stride) {
    float4 v = *(const float4*)(in + (size_t)i * 4);
    ushort4 o;
    o.x = f2bf(v.x); o.y = f2bf(v.y); o.z = f2bf(v.z); o.w = f2bf(v.w);
    *(ushort4*)(out + (size_t)i * 4) = o;
  }
}

__global__ void prep_kernel(const float* __restrict__ x, const float* __restrict__ ctx,
                            const int* __restrict__ cmask,
                            const float* __restrict__ q_w, const float* __restrict__ kv_w,
                            const float* __restrict__ proj_w,
                            u16* __restrict__ x_bf, u16* __restrict__ ctx_bf,
                            u16* __restrict__ qwT, u16* __restrict__ kvwT,
                            u16* __restrict__ pwT, float* __restrict__ maskf) {
  __shared__ float t[32][33];
  const int bid = blockIdx.x;
  if (bid < 2048) {
    cvt_body(x, x_bf, bid, 2048, 16777216 / 4);
    return;
  }
  if (bid < 2560) {
    cvt_body(ctx, ctx_bf, bid - 2048, 512, 2097152 / 4);
    return;
  }
  if (bid >= 6656) {
    const int i = (bid - 6656) * 256 + threadIdx.x;
    if (i < NB * NS) maskf[i] = cmask[i] ? -1e30f : 0.0f;
    return;
  }
  // transpose jobs: W [K][N] f32 -> WT [N][K] bf16
  const float* W;
  u16* WT;
  int K, N, local;
  if (bid < 3584) {
    W = q_w; WT = qwT; K = 1024; N = 1024; local = bid - 2560;
  } else if (bid < 5632) {
    W = kv_w; WT = kvwT; K = 1024; N = 2048; local = bid - 3584;
  } else {
    W = proj_w; WT = pwT; K = 1024; N = 1024; local = bid - 5632;
  }
  const int nbx = N >> 5;
  const int bx = (local % nbx) * 32;
  const int by = (local / nbx) * 32;
  const int tx = threadIdx.x & 31, ty = threadIdx.x >> 5;  // ty 0..7
#pragma unroll
  for (int i = 0; i < 32; i += 8)
    t[ty + i][tx] = W[(size_t)(by + ty + i) * N + bx + tx];
  __syncthreads();
#pragma unroll
  for (int i = 0; i < 32; i += 8)
    WT[(size_t)(bx + ty + i) * K + by + tx] = f2bf(t[tx][ty + i]);
}

// ---------------- 128-tile bf16 GEMM (KV scatter only) ----------------

__launch_bounds__(256)
__global__ void gemm_kv(const u16* __restrict__ A, const u16* __restrict__ BT,
                        const float* __restrict__ bias, u16* __restrict__ Kout,
                        u16* __restrict__ VTout, int M, int N, int K) {
  __shared__ __align__(16) u16 As[128 * 32];
  __shared__ __align__(16) u16 Bs[128 * 32];
  const int tid = threadIdx.x;
  const int w = tid >> 6, l = tid & 63;
  const int wr = w >> 1, wc = w & 1;
  const int fr = l & 15, fhi = l >> 4;

  const int nwg = gridDim.x * gridDim.y;
  const int o = blockIdx.y * gridDim.x + blockIdx.x;
  const int tIdx = (o & 7) * (nwg >> 3) + (o >> 3);
  const int m0 = (tIdx / gridDim.x) * 128;
  const int n0 = (tIdx % gridDim.x) * 128;

  const f32x4 fz = {0.f, 0.f, 0.f, 0.f};
  f32x4 acc[4][4];
#pragma unroll
  for (int mt = 0; mt < 4; mt++)
#pragma unroll
    for (int nt = 0; nt < 4; nt++) acc[mt][nt] = fz;

  const int f0 = w * 2048 + l * 16;
  const int f1 = f0 + 1024;
  const int ar0 = f0 >> 6, ac0 = (f0 & 63) >> 1;
  const int ar1 = f1 >> 6, ac1 = (f1 & 63) >> 1;
  const u16* Ag0 = A + (size_t)(m0 + ar0) * K + ac0;
  const u16* Ag1 = A + (size_t)(m0 + ar1) * K + ac1;
  const u16* Bg0 = BT + (size_t)(n0 + ar0) * K + ac0;
  const u16* Bg1 = BT + (size_t)(n0 + ar1) * K + ac1;

  for (int k0 = 0; k0 < K; k0 += 32) {
    gload_lds16(Ag0 + k0, &As[w * 1024]);
    gload_lds16(Ag1 + k0, &As[w * 1024 + 512]);
    gload_lds16(Bg0 + k0, &Bs[w * 1024]);
    gload_lds16(Bg1 + k0, &Bs[w * 1024 + 512]);
    __syncthreads();

    bf16x8 a[4], b[4];
#pragma unroll
    for (int t = 0; t < 4; t++) {
      a[t] = *(const bf16x8*)&As[(wr * 64 + t * 16 + fr) * 32 + fhi * 8];
      b[t] = *(const bf16x8*)&Bs[(wc * 64 + t * 16 + fr) * 32 + fhi * 8];
    }
#pragma unroll
    for (int mt = 0; mt < 4; mt++)
#pragma unroll
      for (int nt = 0; nt < 4; nt++)
        acc[mt][nt] = __builtin_amdgcn_mfma_f32_16x16x32_bf16(a[mt], b[nt], acc[mt][nt], 0, 0, 0);
    __syncthreads();
  }

#pragma unroll
  for (int mt = 0; mt < 4; mt++) {
#pragma unroll
    for (int nt = 0; nt < 4; nt++) {
      const int col = n0 + wc * 64 + nt * 16 + fr;
      const float bv = bias[col];
#pragma unroll
      for (int r = 0; r < 4; r++) {
        const int row = m0 + wr * 64 + mt * 16 + fhi * 4 + r;
        const float v = acc[mt][nt][r] + bv;
        const int b = row >> 9, s = row & 511;
        if (col < 1024) {
          const int h = col >> 6, d = col & 63;
          Kout[(((size_t)(b * 16 + h)) * 512 + s) * 64 + d] = f2bf(v);
        } else {
          const int c2 = col - 1024;
          const int h = c2 >> 6, d = c2 & 63;
          VTout[(((size_t)(b * 16 + h)) * 64 + d) * 512 + s] = f2bf(v);
        }
      }
    }
  }
}

// ---------------- 256-tile 8-phase bf16 GEMM (T2+T3+T5, r8-verified waits) ----
// Drain vmcnt(0) once per K-tile (REQUIRED: each wave reads LDS written by
// OTHER waves' global_load_lds -- per-wave counted vmcnt cannot order that;
// r14's counted variant corrupted results). Latency tweak vs r12: all 8
// next-tile loads issue in phase 0, giving them ~3 phases to land before the
// tile-end drain (same buffers, same barriers, same WAR protection).

template<int MODE>
__launch_bounds__(512, 1)
__global__ void gemm256(const u16* __restrict__ A, const u16* __restrict__ BT,
                        const float* __restrict__ bias, void* __restrict__ C0,
                        int M, int N, int K) {
  __shared__ __align__(16) u16 As[2][16384];
  __shared__ __align__(16) u16 Bs[2][16384];
  const int tid = threadIdx.x;
  const int w = tid >> 6, l = tid & 63;
  const int wm = w >> 2, wn = w & 3;
  const int fr = l & 15, fhi = l >> 4;

  const int nblk = gridDim.x;
  const int nN = N >> 8;
  const int o = blockIdx.x;
  const int tIdx = (o & 7) * (nblk >> 3) + (o >> 3);
  const int m0 = (tIdx / nN) << 8;
  const int n0 = (tIdx % nN) << 8;

  const int rowoff = tid >> 3;
  const int gchunk = (tid & 7) ^ (rowoff & 7);
  const u16* Abase = A + (size_t)(m0 + rowoff) * K + gchunk * 8;
  const u16* Bbase = BT + (size_t)(n0 + rowoff) * K + gchunk * 8;
  const int ldsoff = w * 512;

  const f32x4 fz = {0.f, 0.f, 0.f, 0.f};
  f32x4 acc[2][4][4];
#pragma unroll
  for (int mh = 0; mh < 2; mh++)
#pragma unroll
    for (int m = 0; m < 4; m++)
#pragma unroll
      for (int n = 0; n < 4; n++) acc[mh][m][n] = fz;

  const int KT = K >> 6;

  // prologue: stage tile 0 into buffer 0; full drain (phase 0 reads data
  // staged by all waves).
#pragma unroll
  for (int p = 0; p < 4; ++p) {
    gload_lds16(Abase + (size_t)(p * 64) * K, &As[0][p * 4096 + ldsoff]);
    gload_lds16(Bbase + (size_t)(p * 64) * K, &Bs[0][p * 4096 + ldsoff]);
  }
  asm volatile("s_waitcnt vmcnt(0)" ::: "memory");
  __builtin_amdgcn_s_barrier();

  int nb = 0;
  for (int kt = 0; kt < KT; ++kt) {
    const int knext = (kt + 1) << 6;
    const bool more = (kt + 1) < KT;
#pragma unroll
    for (int p = 0; p < 4; ++p) {
      const int mh = p >> 1, kk = p & 1;
      const int ch = ((kk << 2) | fhi) ^ (fr & 7);
      bf16x8 af[4], bfr[4];
#pragma unroll
      for (int m = 0; m < 4; ++m) {
        const int row = wm * 128 + mh * 64 + m * 16 + fr;
        af[m] = *(const bf16x8*)((const char*)&As[nb][0] + row * 128 + ch * 16);
      }
#pragma unroll
      for (int n = 0; n < 4; ++n) {
        const int row = wn * 64 + n * 16 + fr;
        bfr[n] = *(const bf16x8*)((const char*)&Bs[nb][0] + row * 128 + ch * 16);
      }
      // issue ALL next-tile loads early (phase 0) -> ~3 phases of cover
      // before the tile-end drain. Writes target buf nb^1, protected from
      // WAR by the previous tile's end barrier.
      if (more && p == 0) {
#pragma unroll
        for (int q = 0; q < 4; ++q) {
          gload_lds16(Abase + (size_t)(q * 64) * K + knext, &As[nb ^ 1][q * 4096 + ldsoff]);
          gload_lds16(Bbase + (size_t)(q * 64) * K + knext, &Bs[nb ^ 1][q * 4096 + ldsoff]);
        }
      }
      __builtin_amdgcn_s_barrier();
      asm volatile("s_waitcnt lgkmcnt(0)" ::: "memory");
      __builtin_amdgcn_s_setprio(1);
#pragma unroll
      for (int m = 0; m < 4; ++m)
#pragma unroll
        for (int n = 0; n < 4; ++n)
          acc[mh][m][n] = __builtin_amdgcn_mfma_f32_16x16x32_bf16(af[m], bfr[n], acc[mh][m][n], 0, 0, 0);
      __builtin_amdgcn_s_setprio(0);
      __builtin_amdgcn_s_barrier();
    }
    // all 8 staged loads (all waves) must land before next tile's phase 0
    asm volatile("s_waitcnt vmcnt(0)" ::: "memory");
    __builtin_amdgcn_s_barrier();
    nb ^= 1;
  }

#pragma unroll
  for (int mh = 0; mh < 2; ++mh)
#pragma unroll
    for (int m = 0; m < 4; ++m)
#pragma unroll
      for (int n = 0; n < 4; ++n) {
        const int col = n0 + wn * 64 + n * 16 + fr;
        const float bv = bias[col];
#pragma unroll
        for (int r = 0; r < 4; ++r) {
          const int row = m0 + wm * 128 + mh * 64 + m * 16 + fhi * 4 + r;
          const float v = acc[mh][m][n][r] + bv;
          if (MODE == 0)
            ((u16*)C0)[(size_t)row * N + col] = f2bf(v * 0.125f);
          else
            ((float*)C0)[(size_t)row * N + col] = v;
        }
      }
}

// ---------------- fused attention v12 (verified, 55.9us): K+V LDS-resident ----
// 512 blocks = 64 bh x 8 q-chunks (XCD-grouped), 512 threads (8 waves x 64
// q-rows; wave tile 32 rows x 2 sequential q-tiles). Prologue stages K
// [512][64] AND V^T [64][512] into XOR-swizzled LDS once (one vmcnt(0) +
// one barrier). Main loop: ZERO barriers, ZERO global loads. 160KB LDS.
__launch_bounds__(512, 2)
__global__ void attn_kernel(const u16* __restrict__ Q, const u16* __restrict__ Kb,
                            const u16* __restrict__ VT, const float* __restrict__ maskf,
                            u16* __restrict__ O) {
  __shared__ __align__(16) u16 Ks[512 * 64];  // 64KB swizzled K [512 s][64 d]
  __shared__ __align__(16) u16 Vs[64 * 512];  // 64KB swizzled V^T [64 d][512 s]
  __shared__ __align__(16) u16 Ps[8][2048];   // 32KB, 4KB/wave swizzled P[32][64]
  const int tid = threadIdx.x, w = tid >> 6, l = tid & 63;
  const int fr = l & 15, fhi = l >> 4;

  // XCD-aware decode: 512 blocks, 64/XCD -> 8 contiguous bh per XCD
  const int rid = blockIdx.x;
  const int orig = ((rid & 7) << 6) + (rid >> 3);
  const int bh = orig >> 3, qc = orig & 7;
  const int b = bh >> 4, h = bh & 15;

  const u16* Kg = Kb + (size_t)bh * NS * HDIM;   // [512][64]
  const u16* Vg = VT + (size_t)bh * HDIM * NS;   // [64][512]
  const float* mrow = maskf + b * NS;

  // ---- prologue: stage ALL of K and V^T into swizzled LDS (once) ----
#pragma unroll
  for (int it = 0; it < 8; ++it) {
    const int slot = it * 512 + tid;
    const int r = slot >> 3, c3 = slot & 7;
    const int gc = c3 ^ (r & 7);
    gload_lds16(Kg + (size_t)r * HDIM + gc * 8, &Ks[slot * 8]);
  }
#pragma unroll
  for (int it = 0; it < 8; ++it) {
    const int slot = it * 512 + tid;
    const int r = slot >> 6, c6 = slot & 63;
    const int gc = c6 ^ (r & 7);
    gload_lds16(Vg + (size_t)r * NS + gc * 8, &Vs[slot * 8]);
  }
  asm volatile("s_waitcnt vmcnt(0)" ::: "memory");
  __syncthreads();
  // ---- K,V resident; no barriers, no global loads from here on ----

  u16* Pw = Ps[w];
  const f32x4 fz = {0.f, 0.f, 0.f, 0.f};

#pragma unroll 1
  for (int qt = 0; qt < 2; ++qt) {
    const int rowbase = b * NQ + qc * 512 + w * 64 + qt * 32;

    // Q fragments (B-operand of swapped QK^T)
    bf16x8 qf[2][2];
#pragma unroll
    for (int mt = 0; mt < 2; mt++)
#pragma unroll
      for (int kk = 0; kk < 2; kk++)
        qf[mt][kk] = *(const bf16x8*)&Q[(size_t)(rowbase + mt * 16 + fr) * DIMC +
                                        h * 64 + kk * 32 + fhi * 8];

    float l_run[2] = {0.f, 0.f};
    f32x4 o_acc[2][4];
#pragma unroll
    for (int mt = 0; mt < 2; mt++)
#pragma unroll
      for (int dn = 0; dn < 4; dn++) o_acc[mt][dn] = fz;

#pragma unroll
    for (int t = 0; t < 8; ++t) {
      const int sc = t * 64;

      // S^T = K Q^T : lane holds S^T[s = sc+sn*16+fhi*4+r][q = mt*16+fr]
      f32x4 sacc[2][4];
#pragma unroll
      for (int mt = 0; mt < 2; mt++)
#pragma unroll
        for (int sn = 0; sn < 4; sn++) sacc[mt][sn] = fz;

      __builtin_amdgcn_s_setprio(1);
#pragma unroll
      for (int kk = 0; kk < 2; kk++) {
        bf16x8 kf[4];
#pragma unroll
        for (int sn = 0; sn < 4; sn++) {
          const int row = sc + sn * 16 + fr;
          const int byte = row * 128 + ((((kk << 2) | fhi) ^ (fr & 7)) << 4);
          kf[sn] = *(const bf16x8*)((const char*)&Ks[0] + byte);
        }
#pragma unroll
        for (int sn = 0; sn < 4; sn++)
#pragma unroll
          for (int mt = 0; mt < 2; mt++)
            sacc[mt][sn] = __builtin_amdgcn_mfma_f32_16x16x32_bf16(kf[sn], qf[mt][kk], sacc[mt][sn], 0, 0, 0);
      }
      __builtin_amdgcn_s_setprio(0);

      float4 mv4[4];
#pragma unroll
      for (int sn = 0; sn < 4; sn++)
        mv4[sn] = *(const float4*)&mrow[sc + sn * 16 + fhi * 4];

      // no-max softmax: e = 2^(s*log2e + mask); per-lane partial sums only
#pragma unroll
      for (int mt = 0; mt < 2; mt++) {
        float ls = 0.f;
        const int qrow = mt * 16 + fr;
#pragma unroll
        for (int sn = 0; sn < 4; sn++) {
          const float e0 = EXP2F(fmaf(sacc[mt][sn][0], LOG2E, ((const float*)&mv4[sn])[0]));
          const float e1 = EXP2F(fmaf(sacc[mt][sn][1], LOG2E, ((const float*)&mv4[sn])[1]));
          const float e2 = EXP2F(fmaf(sacc[mt][sn][2], LOG2E, ((const float*)&mv4[sn])[2]));
          const float e3 = EXP2F(fmaf(sacc[mt][sn][3], LOG2E, ((const float*)&mv4[sn])[3]));
          ls += (e0 + e1) + (e2 + e3);
          int byte = qrow * 128 + sn * 32 + fhi * 8;
          byte ^= (qrow & 7) << 4;
          uint2 pk;
          pk.x = pack_bf2(e0, e1);
          pk.y = pack_bf2(e2, e3);
          *(uint2*)((char*)Pw + byte) = pk;
        }
        l_run[mt] += ls;
      }
      asm volatile("s_waitcnt lgkmcnt(0)" ::: "memory");

      // O += P V : P from wave-private swizzled LDS, V from resident swizzled LDS
      __builtin_amdgcn_s_setprio(1);
#pragma unroll
      for (int kk = 0; kk < 2; kk++) {
        bf16x8 vv[4];
#pragma unroll
        for (int dn = 0; dn < 4; dn++) {
          const int row = dn * 16 + fr;
          const int byte = row * 1024 +
              (((sc >> 3) + ((((kk << 2) | fhi) ^ (fr & 7)))) << 4);
          vv[dn] = *(const bf16x8*)((const char*)&Vs[0] + byte);
        }
#pragma unroll
        for (int mt = 0; mt < 2; mt++) {
          int byte = (mt * 16 + fr) * 128 + kk * 64 + fhi * 16;
          byte ^= (fr & 7) << 4;
          const bf16x8 pa = *(const bf16x8*)((char*)Pw + byte);
#pragma unroll
          for (int dn = 0; dn < 4; dn++)
            o_acc[mt][dn] = __builtin_amdgcn_mfma_f32_16x16x32_bf16(pa, vv[dn], o_acc[mt][dn], 0, 0, 0);
        }
      }
      __builtin_amdgcn_s_setprio(0);
    }

    // per-q-tile epilogue: reduce l, normalize, store
#pragma unroll
    for (int mt = 0; mt < 2; mt++) {
      l_run[mt] += __shfl_xor(l_run[mt], 16);
      l_run[mt] += __shfl_xor(l_run[mt], 32);
    }
#pragma unroll
    for (int mt = 0; mt < 2; mt++) {
      float lo[4];
#pragma unroll
      for (int r = 0; r < 4; r++) {
        lo[r] = RCPF(__shfl(l_run[mt], fhi * 4 + r));
      }
#pragma unroll
      for (int dn = 0; dn < 4; dn++)
#pragma unroll
        for (int r = 0; r < 4; r++) {
          const float v = o_acc[mt][dn][r] * lo[r];
          const int row = rowbase + mt * 16 + fhi * 4 + r;
          O[(size_t)row * DIMC + h * 64 + dn * 16 + fr] = f2bf(v);
        }
    }
  }
}

// ---------------- launch ----------------

extern "C" void kernel_launch(void* const* d_in, const int* in_sizes, int n_in,
                              void* d_out, int out_size, void* d_ws, size_t ws_size,
                              hipStream_t stream) {
  const float* x      = (const float*)d_in[0];
  const float* ctx    = (const float*)d_in[1];
  const int*   cmask  = (const int*)d_in[2];
  const float* q_w    = (const float*)d_in[3];
  const float* q_b    = (const float*)d_in[4];
  const float* kv_w   = (const float*)d_in[5];
  const float* kv_b   = (const float*)d_in[6];
  const float* proj_w = (const float*)d_in[7];
  const float* proj_b = (const float*)d_in[8];
  float* out = (float*)d_out;

  char* ws = (char*)d_ws;
  size_t off = 0;
  auto alloc = [&](size_t bytes) {
    void* p = ws + off;
    off += (bytes + 255) & ~(size_t)255;
    return p;
  };
  u16* x_bf   = (u16*)alloc((size_t)16384 * 1024 * 2);
  u16* ctx_bf = (u16*)alloc((size_t)2048 * 1024 * 2);
  u16* qwT    = (u16*)alloc((size_t)1024 * 1024 * 2);
  u16* kvwT   = (u16*)alloc((size_t)2048 * 1024 * 2);
  u16* pwT    = (u16*)alloc((size_t)1024 * 1024 * 2);
  u16* Qb     = (u16*)alloc((size_t)16384 * 1024 * 2);
  u16* Kbuf   = (u16*)alloc((size_t)64 * 512 * 64 * 2);
  u16* VTbuf  = (u16*)alloc((size_t)64 * 64 * 512 * 2);
  u16* Ob     = (u16*)alloc((size_t)16384 * 1024 * 2);
  float* maskf = (float*)alloc((size_t)NB * NS * 4);

  // all preprocessing in one launch
  prep_kernel<<<6664, 256, 0, stream>>>(x, ctx, cmask, q_w, kv_w, proj_w,
                                        x_bf, ctx_bf, qwT, kvwT, pwT, maskf);

  // Q = (x @ q_w + q_b) * 0.125  (bf16 out, attention scale folded) -- 8-phase 256^2
  gemm256<0><<<256, 512, 0, stream>>>(x_bf, qwT, q_b, Qb, 16384, 1024, 1024);
  // KV = ctx @ kv_w + kv_b  (scatter to K / V^T) -- 128^2
  gemm_kv<<<dim3(16, 16), 256, 0, stream>>>(ctx_bf, kvwT, kv_b, Kbuf, VTbuf, 2048, 2048, 1024);
  // attention (K+V LDS-resident, r12 verified structure)
  attn_kernel<<<512, 512, 0, stream>>>(Qb, Kbuf, VTbuf, maskf, Ob);
  // out = O @ proj_w + proj_b (f32) -- 8-phase 256^2, early-issue staging
  gemm256<2><<<256, 512, 0, stream>>>(Ob, pwT, proj_b, out, 16384, 1024, 1024);
}

// Round 16
// 182.935 us; speedup vs baseline: 1.0233x; 1.0233x over previous
//
#include <hip/hip_runtime.h>
#include <hip/hip_bf16.h>

typedef __attribute__((ext_vector_type(8))) short bf16x8;
typedef __attribute__((ext_vector_type(4))) float f32x4;
typedef unsigned short u16;

#define DIMC 1024
#define NHEAD 16
#define HDIM 64
#define NB 4
#define NQ 4096
#define NS 512

#define LOG2E 1.44269504f

#if __has_builtin(__builtin_amdgcn_exp2f)
#define EXP2F(x) __builtin_amdgcn_exp2f(x)
#else
#define EXP2F(x) __expf(0.69314718f * (x))
#endif

#if __has_builtin(__builtin_amdgcn_rcpf)
#define RCPF(x) __builtin_amdgcn_rcpf(x)
#else
#define RCPF(x) (1.0f / (x))
#endif

__device__ __forceinline__ u16 f2bf(float f) {
  __hip_bfloat16 h = __float2bfloat16(f);
  return *reinterpret_cast<u16*>(&h);
}

__device__ __forceinline__ unsigned pack_bf2(float a, float b) {
  __hip_bfloat162 h2 = __float22bfloat162_rn(make_float2(a, b));
  return *reinterpret_cast<unsigned*>(&h2);
}

__device__ __forceinline__ void gload_lds16(const void* g, void* s) {
  __builtin_amdgcn_global_load_lds(
      (const __attribute__((address_space(1))) void*)g,
      (__attribute__((address_space(3))) void*)s, 16, 0, 0);
}

// ---------------- fused preprocessing kernel ----------------

__device__ __forceinline__ void cvt_body(const float* __restrict__ in,
                                         u16* __restrict__ out, int base, int nblk,
                                         int n4) {
  const int stride = nblk * 256;
  for (int i = base * 256 + threadIdx.x; i < n4; i += stride) {
    float4 v = *(const float4*)(in + (size_t)i * 4);
    ushort4 o;
    o.x = f2bf(v.x); o.y = f2bf(v.y); o.z = f2bf(v.z); o.w = f2bf(v.w);
    *(ushort4*)(out + (size_t)i * 4) = o;
  }
}

__global__ void prep_kernel(const float* __restrict__ x, const float* __restrict__ ctx,
                            const int* __restrict__ cmask,
                            const float* __restrict__ q_w, const float* __restrict__ kv_w,
                            const float* __restrict__ proj_w,
                            u16* __restrict__ x_bf, u16* __restrict__ ctx_bf,
                            u16* __restrict__ qwT, u16* __restrict__ kvwT,
                            u16* __restrict__ pwT, float* __restrict__ maskf) {
  __shared__ float t[32][33];
  const int bid = blockIdx.x;
  if (bid < 2048) {
    cvt_body(x, x_bf, bid, 2048, 16777216 / 4);
    return;
  }
  if (bid < 2560) {
    cvt_body(ctx, ctx_bf, bid - 2048, 512, 2097152 / 4);
    return;
  }
  if (bid >= 6656) {
    const int i = (bid - 6656) * 256 + threadIdx.x;
    if (i < NB * NS) maskf[i] = cmask[i] ? -1e30f : 0.0f;
    return;
  }
  // transpose jobs: W [K][N] f32 -> WT [N][K] bf16
  const float* W;
  u16* WT;
  int K, N, local;
  if (bid < 3584) {
    W = q_w; WT = qwT; K = 1024; N = 1024; local = bid - 2560;
  } else if (bid < 5632) {
    W = kv_w; WT = kvwT; K = 1024; N = 2048; local = bid - 3584;
  } else {
    W = proj_w; WT = pwT; K = 1024; N = 1024; local = bid - 5632;
  }
  const int nbx = N >> 5;
  const int bx = (local % nbx) * 32;
  const int by = (local / nbx) * 32;
  const int tx = threadIdx.x & 31, ty = threadIdx.x >> 5;  // ty 0..7
#pragma unroll
  for (int i = 0; i < 32; i += 8)
    t[ty + i][tx] = W[(size_t)(by + ty + i) * N + bx + tx];
  __syncthreads();
#pragma unroll
  for (int i = 0; i < 32; i += 8)
    WT[(size_t)(bx + ty + i) * K + by + tx] = f2bf(t[tx][ty + i]);
}

// ---------------- 128-tile bf16 GEMM (KV scatter only) ----------------

__launch_bounds__(256)
__global__ void gemm_kv(const u16* __restrict__ A, const u16* __restrict__ BT,
                        const float* __restrict__ bias, u16* __restrict__ Kout,
                        u16* __restrict__ VTout, int M, int N, int K) {
  __shared__ __align__(16) u16 As[128 * 32];
  __shared__ __align__(16) u16 Bs[128 * 32];
  const int tid = threadIdx.x;
  const int w = tid >> 6, l = tid & 63;
  const int wr = w >> 1, wc = w & 1;
  const int fr = l & 15, fhi = l >> 4;

  const int nwg = gridDim.x * gridDim.y;
  const int o = blockIdx.y * gridDim.x + blockIdx.x;
  const int tIdx = (o & 7) * (nwg >> 3) + (o >> 3);
  const int m0 = (tIdx / gridDim.x) * 128;
  const int n0 = (tIdx % gridDim.x) * 128;

  const f32x4 fz = {0.f, 0.f, 0.f, 0.f};
  f32x4 acc[4][4];
#pragma unroll
  for (int mt = 0; mt < 4; mt++)
#pragma unroll
    for (int nt = 0; nt < 4; nt++) acc[mt][nt] = fz;

  const int f0 = w * 2048 + l * 16;
  const int f1 = f0 + 1024;
  const int ar0 = f0 >> 6, ac0 = (f0 & 63) >> 1;
  const int ar1 = f1 >> 6, ac1 = (f1 & 63) >> 1;
  const u16* Ag0 = A + (size_t)(m0 + ar0) * K + ac0;
  const u16* Ag1 = A + (size_t)(m0 + ar1) * K + ac1;
  const u16* Bg0 = BT + (size_t)(n0 + ar0) * K + ac0;
  const u16* Bg1 = BT + (size_t)(n0 + ar1) * K + ac1;

  for (int k0 = 0; k0 < K; k0 += 32) {
    gload_lds16(Ag0 + k0, &As[w * 1024]);
    gload_lds16(Ag1 + k0, &As[w * 1024 + 512]);
    gload_lds16(Bg0 + k0, &Bs[w * 1024]);
    gload_lds16(Bg1 + k0, &Bs[w * 1024 + 512]);
    __syncthreads();

    bf16x8 a[4], b[4];
#pragma unroll
    for (int t = 0; t < 4; t++) {
      a[t] = *(const bf16x8*)&As[(wr * 64 + t * 16 + fr) * 32 + fhi * 8];
      b[t] = *(const bf16x8*)&Bs[(wc * 64 + t * 16 + fr) * 32 + fhi * 8];
    }
#pragma unroll
    for (int mt = 0; mt < 4; mt++)
#pragma unroll
      for (int nt = 0; nt < 4; nt++)
        acc[mt][nt] = __builtin_amdgcn_mfma_f32_16x16x32_bf16(a[mt], b[nt], acc[mt][nt], 0, 0, 0);
    __syncthreads();
  }

#pragma unroll
  for (int mt = 0; mt < 4; mt++) {
#pragma unroll
    for (int nt = 0; nt < 4; nt++) {
      const int col = n0 + wc * 64 + nt * 16 + fr;
      const float bv = bias[col];
#pragma unroll
      for (int r = 0; r < 4; r++) {
        const int row = m0 + wr * 64 + mt * 16 + fhi * 4 + r;
        const float v = acc[mt][nt][r] + bv;
        const int b = row >> 9, s = row & 511;
        if (col < 1024) {
          const int h = col >> 6, d = col & 63;
          Kout[(((size_t)(b * 16 + h)) * 512 + s) * 64 + d] = f2bf(v);
        } else {
          const int c2 = col - 1024;
          const int h = c2 >> 6, d = c2 & 63;
          VTout[(((size_t)(b * 16 + h)) * 64 + d) * 512 + s] = f2bf(v);
        }
      }
    }
  }
}

// ---------------- 256-tile 8-phase bf16 GEMM (r12-verified schedule) ----------
// Per-phase staging (2 loads/wave/phase), drain vmcnt(0) once per K-tile
// (REQUIRED: waves read LDS written by other waves' global_load_lds; r14's
// counted variant corrupted results, r15's early-issue burst regressed ~2.5%).

template<int MODE>
__launch_bounds__(512, 1)
__global__ void gemm256(const u16* __restrict__ A, const u16* __restrict__ BT,
                        const float* __restrict__ bias, void* __restrict__ C0,
                        int M, int N, int K) {
  __shared__ __align__(16) u16 As[2][16384];
  __shared__ __align__(16) u16 Bs[2][16384];
  const int tid = threadIdx.x;
  const int w = tid >> 6, l = tid & 63;
  const int wm = w >> 2, wn = w & 3;
  const int fr = l & 15, fhi = l >> 4;

  const int nblk = gridDim.x;
  const int nN = N >> 8;
  const int o = blockIdx.x;
  const int tIdx = (o & 7) * (nblk >> 3) + (o >> 3);
  const int m0 = (tIdx / nN) << 8;
  const int n0 = (tIdx % nN) << 8;

  const int rowoff = tid >> 3;
  const int gchunk = (tid & 7) ^ (rowoff & 7);
  const u16* Abase = A + (size_t)(m0 + rowoff) * K + gchunk * 8;
  const u16* Bbase = BT + (size_t)(n0 + rowoff) * K + gchunk * 8;
  const int ldsoff = w * 512;

  const f32x4 fz = {0.f, 0.f, 0.f, 0.f};
  f32x4 acc[2][4][4];
#pragma unroll
  for (int mh = 0; mh < 2; mh++)
#pragma unroll
    for (int m = 0; m < 4; m++)
#pragma unroll
      for (int n = 0; n < 4; n++) acc[mh][m][n] = fz;

  const int KT = K >> 6;

#pragma unroll
  for (int p = 0; p < 4; ++p) {
    gload_lds16(Abase + (size_t)(p * 64) * K, &As[0][p * 4096 + ldsoff]);
    gload_lds16(Bbase + (size_t)(p * 64) * K, &Bs[0][p * 4096 + ldsoff]);
  }
  asm volatile("s_waitcnt vmcnt(0)" ::: "memory");
  __builtin_amdgcn_s_barrier();

  int nb = 0;
  for (int kt = 0; kt < KT; ++kt) {
    const int knext = (kt + 1) << 6;
    const bool more = (kt + 1) < KT;
#pragma unroll
    for (int p = 0; p < 4; ++p) {
      const int mh = p >> 1, kk = p & 1;
      const int ch = ((kk << 2) | fhi) ^ (fr & 7);
      bf16x8 af[4], bfr[4];
#pragma unroll
      for (int m = 0; m < 4; ++m) {
        const int row = wm * 128 + mh * 64 + m * 16 + fr;
        af[m] = *(const bf16x8*)((const char*)&As[nb][0] + row * 128 + ch * 16);
      }
#pragma unroll
      for (int n = 0; n < 4; ++n) {
        const int row = wn * 64 + n * 16 + fr;
        bfr[n] = *(const bf16x8*)((const char*)&Bs[nb][0] + row * 128 + ch * 16);
      }
      if (more) {
        gload_lds16(Abase + (size_t)(p * 64) * K + knext, &As[nb ^ 1][p * 4096 + ldsoff]);
        gload_lds16(Bbase + (size_t)(p * 64) * K + knext, &Bs[nb ^ 1][p * 4096 + ldsoff]);
      }
      __builtin_amdgcn_s_barrier();
      asm volatile("s_waitcnt lgkmcnt(0)" ::: "memory");
      __builtin_amdgcn_s_setprio(1);
#pragma unroll
      for (int m = 0; m < 4; ++m)
#pragma unroll
        for (int n = 0; n < 4; ++n)
          acc[mh][m][n] = __builtin_amdgcn_mfma_f32_16x16x32_bf16(af[m], bfr[n], acc[mh][m][n], 0, 0, 0);
      __builtin_amdgcn_s_setprio(0);
      __builtin_amdgcn_s_barrier();
    }
    asm volatile("s_waitcnt vmcnt(0)" ::: "memory");
    __builtin_amdgcn_s_barrier();
    nb ^= 1;
  }

#pragma unroll
  for (int mh = 0; mh < 2; ++mh)
#pragma unroll
    for (int m = 0; m < 4; ++m)
#pragma unroll
      for (int n = 0; n < 4; ++n) {
        const int col = n0 + wn * 64 + n * 16 + fr;
        const float bv = bias[col];
#pragma unroll
        for (int r = 0; r < 4; ++r) {
          const int row = m0 + wm * 128 + mh * 64 + m * 16 + fhi * 4 + r;
          const float v = acc[mh][m][n][r] + bv;
          if (MODE == 0)
            ((u16*)C0)[(size_t)row * N + col] = f2bf(v * 0.125f);
          else
            ((float*)C0)[(size_t)row * N + col] = v;
        }
      }
}

// ---------------- fused attention v16: K+V LDS-resident, 1 block/CU, 1 round --
// 256 blocks = 64 bh x 4 q-chunks (XCD-grouped: 8 contiguous bh per XCD),
// 512 threads. One prologue stage per CU instead of two rounds of 512 blocks:
// saves a 128KB stage + pipeline fill/drain + inter-round tail; K/V L2
// re-fetch halves (4x vs 8x). Wave covers 4 qt sub-tiles of 32 q-rows
// (index arithmetic only vs r12's verified 2-qt version; no sync changes).
__launch_bounds__(512, 2)
__global__ void attn_kernel(const u16* __restrict__ Q, const u16* __restrict__ Kb,
                            const u16* __restrict__ VT, const float* __restrict__ maskf,
                            u16* __restrict__ O) {
  __shared__ __align__(16) u16 Ks[512 * 64];  // 64KB swizzled K [512 s][64 d]
  __shared__ __align__(16) u16 Vs[64 * 512];  // 64KB swizzled V^T [64 d][512 s]
  __shared__ __align__(16) u16 Ps[8][2048];   // 32KB, 4KB/wave swizzled P[32][64]
  const int tid = threadIdx.x, w = tid >> 6, l = tid & 63;
  const int fr = l & 15, fhi = l >> 4;

  // XCD-aware decode: 256 blocks, 32/XCD -> 8 contiguous bh per XCD
  const int rid = blockIdx.x;
  const int orig = ((rid & 7) << 5) + (rid >> 3);
  const int bh = orig >> 2, qc = orig & 3;
  const int b = bh >> 4, h = bh & 15;

  const u16* Kg = Kb + (size_t)bh * NS * HDIM;   // [512][64]
  const u16* Vg = VT + (size_t)bh * HDIM * NS;   // [64][512]
  const float* mrow = maskf + b * NS;

  // ---- prologue: stage ALL of K and V^T into swizzled LDS (once) ----
#pragma unroll
  for (int it = 0; it < 8; ++it) {
    const int slot = it * 512 + tid;
    const int r = slot >> 3, c3 = slot & 7;
    const int gc = c3 ^ (r & 7);
    gload_lds16(Kg + (size_t)r * HDIM + gc * 8, &Ks[slot * 8]);
  }
#pragma unroll
  for (int it = 0; it < 8; ++it) {
    const int slot = it * 512 + tid;
    const int r = slot >> 6, c6 = slot & 63;
    const int gc = c6 ^ (r & 7);
    gload_lds16(Vg + (size_t)r * NS + gc * 8, &Vs[slot * 8]);
  }
  asm volatile("s_waitcnt vmcnt(0)" ::: "memory");
  __syncthreads();
  // ---- K,V resident; no barriers, no global loads from here on ----

  u16* Pw = Ps[w];
  const f32x4 fz = {0.f, 0.f, 0.f, 0.f};

#pragma unroll 1
  for (int qt = 0; qt < 4; ++qt) {
    const int rowbase = b * NQ + qc * 1024 + w * 128 + qt * 32;

    // Q fragments (B-operand of swapped QK^T)
    bf16x8 qf[2][2];
#pragma unroll
    for (int mt = 0; mt < 2; mt++)
#pragma unroll
      for (int kk = 0; kk < 2; kk++)
        qf[mt][kk] = *(const bf16x8*)&Q[(size_t)(rowbase + mt * 16 + fr) * DIMC +
                                        h * 64 + kk * 32 + fhi * 8];

    float l_run[2] = {0.f, 0.f};
    f32x4 o_acc[2][4];
#pragma unroll
    for (int mt = 0; mt < 2; mt++)
#pragma unroll
      for (int dn = 0; dn < 4; dn++) o_acc[mt][dn] = fz;

#pragma unroll
    for (int t = 0; t < 8; ++t) {
      const int sc = t * 64;

      // S^T = K Q^T : lane holds S^T[s = sc+sn*16+fhi*4+r][q = mt*16+fr]
      f32x4 sacc[2][4];
#pragma unroll
      for (int mt = 0; mt < 2; mt++)
#pragma unroll
        for (int sn = 0; sn < 4; sn++) sacc[mt][sn] = fz;

      __builtin_amdgcn_s_setprio(1);
#pragma unroll
      for (int kk = 0; kk < 2; kk++) {
        bf16x8 kf[4];
#pragma unroll
        for (int sn = 0; sn < 4; sn++) {
          const int row = sc + sn * 16 + fr;
          const int byte = row * 128 + ((((kk << 2) | fhi) ^ (fr & 7)) << 4);
          kf[sn] = *(const bf16x8*)((const char*)&Ks[0] + byte);
        }
#pragma unroll
        for (int sn = 0; sn < 4; sn++)
#pragma unroll
          for (int mt = 0; mt < 2; mt++)
            sacc[mt][sn] = __builtin_amdgcn_mfma_f32_16x16x32_bf16(kf[sn], qf[mt][kk], sacc[mt][sn], 0, 0, 0);
      }
      __builtin_amdgcn_s_setprio(0);

      float4 mv4[4];
#pragma unroll
      for (int sn = 0; sn < 4; sn++)
        mv4[sn] = *(const float4*)&mrow[sc + sn * 16 + fhi * 4];

      // no-max softmax: e = 2^(s*log2e + mask); per-lane partial sums only
#pragma unroll
      for (int mt = 0; mt < 2; mt++) {
        float ls = 0.f;
        const int qrow = mt * 16 + fr;
#pragma unroll
        for (int sn = 0; sn < 4; sn++) {
          const float e0 = EXP2F(fmaf(sacc[mt][sn][0], LOG2E, ((const float*)&mv4[sn])[0]));
          const float e1 = EXP2F(fmaf(sacc[mt][sn][1], LOG2E, ((const float*)&mv4[sn])[1]));
          const float e2 = EXP2F(fmaf(sacc[mt][sn][2], LOG2E, ((const float*)&mv4[sn])[2]));
          const float e3 = EXP2F(fmaf(sacc[mt][sn][3], LOG2E, ((const float*)&mv4[sn])[3]));
          ls += (e0 + e1) + (e2 + e3);
          int byte = qrow * 128 + sn * 32 + fhi * 8;
          byte ^= (qrow & 7) << 4;
          uint2 pk;
          pk.x = pack_bf2(e0, e1);
          pk.y = pack_bf2(e2, e3);
          *(uint2*)((char*)Pw + byte) = pk;
        }
        l_run[mt] += ls;
      }
      asm volatile("s_waitcnt lgkmcnt(0)" ::: "memory");

      // O += P V : P from wave-private swizzled LDS, V from resident swizzled LDS
      __builtin_amdgcn_s_setprio(1);
#pragma unroll
      for (int kk = 0; kk < 2; kk++) {
        bf16x8 vv[4];
#pragma unroll
        for (int dn = 0; dn < 4; dn++) {
          const int row = dn * 16 + fr;
          const int byte = row * 1024 +
              (((sc >> 3) + ((((kk << 2) | fhi) ^ (fr & 7)))) << 4);
          vv[dn] = *(const bf16x8*)((const char*)&Vs[0] + byte);
        }
#pragma unroll
        for (int mt = 0; mt < 2; mt++) {
          int byte = (mt * 16 + fr) * 128 + kk * 64 + fhi * 16;
          byte ^= (fr & 7) << 4;
          const bf16x8 pa = *(const bf16x8*)((char*)Pw + byte);
#pragma unroll
          for (int dn = 0; dn < 4; dn++)
            o_acc[mt][dn] = __builtin_amdgcn_mfma_f32_16x16x32_bf16(pa, vv[dn], o_acc[mt][dn], 0, 0, 0);
        }
      }
      __builtin_amdgcn_s_setprio(0);
    }

    // per-q-tile epilogue: reduce l, normalize, store
#pragma unroll
    for (int mt = 0; mt < 2; mt++) {
      l_run[mt] += __shfl_xor(l_run[mt], 16);
      l_run[mt] += __shfl_xor(l_run[mt], 32);
    }
#pragma unroll
    for (int mt = 0; mt < 2; mt++) {
      float lo[4];
#pragma unroll
      for (int r = 0; r < 4; r++) {
        lo[r] = RCPF(__shfl(l_run[mt], fhi * 4 + r));
      }
#pragma unroll
      for (int dn = 0; dn < 4; dn++)
#pragma unroll
        for (int r = 0; r < 4; r++) {
          const float v = o_acc[mt][dn][r] * lo[r];
          const int row = rowbase + mt * 16 + fhi * 4 + r;
          O[(size_t)row * DIMC + h * 64 + dn * 16 + fr] = f2bf(v);
        }
    }
  }
}

// ---------------- launch ----------------

extern "C" void kernel_launch(void* const* d_in, const int* in_sizes, int n_in,
                              void* d_out, int out_size, void* d_ws, size_t ws_size,
                              hipStream_t stream) {
  const float* x      = (const float*)d_in[0];
  const float* ctx    = (const float*)d_in[1];
  const int*   cmask  = (const int*)d_in[2];
  const float* q_w    = (const float*)d_in[3];
  const float* q_b    = (const float*)d_in[4];
  const float* kv_w   = (const float*)d_in[5];
  const float* kv_b   = (const float*)d_in[6];
  const float* proj_w = (const float*)d_in[7];
  const float* proj_b = (const float*)d_in[8];
  float* out = (float*)d_out;

  char* ws = (char*)d_ws;
  size_t off = 0;
  auto alloc = [&](size_t bytes) {
    void* p = ws + off;
    off += (bytes + 255) & ~(size_t)255;
    return p;
  };
  u16* x_bf   = (u16*)alloc((size_t)16384 * 1024 * 2);
  u16* ctx_bf = (u16*)alloc((size_t)2048 * 1024 * 2);
  u16* qwT    = (u16*)alloc((size_t)1024 * 1024 * 2);
  u16* kvwT   = (u16*)alloc((size_t)2048 * 1024 * 2);
  u16* pwT    = (u16*)alloc((size_t)1024 * 1024 * 2);
  u16* Qb     = (u16*)alloc((size_t)16384 * 1024 * 2);
  u16* Kbuf   = (u16*)alloc((size_t)64 * 512 * 64 * 2);
  u16* VTbuf  = (u16*)alloc((size_t)64 * 64 * 512 * 2);
  u16* Ob     = (u16*)alloc((size_t)16384 * 1024 * 2);
  float* maskf = (float*)alloc((size_t)NB * NS * 4);

  // all preprocessing in one launch
  prep_kernel<<<6664, 256, 0, stream>>>(x, ctx, cmask, q_w, kv_w, proj_w,
                                        x_bf, ctx_bf, qwT, kvwT, pwT, maskf);

  // Q = (x @ q_w + q_b) * 0.125  (bf16 out, attention scale folded) -- 8-phase 256^2
  gemm256<0><<<256, 512, 0, stream>>>(x_bf, qwT, q_b, Qb, 16384, 1024, 1024);
  // KV = ctx @ kv_w + kv_b  (scatter to K / V^T) -- 128^2
  gemm_kv<<<dim3(16, 16), 256, 0, stream>>>(ctx_bf, kvwT, kv_b, Kbuf, VTbuf, 2048, 2048, 1024);
  // attention (K+V LDS-resident, 256 blocks = 1/CU, single round)
  attn_kernel<<<256, 512, 0, stream>>>(Qb, Kbuf, VTbuf, maskf, Ob);
  // out = O @ proj_w + proj_b (f32) -- 8-phase 256^2
  gemm256<2><<<256, 512, 0, stream>>>(Ob, pwT, proj_b, out, 16384, 1024, 1024);
}

// Round 17
// 178.370 us; speedup vs baseline: 1.0495x; 1.0256x over previous
//
#include <hip/hip_runtime.h>
#include <hip/hip_bf16.h>

typedef __attribute__((ext_vector_type(8))) short bf16x8;
typedef __attribute__((ext_vector_type(4))) float f32x4;
typedef unsigned short u16;

#define DIMC 1024
#define NHEAD 16
#define HDIM 64
#define NB 4
#define NQ 4096
#define NS 512

#define LOG2E 1.44269504f

#if __has_builtin(__builtin_amdgcn_exp2f)
#define EXP2F(x) __builtin_amdgcn_exp2f(x)
#else
#define EXP2F(x) __expf(0.69314718f * (x))
#endif

#if __has_builtin(__builtin_amdgcn_rcpf)
#define RCPF(x) __builtin_amdgcn_rcpf(x)
#else
#define RCPF(x) (1.0f / (x))
#endif

__device__ __forceinline__ u16 f2bf(float f) {
  __hip_bfloat16 h = __float2bfloat16(f);
  return *reinterpret_cast<u16*>(&h);
}

__device__ __forceinline__ unsigned pack_bf2(float a, float b) {
  __hip_bfloat162 h2 = __float22bfloat162_rn(make_float2(a, b));
  return *reinterpret_cast<unsigned*>(&h2);
}

__device__ __forceinline__ void gload_lds16(const void* g, void* s) {
  __builtin_amdgcn_global_load_lds(
      (const __attribute__((address_space(1))) void*)g,
      (__attribute__((address_space(3))) void*)s, 16, 0, 0);
}

// ---------------- fused preprocessing kernel ----------------

__device__ __forceinline__ void cvt_body(const float* __restrict__ in,
                                         u16* __restrict__ out, int base, int nblk,
                                         int n4) {
  const int stride = nblk * 256;
  for (int i = base * 256 + threadIdx.x; i < n4; i += stride) {
    float4 v = *(const float4*)(in + (size_t)i * 4);
    ushort4 o;
    o.x = f2bf(v.x); o.y = f2bf(v.y); o.z = f2bf(v.z); o.w = f2bf(v.w);
    *(ushort4*)(out + (size_t)i * 4) = o;
  }
}

__global__ void prep_kernel(const float* __restrict__ x, const float* __restrict__ ctx,
                            const int* __restrict__ cmask,
                            const float* __restrict__ q_w, const float* __restrict__ kv_w,
                            const float* __restrict__ proj_w,
                            u16* __restrict__ x_bf, u16* __restrict__ ctx_bf,
                            u16* __restrict__ qwT, u16* __restrict__ kvwT,
                            u16* __restrict__ pwT, float* __restrict__ maskf) {
  __shared__ float t[32][33];
  const int bid = blockIdx.x;
  if (bid < 2048) {
    cvt_body(x, x_bf, bid, 2048, 16777216 / 4);
    return;
  }
  if (bid < 2560) {
    cvt_body(ctx, ctx_bf, bid - 2048, 512, 2097152 / 4);
    return;
  }
  if (bid >= 6656) {
    const int i = (bid - 6656) * 256 + threadIdx.x;
    if (i < NB * NS) maskf[i] = cmask[i] ? -1e30f : 0.0f;
    return;
  }
  // transpose jobs: W [K][N] f32 -> WT [N][K] bf16
  const float* W;
  u16* WT;
  int K, N, local;
  if (bid < 3584) {
    W = q_w; WT = qwT; K = 1024; N = 1024; local = bid - 2560;
  } else if (bid < 5632) {
    W = kv_w; WT = kvwT; K = 1024; N = 2048; local = bid - 3584;
  } else {
    W = proj_w; WT = pwT; K = 1024; N = 1024; local = bid - 5632;
  }
  const int nbx = N >> 5;
  const int bx = (local % nbx) * 32;
  const int by = (local / nbx) * 32;
  const int tx = threadIdx.x & 31, ty = threadIdx.x >> 5;  // ty 0..7
#pragma unroll
  for (int i = 0; i < 32; i += 8)
    t[ty + i][tx] = W[(size_t)(by + ty + i) * N + bx + tx];
  __syncthreads();
#pragma unroll
  for (int i = 0; i < 32; i += 8)
    WT[(size_t)(bx + ty + i) * K + by + tx] = f2bf(t[tx][ty + i]);
}

// ---------------- 128-tile bf16 GEMM (KV scatter only) ----------------

__launch_bounds__(256)
__global__ void gemm_kv(const u16* __restrict__ A, const u16* __restrict__ BT,
                        const float* __restrict__ bias, u16* __restrict__ Kout,
                        u16* __restrict__ VTout, int M, int N, int K) {
  __shared__ __align__(16) u16 As[128 * 32];
  __shared__ __align__(16) u16 Bs[128 * 32];
  const int tid = threadIdx.x;
  const int w = tid >> 6, l = tid & 63;
  const int wr = w >> 1, wc = w & 1;
  const int fr = l & 15, fhi = l >> 4;

  const int nwg = gridDim.x * gridDim.y;
  const int o = blockIdx.y * gridDim.x + blockIdx.x;
  const int tIdx = (o & 7) * (nwg >> 3) + (o >> 3);
  const int m0 = (tIdx / gridDim.x) * 128;
  const int n0 = (tIdx % gridDim.x) * 128;

  const f32x4 fz = {0.f, 0.f, 0.f, 0.f};
  f32x4 acc[4][4];
#pragma unroll
  for (int mt = 0; mt < 4; mt++)
#pragma unroll
    for (int nt = 0; nt < 4; nt++) acc[mt][nt] = fz;

  const int f0 = w * 2048 + l * 16;
  const int f1 = f0 + 1024;
  const int ar0 = f0 >> 6, ac0 = (f0 & 63) >> 1;
  const int ar1 = f1 >> 6, ac1 = (f1 & 63) >> 1;
  const u16* Ag0 = A + (size_t)(m0 + ar0) * K + ac0;
  const u16* Ag1 = A + (size_t)(m0 + ar1) * K + ac1;
  const u16* Bg0 = BT + (size_t)(n0 + ar0) * K + ac0;
  const u16* Bg1 = BT + (size_t)(n0 + ar1) * K + ac1;

  for (int k0 = 0; k0 < K; k0 += 32) {
    gload_lds16(Ag0 + k0, &As[w * 1024]);
    gload_lds16(Ag1 + k0, &As[w * 1024 + 512]);
    gload_lds16(Bg0 + k0, &Bs[w * 1024]);
    gload_lds16(Bg1 + k0, &Bs[w * 1024 + 512]);
    __syncthreads();

    bf16x8 a[4], b[4];
#pragma unroll
    for (int t = 0; t < 4; t++) {
      a[t] = *(const bf16x8*)&As[(wr * 64 + t * 16 + fr) * 32 + fhi * 8];
      b[t] = *(const bf16x8*)&Bs[(wc * 64 + t * 16 + fr) * 32 + fhi * 8];
    }
#pragma unroll
    for (int mt = 0; mt < 4; mt++)
#pragma unroll
      for (int nt = 0; nt < 4; nt++)
        acc[mt][nt] = __builtin_amdgcn_mfma_f32_16x16x32_bf16(a[mt], b[nt], acc[mt][nt], 0, 0, 0);
    __syncthreads();
  }

#pragma unroll
  for (int mt = 0; mt < 4; mt++) {
#pragma unroll
    for (int nt = 0; nt < 4; nt++) {
      const int col = n0 + wc * 64 + nt * 16 + fr;
      const float bv = bias[col];
#pragma unroll
      for (int r = 0; r < 4; r++) {
        const int row = m0 + wr * 64 + mt * 16 + fhi * 4 + r;
        const float v = acc[mt][nt][r] + bv;
        const int b = row >> 9, s = row & 511;
        if (col < 1024) {
          const int h = col >> 6, d = col & 63;
          Kout[(((size_t)(b * 16 + h)) * 512 + s) * 64 + d] = f2bf(v);
        } else {
          const int c2 = col - 1024;
          const int h = c2 >> 6, d = c2 & 63;
          VTout[(((size_t)(b * 16 + h)) * 64 + d) * 512 + s] = f2bf(v);
        }
      }
    }
  }
}

// ---------------- 256-tile 8-phase bf16 GEMM (r12-verified schedule) ----------
// Per-phase staging (2 loads/wave/phase), drain vmcnt(0) once per K-tile
// (REQUIRED: waves read LDS written by other waves' global_load_lds; r14's
// counted variant corrupted results, r15's early-issue burst regressed ~2.5%).

template<int MODE>
__launch_bounds__(512, 1)
__global__ void gemm256(const u16* __restrict__ A, const u16* __restrict__ BT,
                        const float* __restrict__ bias, void* __restrict__ C0,
                        int M, int N, int K) {
  __shared__ __align__(16) u16 As[2][16384];
  __shared__ __align__(16) u16 Bs[2][16384];
  const int tid = threadIdx.x;
  const int w = tid >> 6, l = tid & 63;
  const int wm = w >> 2, wn = w & 3;
  const int fr = l & 15, fhi = l >> 4;

  const int nblk = gridDim.x;
  const int nN = N >> 8;
  const int o = blockIdx.x;
  const int tIdx = (o & 7) * (nblk >> 3) + (o >> 3);
  const int m0 = (tIdx / nN) << 8;
  const int n0 = (tIdx % nN) << 8;

  const int rowoff = tid >> 3;
  const int gchunk = (tid & 7) ^ (rowoff & 7);
  const u16* Abase = A + (size_t)(m0 + rowoff) * K + gchunk * 8;
  const u16* Bbase = BT + (size_t)(n0 + rowoff) * K + gchunk * 8;
  const int ldsoff = w * 512;

  const f32x4 fz = {0.f, 0.f, 0.f, 0.f};
  f32x4 acc[2][4][4];
#pragma unroll
  for (int mh = 0; mh < 2; mh++)
#pragma unroll
    for (int m = 0; m < 4; m++)
#pragma unroll
      for (int n = 0; n < 4; n++) acc[mh][m][n] = fz;

  const int KT = K >> 6;

#pragma unroll
  for (int p = 0; p < 4; ++p) {
    gload_lds16(Abase + (size_t)(p * 64) * K, &As[0][p * 4096 + ldsoff]);
    gload_lds16(Bbase + (size_t)(p * 64) * K, &Bs[0][p * 4096 + ldsoff]);
  }
  asm volatile("s_waitcnt vmcnt(0)" ::: "memory");
  __builtin_amdgcn_s_barrier();

  int nb = 0;
  for (int kt = 0; kt < KT; ++kt) {
    const int knext = (kt + 1) << 6;
    const bool more = (kt + 1) < KT;
#pragma unroll
    for (int p = 0; p < 4; ++p) {
      const int mh = p >> 1, kk = p & 1;
      const int ch = ((kk << 2) | fhi) ^ (fr & 7);
      bf16x8 af[4], bfr[4];
#pragma unroll
      for (int m = 0; m < 4; ++m) {
        const int row = wm * 128 + mh * 64 + m * 16 + fr;
        af[m] = *(const bf16x8*)((const char*)&As[nb][0] + row * 128 + ch * 16);
      }
#pragma unroll
      for (int n = 0; n < 4; ++n) {
        const int row = wn * 64 + n * 16 + fr;
        bfr[n] = *(const bf16x8*)((const char*)&Bs[nb][0] + row * 128 + ch * 16);
      }
      if (more) {
        gload_lds16(Abase + (size_t)(p * 64) * K + knext, &As[nb ^ 1][p * 4096 + ldsoff]);
        gload_lds16(Bbase + (size_t)(p * 64) * K + knext, &Bs[nb ^ 1][p * 4096 + ldsoff]);
      }
      __builtin_amdgcn_s_barrier();
      asm volatile("s_waitcnt lgkmcnt(0)" ::: "memory");
      __builtin_amdgcn_s_setprio(1);
#pragma unroll
      for (int m = 0; m < 4; ++m)
#pragma unroll
        for (int n = 0; n < 4; ++n)
          acc[mh][m][n] = __builtin_amdgcn_mfma_f32_16x16x32_bf16(af[m], bfr[n], acc[mh][m][n], 0, 0, 0);
      __builtin_amdgcn_s_setprio(0);
      __builtin_amdgcn_s_barrier();
    }
    asm volatile("s_waitcnt vmcnt(0)" ::: "memory");
    __builtin_amdgcn_s_barrier();
    nb ^= 1;
  }

#pragma unroll
  for (int mh = 0; mh < 2; ++mh)
#pragma unroll
    for (int m = 0; m < 4; ++m)
#pragma unroll
      for (int n = 0; n < 4; ++n) {
        const int col = n0 + wn * 64 + n * 16 + fr;
        const float bv = bias[col];
#pragma unroll
        for (int r = 0; r < 4; ++r) {
          const int row = m0 + wm * 128 + mh * 64 + m * 16 + fhi * 4 + r;
          const float v = acc[mh][m][n][r] + bv;
          if (MODE == 0)
            ((u16*)C0)[(size_t)row * N + col] = f2bf(v * 0.125f);
          else
            ((float*)C0)[(size_t)row * N + col] = v;
        }
      }
}

// ---------------- fused attention v17: K+V LDS-resident + l via ones-MFMA ------
// r16 structure (256 blocks = 1/CU single round, 8 waves, 160KB LDS, barrier-
// free loop) with the softmax denominator computed on the MATRIX pipe:
// an extra MFMA per (kk,mt) with a constant ones B-fragment accumulates
// l[q] = sum_s P[q][s] into lacc[mt] -- replacing the per-lane VALU adder
// tree (32 adds/lane/t) AND landing l in o_acc's exact row layout, which
// deletes all epilogue shuffles. l is summed from the same bf16 P the PV
// consumes (more consistent normalization).
__launch_bounds__(512, 2)
__global__ void attn_kernel(const u16* __restrict__ Q, const u16* __restrict__ Kb,
                            const u16* __restrict__ VT, const float* __restrict__ maskf,
                            u16* __restrict__ O) {
  __shared__ __align__(16) u16 Ks[512 * 64];  // 64KB swizzled K [512 s][64 d]
  __shared__ __align__(16) u16 Vs[64 * 512];  // 64KB swizzled V^T [64 d][512 s]
  __shared__ __align__(16) u16 Ps[8][2048];   // 32KB, 4KB/wave swizzled P[32][64]
  const int tid = threadIdx.x, w = tid >> 6, l = tid & 63;
  const int fr = l & 15, fhi = l >> 4;

  // XCD-aware decode: 256 blocks, 32/XCD -> 8 contiguous bh per XCD
  const int rid = blockIdx.x;
  const int orig = ((rid & 7) << 5) + (rid >> 3);
  const int bh = orig >> 2, qc = orig & 3;
  const int b = bh >> 4, h = bh & 15;

  const u16* Kg = Kb + (size_t)bh * NS * HDIM;   // [512][64]
  const u16* Vg = VT + (size_t)bh * HDIM * NS;   // [64][512]
  const float* mrow = maskf + b * NS;

  // ---- prologue: stage ALL of K and V^T into swizzled LDS (once) ----
#pragma unroll
  for (int it = 0; it < 8; ++it) {
    const int slot = it * 512 + tid;
    const int r = slot >> 3, c3 = slot & 7;
    const int gc = c3 ^ (r & 7);
    gload_lds16(Kg + (size_t)r * HDIM + gc * 8, &Ks[slot * 8]);
  }
#pragma unroll
  for (int it = 0; it < 8; ++it) {
    const int slot = it * 512 + tid;
    const int r = slot >> 6, c6 = slot & 63;
    const int gc = c6 ^ (r & 7);
    gload_lds16(Vg + (size_t)r * NS + gc * 8, &Vs[slot * 8]);
  }
  asm volatile("s_waitcnt vmcnt(0)" ::: "memory");
  __syncthreads();
  // ---- K,V resident; no barriers, no global loads from here on ----

  u16* Pw = Ps[w];
  const f32x4 fz = {0.f, 0.f, 0.f, 0.f};

  // constant ones B-fragment (bf16 1.0 = 0x3F80)
  bf16x8 onesf;
#pragma unroll
  for (int i = 0; i < 8; ++i) onesf[i] = (short)0x3F80;

#pragma unroll 1
  for (int qt = 0; qt < 4; ++qt) {
    const int rowbase = b * NQ + qc * 1024 + w * 128 + qt * 32;

    // Q fragments (B-operand of swapped QK^T)
    bf16x8 qf[2][2];
#pragma unroll
    for (int mt = 0; mt < 2; mt++)
#pragma unroll
      for (int kk = 0; kk < 2; kk++)
        qf[mt][kk] = *(const bf16x8*)&Q[(size_t)(rowbase + mt * 16 + fr) * DIMC +
                                        h * 64 + kk * 32 + fhi * 8];

    f32x4 lacc[2];
    f32x4 o_acc[2][4];
#pragma unroll
    for (int mt = 0; mt < 2; mt++) {
      lacc[mt] = fz;
#pragma unroll
      for (int dn = 0; dn < 4; dn++) o_acc[mt][dn] = fz;
    }

#pragma unroll
    for (int t = 0; t < 8; ++t) {
      const int sc = t * 64;

      // S^T = K Q^T : lane holds S^T[s = sc+sn*16+fhi*4+r][q = mt*16+fr]
      f32x4 sacc[2][4];
#pragma unroll
      for (int mt = 0; mt < 2; mt++)
#pragma unroll
        for (int sn = 0; sn < 4; sn++) sacc[mt][sn] = fz;

      __builtin_amdgcn_s_setprio(1);
#pragma unroll
      for (int kk = 0; kk < 2; kk++) {
        bf16x8 kf[4];
#pragma unroll
        for (int sn = 0; sn < 4; sn++) {
          const int row = sc + sn * 16 + fr;
          const int byte = row * 128 + ((((kk << 2) | fhi) ^ (fr & 7)) << 4);
          kf[sn] = *(const bf16x8*)((const char*)&Ks[0] + byte);
        }
#pragma unroll
        for (int sn = 0; sn < 4; sn++)
#pragma unroll
          for (int mt = 0; mt < 2; mt++)
            sacc[mt][sn] = __builtin_amdgcn_mfma_f32_16x16x32_bf16(kf[sn], qf[mt][kk], sacc[mt][sn], 0, 0, 0);
      }
      __builtin_amdgcn_s_setprio(0);

      float4 mv4[4];
#pragma unroll
      for (int sn = 0; sn < 4; sn++)
        mv4[sn] = *(const float4*)&mrow[sc + sn * 16 + fhi * 4];

      // no-max softmax: e = 2^(s*log2e + mask); pack straight to LDS.
      // (l is NOT summed here -- it comes from the ones-MFMA in PV.)
#pragma unroll
      for (int mt = 0; mt < 2; mt++) {
        const int qrow = mt * 16 + fr;
#pragma unroll
        for (int sn = 0; sn < 4; sn++) {
          const float e0 = EXP2F(fmaf(sacc[mt][sn][0], LOG2E, ((const float*)&mv4[sn])[0]));
          const float e1 = EXP2F(fmaf(sacc[mt][sn][1], LOG2E, ((const float*)&mv4[sn])[1]));
          const float e2 = EXP2F(fmaf(sacc[mt][sn][2], LOG2E, ((const float*)&mv4[sn])[2]));
          const float e3 = EXP2F(fmaf(sacc[mt][sn][3], LOG2E, ((const float*)&mv4[sn])[3]));
          int byte = qrow * 128 + sn * 32 + fhi * 8;
          byte ^= (qrow & 7) << 4;
          uint2 pk;
          pk.x = pack_bf2(e0, e1);
          pk.y = pack_bf2(e2, e3);
          *(uint2*)((char*)Pw + byte) = pk;
        }
      }
      asm volatile("s_waitcnt lgkmcnt(0)" ::: "memory");

      // O += P V ; l += P 1 : P from wave-private swizzled LDS, V from
      // resident swizzled LDS, ones from registers.
      __builtin_amdgcn_s_setprio(1);
#pragma unroll
      for (int kk = 0; kk < 2; kk++) {
        bf16x8 vv[4];
#pragma unroll
        for (int dn = 0; dn < 4; dn++) {
          const int row = dn * 16 + fr;
          const int byte = row * 1024 +
              (((sc >> 3) + ((((kk << 2) | fhi) ^ (fr & 7)))) << 4);
          vv[dn] = *(const bf16x8*)((const char*)&Vs[0] + byte);
        }
#pragma unroll
        for (int mt = 0; mt < 2; mt++) {
          int byte = (mt * 16 + fr) * 128 + kk * 64 + fhi * 16;
          byte ^= (fr & 7) << 4;
          const bf16x8 pa = *(const bf16x8*)((char*)Pw + byte);
#pragma unroll
          for (int dn = 0; dn < 4; dn++)
            o_acc[mt][dn] = __builtin_amdgcn_mfma_f32_16x16x32_bf16(pa, vv[dn], o_acc[mt][dn], 0, 0, 0);
          lacc[mt] = __builtin_amdgcn_mfma_f32_16x16x32_bf16(pa, onesf, lacc[mt], 0, 0, 0);
        }
      }
      __builtin_amdgcn_s_setprio(0);
    }

    // per-q-tile epilogue: lacc[mt][r] already = l for row mt*16+fhi*4+r
    // (same layout as o_acc rows) -- no shuffles needed.
#pragma unroll
    for (int mt = 0; mt < 2; mt++) {
      float lo[4];
#pragma unroll
      for (int r = 0; r < 4; r++) lo[r] = RCPF(lacc[mt][r]);
#pragma unroll
      for (int dn = 0; dn < 4; dn++)
#pragma unroll
        for (int r = 0; r < 4; r++) {
          const float v = o_acc[mt][dn][r] * lo[r];
          const int row = rowbase + mt * 16 + fhi * 4 + r;
          O[(size_t)row * DIMC + h * 64 + dn * 16 + fr] = f2bf(v);
        }
    }
  }
}

// ---------------- launch ----------------

extern "C" void kernel_launch(void* const* d_in, const int* in_sizes, int n_in,
                              void* d_out, int out_size, void* d_ws, size_t ws_size,
                              hipStream_t stream) {
  const float* x      = (const float*)d_in[0];
  const float* ctx    = (const float*)d_in[1];
  const int*   cmask  = (const int*)d_in[2];
  const float* q_w    = (const float*)d_in[3];
  const float* q_b    = (const float*)d_in[4];
  const float* kv_w   = (const float*)d_in[5];
  const float* kv_b   = (const float*)d_in[6];
  const float* proj_w = (const float*)d_in[7];
  const float* proj_b = (const float*)d_in[8];
  float* out = (float*)d_out;

  char* ws = (char*)d_ws;
  size_t off = 0;
  auto alloc = [&](size_t bytes) {
    void* p = ws + off;
    off += (bytes + 255) & ~(size_t)255;
    return p;
  };
  u16* x_bf   = (u16*)alloc((size_t)16384 * 1024 * 2);
  u16* ctx_bf = (u16*)alloc((size_t)2048 * 1024 * 2);
  u16* qwT    = (u16*)alloc((size_t)1024 * 1024 * 2);
  u16* kvwT   = (u16*)alloc((size_t)2048 * 1024 * 2);
  u16* pwT    = (u16*)alloc((size_t)1024 * 1024 * 2);
  u16* Qb     = (u16*)alloc((size_t)16384 * 1024 * 2);
  u16* Kbuf   = (u16*)alloc((size_t)64 * 512 * 64 * 2);
  u16* VTbuf  = (u16*)alloc((size_t)64 * 64 * 512 * 2);
  u16* Ob     = (u16*)alloc((size_t)16384 * 1024 * 2);
  float* maskf = (float*)alloc((size_t)NB * NS * 4);

  // all preprocessing in one launch
  prep_kernel<<<6664, 256, 0, stream>>>(x, ctx, cmask, q_w, kv_w, proj_w,
                                        x_bf, ctx_bf, qwT, kvwT, pwT, maskf);

  // Q = (x @ q_w + q_b) * 0.125  (bf16 out, attention scale folded) -- 8-phase 256^2
  gemm256<0><<<256, 512, 0, stream>>>(x_bf, qwT, q_b, Qb, 16384, 1024, 1024);
  // KV = ctx @ kv_w + kv_b  (scatter to K / V^T) -- 128^2
  gemm_kv<<<dim3(16, 16), 256, 0, stream>>>(ctx_bf, kvwT, kv_b, Kbuf, VTbuf, 2048, 2048, 1024);
  // attention (K+V LDS-resident, l via ones-MFMA)
  attn_kernel<<<256, 512, 0, stream>>>(Qb, Kbuf, VTbuf, maskf, Ob);
  // out = O @ proj_w + proj_b (f32) -- 8-phase 256^2
  gemm256<2><<<256, 512, 0, stream>>>(Ob, pwT, proj_b, out, 16384, 1024, 1024);
}

// Round 18
// 177.162 us; speedup vs baseline: 1.0567x; 1.0068x over previous
//
#include <hip/hip_runtime.h>
#include <hip/hip_bf16.h>

typedef __attribute__((ext_vector_type(8))) short bf16x8;
typedef __attribute__((ext_vector_type(4))) float f32x4;
typedef unsigned short u16;

#define DIMC 1024
#define NHEAD 16
#define HDIM 64
#define NB 4
#define NQ 4096
#define NS 512

#define LOG2E 1.44269504f

#if __has_builtin(__builtin_amdgcn_exp2f)
#define EXP2F(x) __builtin_amdgcn_exp2f(x)
#else
#define EXP2F(x) __expf(0.69314718f * (x))
#endif

#if __has_builtin(__builtin_amdgcn_rcpf)
#define RCPF(x) __builtin_amdgcn_rcpf(x)
#else
#define RCPF(x) (1.0f / (x))
#endif

__device__ __forceinline__ u16 f2bf(float f) {
  __hip_bfloat16 h = __float2bfloat16(f);
  return *reinterpret_cast<u16*>(&h);
}

__device__ __forceinline__ unsigned pack_bf2(float a, float b) {
  __hip_bfloat162 h2 = __float22bfloat162_rn(make_float2(a, b));
  return *reinterpret_cast<unsigned*>(&h2);
}

__device__ __forceinline__ void gload_lds16(const void* g, void* s) {
  __builtin_amdgcn_global_load_lds(
      (const __attribute__((address_space(1))) void*)g,
      (__attribute__((address_space(3))) void*)s, 16, 0, 0);
}

// ---------------- fused preprocessing kernel ----------------

__device__ __forceinline__ void cvt_body(const float* __restrict__ in,
                                         u16* __restrict__ out, int base, int nblk,
                                         int n4) {
  const int stride = nblk * 256;
  for (int i = base * 256 + threadIdx.x; i < n4; i += stride) {
    float4 v = *(const float4*)(in + (size_t)i * 4);
    ushort4 o;
    o.x = f2bf(v.x); o.y = f2bf(v.y); o.z = f2bf(v.z); o.w = f2bf(v.w);
    *(ushort4*)(out + (size_t)i * 4) = o;
  }
}

__global__ void prep_kernel(const float* __restrict__ x, const float* __restrict__ ctx,
                            const int* __restrict__ cmask,
                            const float* __restrict__ q_w, const float* __restrict__ kv_w,
                            const float* __restrict__ proj_w,
                            u16* __restrict__ x_bf, u16* __restrict__ ctx_bf,
                            u16* __restrict__ qwT, u16* __restrict__ kvwT,
                            u16* __restrict__ pwT, float* __restrict__ maskf) {
  __shared__ float t[32][33];
  const int bid = blockIdx.x;
  if (bid < 2048) {
    cvt_body(x, x_bf, bid, 2048, 16777216 / 4);
    return;
  }
  if (bid < 2560) {
    cvt_body(ctx, ctx_bf, bid - 2048, 512, 2097152 / 4);
    return;
  }
  if (bid >= 6656) {
    const int i = (bid - 6656) * 256 + threadIdx.x;
    if (i < NB * NS) maskf[i] = cmask[i] ? -1e30f : 0.0f;
    return;
  }
  // transpose jobs: W [K][N] f32 -> WT [N][K] bf16
  const float* W;
  u16* WT;
  int K, N, local;
  if (bid < 3584) {
    W = q_w; WT = qwT; K = 1024; N = 1024; local = bid - 2560;
  } else if (bid < 5632) {
    W = kv_w; WT = kvwT; K = 1024; N = 2048; local = bid - 3584;
  } else {
    W = proj_w; WT = pwT; K = 1024; N = 1024; local = bid - 5632;
  }
  const int nbx = N >> 5;
  const int bx = (local % nbx) * 32;
  const int by = (local / nbx) * 32;
  const int tx = threadIdx.x & 31, ty = threadIdx.x >> 5;  // ty 0..7
#pragma unroll
  for (int i = 0; i < 32; i += 8)
    t[ty + i][tx] = W[(size_t)(by + ty + i) * N + bx + tx];
  __syncthreads();
#pragma unroll
  for (int i = 0; i < 32; i += 8)
    WT[(size_t)(bx + ty + i) * K + by + tx] = f2bf(t[tx][ty + i]);
}

// ---------------- 128-tile bf16 GEMM (KV scatter only) ----------------

__launch_bounds__(256)
__global__ void gemm_kv(const u16* __restrict__ A, const u16* __restrict__ BT,
                        const float* __restrict__ bias, u16* __restrict__ Kout,
                        u16* __restrict__ VTout, int M, int N, int K) {
  __shared__ __align__(16) u16 As[128 * 32];
  __shared__ __align__(16) u16 Bs[128 * 32];
  const int tid = threadIdx.x;
  const int w = tid >> 6, l = tid & 63;
  const int wr = w >> 1, wc = w & 1;
  const int fr = l & 15, fhi = l >> 4;

  const int nwg = gridDim.x * gridDim.y;
  const int o = blockIdx.y * gridDim.x + blockIdx.x;
  const int tIdx = (o & 7) * (nwg >> 3) + (o >> 3);
  const int m0 = (tIdx / gridDim.x) * 128;
  const int n0 = (tIdx % gridDim.x) * 128;

  const f32x4 fz = {0.f, 0.f, 0.f, 0.f};
  f32x4 acc[4][4];
#pragma unroll
  for (int mt = 0; mt < 4; mt++)
#pragma unroll
    for (int nt = 0; nt < 4; nt++) acc[mt][nt] = fz;

  const int f0 = w * 2048 + l * 16;
  const int f1 = f0 + 1024;
  const int ar0 = f0 >> 6, ac0 = (f0 & 63) >> 1;
  const int ar1 = f1 >> 6, ac1 = (f1 & 63) >> 1;
  const u16* Ag0 = A + (size_t)(m0 + ar0) * K + ac0;
  const u16* Ag1 = A + (size_t)(m0 + ar1) * K + ac1;
  const u16* Bg0 = BT + (size_t)(n0 + ar0) * K + ac0;
  const u16* Bg1 = BT + (size_t)(n0 + ar1) * K + ac1;

  for (int k0 = 0; k0 < K; k0 += 32) {
    gload_lds16(Ag0 + k0, &As[w * 1024]);
    gload_lds16(Ag1 + k0, &As[w * 1024 + 512]);
    gload_lds16(Bg0 + k0, &Bs[w * 1024]);
    gload_lds16(Bg1 + k0, &Bs[w * 1024 + 512]);
    __syncthreads();

    bf16x8 a[4], b[4];
#pragma unroll
    for (int t = 0; t < 4; t++) {
      a[t] = *(const bf16x8*)&As[(wr * 64 + t * 16 + fr) * 32 + fhi * 8];
      b[t] = *(const bf16x8*)&Bs[(wc * 64 + t * 16 + fr) * 32 + fhi * 8];
    }
#pragma unroll
    for (int mt = 0; mt < 4; mt++)
#pragma unroll
      for (int nt = 0; nt < 4; nt++)
        acc[mt][nt] = __builtin_amdgcn_mfma_f32_16x16x32_bf16(a[mt], b[nt], acc[mt][nt], 0, 0, 0);
    __syncthreads();
  }

#pragma unroll
  for (int mt = 0; mt < 4; mt++) {
#pragma unroll
    for (int nt = 0; nt < 4; nt++) {
      const int col = n0 + wc * 64 + nt * 16 + fr;
      const float bv = bias[col];
#pragma unroll
      for (int r = 0; r < 4; r++) {
        const int row = m0 + wr * 64 + mt * 16 + fhi * 4 + r;
        const float v = acc[mt][nt][r] + bv;
        const int b = row >> 9, s = row & 511;
        if (col < 1024) {
          const int h = col >> 6, d = col & 63;
          Kout[(((size_t)(b * 16 + h)) * 512 + s) * 64 + d] = f2bf(v);
        } else {
          const int c2 = col - 1024;
          const int h = c2 >> 6, d = c2 & 63;
          VTout[(((size_t)(b * 16 + h)) * 64 + d) * 512 + s] = f2bf(v);
        }
      }
    }
  }
}

// ---------------- 256-tile 8-phase bf16 GEMM (r12-verified schedule) ----------

template<int MODE>
__launch_bounds__(512, 1)
__global__ void gemm256(const u16* __restrict__ A, const u16* __restrict__ BT,
                        const float* __restrict__ bias, void* __restrict__ C0,
                        int M, int N, int K) {
  __shared__ __align__(16) u16 As[2][16384];
  __shared__ __align__(16) u16 Bs[2][16384];
  const int tid = threadIdx.x;
  const int w = tid >> 6, l = tid & 63;
  const int wm = w >> 2, wn = w & 3;
  const int fr = l & 15, fhi = l >> 4;

  const int nblk = gridDim.x;
  const int nN = N >> 8;
  const int o = blockIdx.x;
  const int tIdx = (o & 7) * (nblk >> 3) + (o >> 3);
  const int m0 = (tIdx / nN) << 8;
  const int n0 = (tIdx % nN) << 8;

  const int rowoff = tid >> 3;
  const int gchunk = (tid & 7) ^ (rowoff & 7);
  const u16* Abase = A + (size_t)(m0 + rowoff) * K + gchunk * 8;
  const u16* Bbase = BT + (size_t)(n0 + rowoff) * K + gchunk * 8;
  const int ldsoff = w * 512;

  const f32x4 fz = {0.f, 0.f, 0.f, 0.f};
  f32x4 acc[2][4][4];
#pragma unroll
  for (int mh = 0; mh < 2; mh++)
#pragma unroll
    for (int m = 0; m < 4; m++)
#pragma unroll
      for (int n = 0; n < 4; n++) acc[mh][m][n] = fz;

  const int KT = K >> 6;

#pragma unroll
  for (int p = 0; p < 4; ++p) {
    gload_lds16(Abase + (size_t)(p * 64) * K, &As[0][p * 4096 + ldsoff]);
    gload_lds16(Bbase + (size_t)(p * 64) * K, &Bs[0][p * 4096 + ldsoff]);
  }
  asm volatile("s_waitcnt vmcnt(0)" ::: "memory");
  __builtin_amdgcn_s_barrier();

  int nb = 0;
  for (int kt = 0; kt < KT; ++kt) {
    const int knext = (kt + 1) << 6;
    const bool more = (kt + 1) < KT;
#pragma unroll
    for (int p = 0; p < 4; ++p) {
      const int mh = p >> 1, kk = p & 1;
      const int ch = ((kk << 2) | fhi) ^ (fr & 7);
      bf16x8 af[4], bfr[4];
#pragma unroll
      for (int m = 0; m < 4; ++m) {
        const int row = wm * 128 + mh * 64 + m * 16 + fr;
        af[m] = *(const bf16x8*)((const char*)&As[nb][0] + row * 128 + ch * 16);
      }
#pragma unroll
      for (int n = 0; n < 4; ++n) {
        const int row = wn * 64 + n * 16 + fr;
        bfr[n] = *(const bf16x8*)((const char*)&Bs[nb][0] + row * 128 + ch * 16);
      }
      if (more) {
        gload_lds16(Abase + (size_t)(p * 64) * K + knext, &As[nb ^ 1][p * 4096 + ldsoff]);
        gload_lds16(Bbase + (size_t)(p * 64) * K + knext, &Bs[nb ^ 1][p * 4096 + ldsoff]);
      }
      __builtin_amdgcn_s_barrier();
      asm volatile("s_waitcnt lgkmcnt(0)" ::: "memory");
      __builtin_amdgcn_s_setprio(1);
#pragma unroll
      for (int m = 0; m < 4; ++m)
#pragma unroll
        for (int n = 0; n < 4; ++n)
          acc[mh][m][n] = __builtin_amdgcn_mfma_f32_16x16x32_bf16(af[m], bfr[n], acc[mh][m][n], 0, 0, 0);
      __builtin_amdgcn_s_setprio(0);
      __builtin_amdgcn_s_barrier();
    }
    asm volatile("s_waitcnt vmcnt(0)" ::: "memory");
    __builtin_amdgcn_s_barrier();
    nb ^= 1;
  }

#pragma unroll
  for (int mh = 0; mh < 2; ++mh)
#pragma unroll
    for (int m = 0; m < 4; ++m)
#pragma unroll
      for (int n = 0; n < 4; ++n) {
        const int col = n0 + wn * 64 + n * 16 + fr;
        const float bv = bias[col];
#pragma unroll
        for (int r = 0; r < 4; ++r) {
          const int row = m0 + wm * 128 + mh * 64 + m * 16 + fhi * 4 + r;
          const float v = acc[mh][m][n][r] + bv;
          if (MODE == 0)
            ((u16*)C0)[(size_t)row * N + col] = f2bf(v * 0.125f);
          else
            ((float*)C0)[(size_t)row * N + col] = v;
        }
      }
}

// ---------------- fused attention v18: dual-chain with SHARED K/V registers ----
// r17 structure (256 blocks = 1/CU, 8 waves, 160KB LDS, barrier-free loop,
// ones-MFMA l) with two 32-row q-chains per t-iteration sharing ONE set of
// kf[2][4] / vv[2][4] register fragments: per t, K and V are each read from
// LDS ONCE and consumed by both chains (QK_A, QK_B / PV_A, PV_B). LDS ops
// per chain-pair-t drop 56 -> 40 (the measured wall: ~30us of 52 is LDS
// issue). P buffer reused A->B (same-wave LDS ops are in-order; the exact
// aliasing r13 verified correct). Register peak ~235 < 256 @ 2 waves/SIMD.
__launch_bounds__(512, 2)
__global__ void attn_kernel(const u16* __restrict__ Q, const u16* __restrict__ Kb,
                            const u16* __restrict__ VT, const float* __restrict__ maskf,
                            u16* __restrict__ O) {
  __shared__ __align__(16) u16 Ks[512 * 64];  // 64KB swizzled K [512 s][64 d]
  __shared__ __align__(16) u16 Vs[64 * 512];  // 64KB swizzled V^T [64 d][512 s]
  __shared__ __align__(16) u16 Ps[8][2048];   // 32KB, 4KB/wave swizzled P[32][64]
  const int tid = threadIdx.x, w = tid >> 6, l = tid & 63;
  const int fr = l & 15, fhi = l >> 4;

  // XCD-aware decode: 256 blocks, 32/XCD -> 8 contiguous bh per XCD
  const int rid = blockIdx.x;
  const int orig = ((rid & 7) << 5) + (rid >> 3);
  const int bh = orig >> 2, qc = orig & 3;
  const int b = bh >> 4, h = bh & 15;

  const u16* Kg = Kb + (size_t)bh * NS * HDIM;   // [512][64]
  const u16* Vg = VT + (size_t)bh * HDIM * NS;   // [64][512]
  const float* mrow = maskf + b * NS;

  // ---- prologue: stage ALL of K and V^T into swizzled LDS (once) ----
#pragma unroll
  for (int it = 0; it < 8; ++it) {
    const int slot = it * 512 + tid;
    const int r = slot >> 3, c3 = slot & 7;
    const int gc = c3 ^ (r & 7);
    gload_lds16(Kg + (size_t)r * HDIM + gc * 8, &Ks[slot * 8]);
  }
#pragma unroll
  for (int it = 0; it < 8; ++it) {
    const int slot = it * 512 + tid;
    const int r = slot >> 6, c6 = slot & 63;
    const int gc = c6 ^ (r & 7);
    gload_lds16(Vg + (size_t)r * NS + gc * 8, &Vs[slot * 8]);
  }
  asm volatile("s_waitcnt vmcnt(0)" ::: "memory");
  __syncthreads();
  // ---- K,V resident; no barriers, no global loads from here on ----

  u16* Pw = Ps[w];
  const f32x4 fz = {0.f, 0.f, 0.f, 0.f};

  // constant ones B-fragment (bf16 1.0 = 0x3F80)
  bf16x8 onesf;
#pragma unroll
  for (int i = 0; i < 8; ++i) onesf[i] = (short)0x3F80;

#pragma unroll 1
  for (int qt2 = 0; qt2 < 2; ++qt2) {
    const int rowbase_a = b * NQ + qc * 1024 + w * 128 + qt2 * 64;
    const int rowbase_b = rowbase_a + 32;

    // Q fragments for both chains (B-operand of swapped QK^T)
    bf16x8 qfa[2][2], qfb[2][2];
#pragma unroll
    for (int mt = 0; mt < 2; mt++)
#pragma unroll
      for (int kk = 0; kk < 2; kk++) {
        qfa[mt][kk] = *(const bf16x8*)&Q[(size_t)(rowbase_a + mt * 16 + fr) * DIMC +
                                         h * 64 + kk * 32 + fhi * 8];
        qfb[mt][kk] = *(const bf16x8*)&Q[(size_t)(rowbase_b + mt * 16 + fr) * DIMC +
                                         h * 64 + kk * 32 + fhi * 8];
      }

    f32x4 lacc_a[2], lacc_b[2];
    f32x4 oa[2][4], ob[2][4];
#pragma unroll
    for (int mt = 0; mt < 2; mt++) {
      lacc_a[mt] = fz; lacc_b[mt] = fz;
#pragma unroll
      for (int dn = 0; dn < 4; dn++) { oa[mt][dn] = fz; ob[mt][dn] = fz; }
    }

#pragma unroll
    for (int t = 0; t < 8; ++t) {
      const int sc = t * 64;

      // ---- K fragments ONCE (8 reads), shared by both chains ----
      bf16x8 kf[2][4];
#pragma unroll
      for (int kk = 0; kk < 2; kk++)
#pragma unroll
        for (int sn = 0; sn < 4; sn++) {
          const int row = sc + sn * 16 + fr;
          const int byte = row * 128 + ((((kk << 2) | fhi) ^ (fr & 7)) << 4);
          kf[kk][sn] = *(const bf16x8*)((const char*)&Ks[0] + byte);
        }

      // ---- QK chain A ----
      f32x4 sa[2][4];
#pragma unroll
      for (int mt = 0; mt < 2; mt++)
#pragma unroll
        for (int sn = 0; sn < 4; sn++) sa[mt][sn] = fz;
      __builtin_amdgcn_s_setprio(1);
#pragma unroll
      for (int kk = 0; kk < 2; kk++)
#pragma unroll
        for (int sn = 0; sn < 4; sn++)
#pragma unroll
          for (int mt = 0; mt < 2; mt++)
            sa[mt][sn] = __builtin_amdgcn_mfma_f32_16x16x32_bf16(kf[kk][sn], qfa[mt][kk], sa[mt][sn], 0, 0, 0);
      __builtin_amdgcn_s_setprio(0);

      float4 mv4[4];
#pragma unroll
      for (int sn = 0; sn < 4; sn++)
        mv4[sn] = *(const float4*)&mrow[sc + sn * 16 + fhi * 4];

      // ---- SM_A + Pwrite_A ----
#pragma unroll
      for (int mt = 0; mt < 2; mt++) {
        const int qrow = mt * 16 + fr;
#pragma unroll
        for (int sn = 0; sn < 4; sn++) {
          const float e0 = EXP2F(fmaf(sa[mt][sn][0], LOG2E, ((const float*)&mv4[sn])[0]));
          const float e1 = EXP2F(fmaf(sa[mt][sn][1], LOG2E, ((const float*)&mv4[sn])[1]));
          const float e2 = EXP2F(fmaf(sa[mt][sn][2], LOG2E, ((const float*)&mv4[sn])[2]));
          const float e3 = EXP2F(fmaf(sa[mt][sn][3], LOG2E, ((const float*)&mv4[sn])[3]));
          int byte = qrow * 128 + sn * 32 + fhi * 8;
          byte ^= (qrow & 7) << 4;
          uint2 pk;
          pk.x = pack_bf2(e0, e1);
          pk.y = pack_bf2(e2, e3);
          *(uint2*)((char*)Pw + byte) = pk;
        }
      }
      asm volatile("s_waitcnt lgkmcnt(0)" ::: "memory");

      // ---- V fragments ONCE (8 reads), shared by both chains ----
      bf16x8 vv[2][4];
#pragma unroll
      for (int kk = 0; kk < 2; kk++)
#pragma unroll
        for (int dn = 0; dn < 4; dn++) {
          const int row = dn * 16 + fr;
          const int byte = row * 1024 +
              (((sc >> 3) + ((((kk << 2) | fhi) ^ (fr & 7)))) << 4);
          vv[kk][dn] = *(const bf16x8*)((const char*)&Vs[0] + byte);
        }

      // ---- PV_A + ones ----
      __builtin_amdgcn_s_setprio(1);
#pragma unroll
      for (int kk = 0; kk < 2; kk++)
#pragma unroll
        for (int mt = 0; mt < 2; mt++) {
          int byte = (mt * 16 + fr) * 128 + kk * 64 + fhi * 16;
          byte ^= (fr & 7) << 4;
          const bf16x8 pa = *(const bf16x8*)((char*)Pw + byte);
#pragma unroll
          for (int dn = 0; dn < 4; dn++)
            oa[mt][dn] = __builtin_amdgcn_mfma_f32_16x16x32_bf16(pa, vv[kk][dn], oa[mt][dn], 0, 0, 0);
          lacc_a[mt] = __builtin_amdgcn_mfma_f32_16x16x32_bf16(pa, onesf, lacc_a[mt], 0, 0, 0);
        }
      __builtin_amdgcn_s_setprio(0);

      // ---- QK chain B (kf reused; no LDS reads) ----
      f32x4 sb[2][4];
#pragma unroll
      for (int mt = 0; mt < 2; mt++)
#pragma unroll
        for (int sn = 0; sn < 4; sn++) sb[mt][sn] = fz;
      __builtin_amdgcn_s_setprio(1);
#pragma unroll
      for (int kk = 0; kk < 2; kk++)
#pragma unroll
        for (int sn = 0; sn < 4; sn++)
#pragma unroll
          for (int mt = 0; mt < 2; mt++)
            sb[mt][sn] = __builtin_amdgcn_mfma_f32_16x16x32_bf16(kf[kk][sn], qfb[mt][kk], sb[mt][sn], 0, 0, 0);
      __builtin_amdgcn_s_setprio(0);

      // ---- SM_B + Pwrite_B (P buffer reuse; same-wave LDS in-order:
      //      PV_A's reads precede these writes) ----
#pragma unroll
      for (int mt = 0; mt < 2; mt++) {
        const int qrow = mt * 16 + fr;
#pragma unroll
        for (int sn = 0; sn < 4; sn++) {
          const float e0 = EXP2F(fmaf(sb[mt][sn][0], LOG2E, ((const float*)&mv4[sn])[0]));
          const float e1 = EXP2F(fmaf(sb[mt][sn][1], LOG2E, ((const float*)&mv4[sn])[1]));
          const float e2 = EXP2F(fmaf(sb[mt][sn][2], LOG2E, ((const float*)&mv4[sn])[2]));
          const float e3 = EXP2F(fmaf(sb[mt][sn][3], LOG2E, ((const float*)&mv4[sn])[3]));
          int byte = qrow * 128 + sn * 32 + fhi * 8;
          byte ^= (qrow & 7) << 4;
          uint2 pk;
          pk.x = pack_bf2(e0, e1);
          pk.y = pack_bf2(e2, e3);
          *(uint2*)((char*)Pw + byte) = pk;
        }
      }
      asm volatile("s_waitcnt lgkmcnt(0)" ::: "memory");

      // ---- PV_B + ones (vv reused; no V LDS reads) ----
      __builtin_amdgcn_s_setprio(1);
#pragma unroll
      for (int kk = 0; kk < 2; kk++)
#pragma unroll
        for (int mt = 0; mt < 2; mt++) {
          int byte = (mt * 16 + fr) * 128 + kk * 64 + fhi * 16;
          byte ^= (fr & 7) << 4;
          const bf16x8 pa = *(const bf16x8*)((char*)Pw + byte);
#pragma unroll
          for (int dn = 0; dn < 4; dn++)
            ob[mt][dn] = __builtin_amdgcn_mfma_f32_16x16x32_bf16(pa, vv[kk][dn], ob[mt][dn], 0, 0, 0);
          lacc_b[mt] = __builtin_amdgcn_mfma_f32_16x16x32_bf16(pa, onesf, lacc_b[mt], 0, 0, 0);
        }
      __builtin_amdgcn_s_setprio(0);
    }

    // ---- epilogues: lacc rows match o_acc rows; no shuffles ----
#pragma unroll
    for (int mt = 0; mt < 2; mt++) {
      float loa[4], lob[4];
#pragma unroll
      for (int r = 0; r < 4; r++) {
        loa[r] = RCPF(lacc_a[mt][r]);
        lob[r] = RCPF(lacc_b[mt][r]);
      }
#pragma unroll
      for (int dn = 0; dn < 4; dn++)
#pragma unroll
        for (int r = 0; r < 4; r++) {
          const int rowa = rowbase_a + mt * 16 + fhi * 4 + r;
          O[(size_t)rowa * DIMC + h * 64 + dn * 16 + fr] = f2bf(oa[mt][dn][r] * loa[r]);
          const int rowb = rowbase_b + mt * 16 + fhi * 4 + r;
          O[(size_t)rowb * DIMC + h * 64 + dn * 16 + fr] = f2bf(ob[mt][dn][r] * lob[r]);
        }
    }
  }
}

// ---------------- launch ----------------

extern "C" void kernel_launch(void* const* d_in, const int* in_sizes, int n_in,
                              void* d_out, int out_size, void* d_ws, size_t ws_size,
                              hipStream_t stream) {
  const float* x      = (const float*)d_in[0];
  const float* ctx    = (const float*)d_in[1];
  const int*   cmask  = (const int*)d_in[2];
  const float* q_w    = (const float*)d_in[3];
  const float* q_b    = (const float*)d_in[4];
  const float* kv_w   = (const float*)d_in[5];
  const float* kv_b   = (const float*)d_in[6];
  const float* proj_w = (const float*)d_in[7];
  const float* proj_b = (const float*)d_in[8];
  float* out = (float*)d_out;

  char* ws = (char*)d_ws;
  size_t off = 0;
  auto alloc = [&](size_t bytes) {
    void* p = ws + off;
    off += (bytes + 255) & ~(size_t)255;
    return p;
  };
  u16* x_bf   = (u16*)alloc((size_t)16384 * 1024 * 2);
  u16* ctx_bf = (u16*)alloc((size_t)2048 * 1024 * 2);
  u16* qwT    = (u16*)alloc((size_t)1024 * 1024 * 2);
  u16* kvwT   = (u16*)alloc((size_t)2048 * 1024 * 2);
  u16* pwT    = (u16*)alloc((size_t)1024 * 1024 * 2);
  u16* Qb     = (u16*)alloc((size_t)16384 * 1024 * 2);
  u16* Kbuf   = (u16*)alloc((size_t)64 * 512 * 64 * 2);
  u16* VTbuf  = (u16*)alloc((size_t)64 * 64 * 512 * 2);
  u16* Ob     = (u16*)alloc((size_t)16384 * 1024 * 2);
  float* maskf = (float*)alloc((size_t)NB * NS * 4);

  // all preprocessing in one launch
  prep_kernel<<<6664, 256, 0, stream>>>(x, ctx, cmask, q_w, kv_w, proj_w,
                                        x_bf, ctx_bf, qwT, kvwT, pwT, maskf);

  // Q = (x @ q_w + q_b) * 0.125  (bf16 out, attention scale folded) -- 8-phase 256^2
  gemm256<0><<<256, 512, 0, stream>>>(x_bf, qwT, q_b, Qb, 16384, 1024, 1024);
  // KV = ctx @ kv_w + kv_b  (scatter to K / V^T) -- 128^2
  gemm_kv<<<dim3(16, 16), 256, 0, stream>>>(ctx_bf, kvwT, kv_b, Kbuf, VTbuf, 2048, 2048, 1024);
  // attention (dual-chain, shared K/V register fragments)
  attn_kernel<<<256, 512, 0, stream>>>(Qb, Kbuf, VTbuf, maskf, Ob);
  // out = O @ proj_w + proj_b (f32) -- 8-phase 256^2
  gemm256<2><<<256, 512, 0, stream>>>(Ob, pwT, proj_b, out, 16384, 1024, 1024);
}

// Round 19
// 174.423 us; speedup vs baseline: 1.0733x; 1.0157x over previous
//
#include <hip/hip_runtime.h>
#include <hip/hip_bf16.h>

typedef __attribute__((ext_vector_type(8))) short bf16x8;
typedef __attribute__((ext_vector_type(4))) float f32x4;
typedef unsigned short u16;

#define DIMC 1024
#define NHEAD 16
#define HDIM 64
#define NB 4
#define NQ 4096
#define NS 512

#define LOG2E 1.44269504f

#if __has_builtin(__builtin_amdgcn_exp2f)
#define EXP2F(x) __builtin_amdgcn_exp2f(x)
#else
#define EXP2F(x) __expf(0.69314718f * (x))
#endif

#if __has_builtin(__builtin_amdgcn_rcpf)
#define RCPF(x) __builtin_amdgcn_rcpf(x)
#else
#define RCPF(x) (1.0f / (x))
#endif

__device__ __forceinline__ u16 f2bf(float f) {
  __hip_bfloat16 h = __float2bfloat16(f);
  return *reinterpret_cast<u16*>(&h);
}

__device__ __forceinline__ unsigned pack_bf2(float a, float b) {
  __hip_bfloat162 h2 = __float22bfloat162_rn(make_float2(a, b));
  return *reinterpret_cast<unsigned*>(&h2);
}

__device__ __forceinline__ void gload_lds16(const void* g, void* s) {
  __builtin_amdgcn_global_load_lds(
      (const __attribute__((address_space(1))) void*)g,
      (__attribute__((address_space(3))) void*)s, 16, 0, 0);
}

// ---------------- fused preprocessing kernel ----------------

__device__ __forceinline__ void cvt_body(const float* __restrict__ in,
                                         u16* __restrict__ out, int base, int nblk,
                                         int n4) {
  const int stride = nblk * 256;
  for (int i = base * 256 + threadIdx.x; i < n4; i += stride) {
    float4 v = *(const float4*)(in + (size_t)i * 4);
    ushort4 o;
    o.x = f2bf(v.x); o.y = f2bf(v.y); o.z = f2bf(v.z); o.w = f2bf(v.w);
    *(ushort4*)(out + (size_t)i * 4) = o;
  }
}

__global__ void prep_kernel(const float* __restrict__ x, const float* __restrict__ ctx,
                            const int* __restrict__ cmask,
                            const float* __restrict__ q_w, const float* __restrict__ kv_w,
                            const float* __restrict__ proj_w,
                            u16* __restrict__ x_bf, u16* __restrict__ ctx_bf,
                            u16* __restrict__ qwT, u16* __restrict__ kvwT,
                            u16* __restrict__ pwT, float* __restrict__ maskf) {
  __shared__ float t[32][33];
  const int bid = blockIdx.x;
  if (bid < 2048) {
    cvt_body(x, x_bf, bid, 2048, 16777216 / 4);
    return;
  }
  if (bid < 2560) {
    cvt_body(ctx, ctx_bf, bid - 2048, 512, 2097152 / 4);
    return;
  }
  if (bid >= 6656) {
    const int i = (bid - 6656) * 256 + threadIdx.x;
    if (i < NB * NS) maskf[i] = cmask[i] ? -1e30f : 0.0f;
    return;
  }
  // transpose jobs: W [K][N] f32 -> WT [N][K] bf16
  const float* W;
  u16* WT;
  int K, N, local;
  if (bid < 3584) {
    W = q_w; WT = qwT; K = 1024; N = 1024; local = bid - 2560;
  } else if (bid < 5632) {
    W = kv_w; WT = kvwT; K = 1024; N = 2048; local = bid - 3584;
  } else {
    W = proj_w; WT = pwT; K = 1024; N = 1024; local = bid - 5632;
  }
  const int nbx = N >> 5;
  const int bx = (local % nbx) * 32;
  const int by = (local / nbx) * 32;
  const int tx = threadIdx.x & 31, ty = threadIdx.x >> 5;  // ty 0..7
#pragma unroll
  for (int i = 0; i < 32; i += 8)
    t[ty + i][tx] = W[(size_t)(by + ty + i) * N + bx + tx];
  __syncthreads();
#pragma unroll
  for (int i = 0; i < 32; i += 8)
    WT[(size_t)(bx + ty + i) * K + by + tx] = f2bf(t[tx][ty + i]);
}

// ---------------- 128-tile bf16 GEMM (KV scatter only) ----------------

__launch_bounds__(256)
__global__ void gemm_kv(const u16* __restrict__ A, const u16* __restrict__ BT,
                        const float* __restrict__ bias, u16* __restrict__ Kout,
                        u16* __restrict__ VTout, int M, int N, int K) {
  __shared__ __align__(16) u16 As[128 * 32];
  __shared__ __align__(16) u16 Bs[128 * 32];
  const int tid = threadIdx.x;
  const int w = tid >> 6, l = tid & 63;
  const int wr = w >> 1, wc = w & 1;
  const int fr = l & 15, fhi = l >> 4;

  const int nwg = gridDim.x * gridDim.y;
  const int o = blockIdx.y * gridDim.x + blockIdx.x;
  const int tIdx = (o & 7) * (nwg >> 3) + (o >> 3);
  const int m0 = (tIdx / gridDim.x) * 128;
  const int n0 = (tIdx % gridDim.x) * 128;

  const f32x4 fz = {0.f, 0.f, 0.f, 0.f};
  f32x4 acc[4][4];
#pragma unroll
  for (int mt = 0; mt < 4; mt++)
#pragma unroll
    for (int nt = 0; nt < 4; nt++) acc[mt][nt] = fz;

  const int f0 = w * 2048 + l * 16;
  const int f1 = f0 + 1024;
  const int ar0 = f0 >> 6, ac0 = (f0 & 63) >> 1;
  const int ar1 = f1 >> 6, ac1 = (f1 & 63) >> 1;
  const u16* Ag0 = A + (size_t)(m0 + ar0) * K + ac0;
  const u16* Ag1 = A + (size_t)(m0 + ar1) * K + ac1;
  const u16* Bg0 = BT + (size_t)(n0 + ar0) * K + ac0;
  const u16* Bg1 = BT + (size_t)(n0 + ar1) * K + ac1;

  for (int k0 = 0; k0 < K; k0 += 32) {
    gload_lds16(Ag0 + k0, &As[w * 1024]);
    gload_lds16(Ag1 + k0, &As[w * 1024 + 512]);
    gload_lds16(Bg0 + k0, &Bs[w * 1024]);
    gload_lds16(Bg1 + k0, &Bs[w * 1024 + 512]);
    __syncthreads();

    bf16x8 a[4], b[4];
#pragma unroll
    for (int t = 0; t < 4; t++) {
      a[t] = *(const bf16x8*)&As[(wr * 64 + t * 16 + fr) * 32 + fhi * 8];
      b[t] = *(const bf16x8*)&Bs[(wc * 64 + t * 16 + fr) * 32 + fhi * 8];
    }
#pragma unroll
    for (int mt = 0; mt < 4; mt++)
#pragma unroll
      for (int nt = 0; nt < 4; nt++)
        acc[mt][nt] = __builtin_amdgcn_mfma_f32_16x16x32_bf16(a[mt], b[nt], acc[mt][nt], 0, 0, 0);
    __syncthreads();
  }

#pragma unroll
  for (int mt = 0; mt < 4; mt++) {
#pragma unroll
    for (int nt = 0; nt < 4; nt++) {
      const int col = n0 + wc * 64 + nt * 16 + fr;
      const float bv = bias[col];
#pragma unroll
      for (int r = 0; r < 4; r++) {
        const int row = m0 + wr * 64 + mt * 16 + fhi * 4 + r;
        const float v = acc[mt][nt][r] + bv;
        const int b = row >> 9, s = row & 511;
        if (col < 1024) {
          const int h = col >> 6, d = col & 63;
          Kout[(((size_t)(b * 16 + h)) * 512 + s) * 64 + d] = f2bf(v);
        } else {
          const int c2 = col - 1024;
          const int h = c2 >> 6, d = c2 & 63;
          VTout[(((size_t)(b * 16 + h)) * 64 + d) * 512 + s] = f2bf(v);
        }
      }
    }
  }
}

// ---------------- 256-tile bf16 GEMM v19: barrier-free tile body ----------
// T3-minimum recipe (guide 5.5): within a K-tile, reads target buf nb
// (stable) and stage-writes target nb^1 (unread until next tile); each
// wave's ds_read->MFMA deps are covered by compiler-inserted counted
// lgkmcnt. WAR on nb across tiles is safe because every wave drains its
// reads before the tile-end barrier. So: ONE vmcnt(0)+s_barrier per K-tile
// (was 9 barriers/tile). Drain (not counted vmcnt) is REQUIRED because the
// phase->staged-pair mapping is wave-dependent (r14 failure analysis).

template<int MODE>
__launch_bounds__(512, 1)
__global__ void gemm256(const u16* __restrict__ A, const u16* __restrict__ BT,
                        const float* __restrict__ bias, void* __restrict__ C0,
                        int M, int N, int K) {
  __shared__ __align__(16) u16 As[2][16384];
  __shared__ __align__(16) u16 Bs[2][16384];
  const int tid = threadIdx.x;
  const int w = tid >> 6, l = tid & 63;
  const int wm = w >> 2, wn = w & 3;
  const int fr = l & 15, fhi = l >> 4;

  const int nblk = gridDim.x;
  const int nN = N >> 8;
  const int o = blockIdx.x;
  const int tIdx = (o & 7) * (nblk >> 3) + (o >> 3);
  const int m0 = (tIdx / nN) << 8;
  const int n0 = (tIdx % nN) << 8;

  const int rowoff = tid >> 3;
  const int gchunk = (tid & 7) ^ (rowoff & 7);
  const u16* Abase = A + (size_t)(m0 + rowoff) * K + gchunk * 8;
  const u16* Bbase = BT + (size_t)(n0 + rowoff) * K + gchunk * 8;
  const int ldsoff = w * 512;

  const f32x4 fz = {0.f, 0.f, 0.f, 0.f};
  f32x4 acc[2][4][4];
#pragma unroll
  for (int mh = 0; mh < 2; mh++)
#pragma unroll
    for (int m = 0; m < 4; m++)
#pragma unroll
      for (int n = 0; n < 4; n++) acc[mh][m][n] = fz;

  const int KT = K >> 6;

#pragma unroll
  for (int p = 0; p < 4; ++p) {
    gload_lds16(Abase + (size_t)(p * 64) * K, &As[0][p * 4096 + ldsoff]);
    gload_lds16(Bbase + (size_t)(p * 64) * K, &Bs[0][p * 4096 + ldsoff]);
  }
  asm volatile("s_waitcnt vmcnt(0)" ::: "memory");
  __builtin_amdgcn_s_barrier();

  int nb = 0;
  for (int kt = 0; kt < KT; ++kt) {
    const int knext = (kt + 1) << 6;
    const bool more = (kt + 1) < KT;
#pragma unroll
    for (int p = 0; p < 4; ++p) {
      const int mh = p >> 1, kk = p & 1;
      const int ch = ((kk << 2) | fhi) ^ (fr & 7);
      bf16x8 af[4], bfr[4];
#pragma unroll
      for (int m = 0; m < 4; ++m) {
        const int row = wm * 128 + mh * 64 + m * 16 + fr;
        af[m] = *(const bf16x8*)((const char*)&As[nb][0] + row * 128 + ch * 16);
      }
#pragma unroll
      for (int n = 0; n < 4; ++n) {
        const int row = wn * 64 + n * 16 + fr;
        bfr[n] = *(const bf16x8*)((const char*)&Bs[nb][0] + row * 128 + ch * 16);
      }
      if (more) {
        gload_lds16(Abase + (size_t)(p * 64) * K + knext, &As[nb ^ 1][p * 4096 + ldsoff]);
        gload_lds16(Bbase + (size_t)(p * 64) * K + knext, &Bs[nb ^ 1][p * 4096 + ldsoff]);
      }
      __builtin_amdgcn_s_setprio(1);
#pragma unroll
      for (int m = 0; m < 4; ++m)
#pragma unroll
        for (int n = 0; n < 4; ++n)
          acc[mh][m][n] = __builtin_amdgcn_mfma_f32_16x16x32_bf16(af[m], bfr[n], acc[mh][m][n], 0, 0, 0);
      __builtin_amdgcn_s_setprio(0);
    }
    // single per-tile sync: all staged loads landed (vmcnt drain; counted
    // waits are invalid here -- phase->pair map is wave-dependent) and all
    // waves done with buffer nb (their ds_reads drained via lgkmcnt deps).
    asm volatile("s_waitcnt vmcnt(0)" ::: "memory");
    __builtin_amdgcn_s_barrier();
    nb ^= 1;
  }

#pragma unroll
  for (int mh = 0; mh < 2; ++mh)
#pragma unroll
    for (int m = 0; m < 4; ++m)
#pragma unroll
      for (int n = 0; n < 4; ++n) {
        const int col = n0 + wn * 64 + n * 16 + fr;
        const float bv = bias[col];
#pragma unroll
        for (int r = 0; r < 4; ++r) {
          const int row = m0 + wm * 128 + mh * 64 + m * 16 + fhi * 4 + r;
          const float v = acc[mh][m][n][r] + bv;
          if (MODE == 0)
            ((u16*)C0)[(size_t)row * N + col] = f2bf(v * 0.125f);
          else
            ((float*)C0)[(size_t)row * N + col] = v;
        }
      }
}

// ---------------- fused attention v18 (verified, 50.3us) ----------------
// dual-chain with shared K/V register fragments; 256 blocks = 1/CU, 8 waves,
// 160KB LDS, barrier-free loop, ones-MFMA l.
__launch_bounds__(512, 2)
__global__ void attn_kernel(const u16* __restrict__ Q, const u16* __restrict__ Kb,
                            const u16* __restrict__ VT, const float* __restrict__ maskf,
                            u16* __restrict__ O) {
  __shared__ __align__(16) u16 Ks[512 * 64];  // 64KB swizzled K [512 s][64 d]
  __shared__ __align__(16) u16 Vs[64 * 512];  // 64KB swizzled V^T [64 d][512 s]
  __shared__ __align__(16) u16 Ps[8][2048];   // 32KB, 4KB/wave swizzled P[32][64]
  const int tid = threadIdx.x, w = tid >> 6, l = tid & 63;
  const int fr = l & 15, fhi = l >> 4;

  // XCD-aware decode: 256 blocks, 32/XCD -> 8 contiguous bh per XCD
  const int rid = blockIdx.x;
  const int orig = ((rid & 7) << 5) + (rid >> 3);
  const int bh = orig >> 2, qc = orig & 3;
  const int b = bh >> 4, h = bh & 15;

  const u16* Kg = Kb + (size_t)bh * NS * HDIM;   // [512][64]
  const u16* Vg = VT + (size_t)bh * HDIM * NS;   // [64][512]
  const float* mrow = maskf + b * NS;

  // ---- prologue: stage ALL of K and V^T into swizzled LDS (once) ----
#pragma unroll
  for (int it = 0; it < 8; ++it) {
    const int slot = it * 512 + tid;
    const int r = slot >> 3, c3 = slot & 7;
    const int gc = c3 ^ (r & 7);
    gload_lds16(Kg + (size_t)r * HDIM + gc * 8, &Ks[slot * 8]);
  }
#pragma unroll
  for (int it = 0; it < 8; ++it) {
    const int slot = it * 512 + tid;
    const int r = slot >> 6, c6 = slot & 63;
    const int gc = c6 ^ (r & 7);
    gload_lds16(Vg + (size_t)r * NS + gc * 8, &Vs[slot * 8]);
  }
  asm volatile("s_waitcnt vmcnt(0)" ::: "memory");
  __syncthreads();
  // ---- K,V resident; no barriers, no global loads from here on ----

  u16* Pw = Ps[w];
  const f32x4 fz = {0.f, 0.f, 0.f, 0.f};

  // constant ones B-fragment (bf16 1.0 = 0x3F80)
  bf16x8 onesf;
#pragma unroll
  for (int i = 0; i < 8; ++i) onesf[i] = (short)0x3F80;

#pragma unroll 1
  for (int qt2 = 0; qt2 < 2; ++qt2) {
    const int rowbase_a = b * NQ + qc * 1024 + w * 128 + qt2 * 64;
    const int rowbase_b = rowbase_a + 32;

    // Q fragments for both chains (B-operand of swapped QK^T)
    bf16x8 qfa[2][2], qfb[2][2];
#pragma unroll
    for (int mt = 0; mt < 2; mt++)
#pragma unroll
      for (int kk = 0; kk < 2; kk++) {
        qfa[mt][kk] = *(const bf16x8*)&Q[(size_t)(rowbase_a + mt * 16 + fr) * DIMC +
                                         h * 64 + kk * 32 + fhi * 8];
        qfb[mt][kk] = *(const bf16x8*)&Q[(size_t)(rowbase_b + mt * 16 + fr) * DIMC +
                                         h * 64 + kk * 32 + fhi * 8];
      }

    f32x4 lacc_a[2], lacc_b[2];
    f32x4 oa[2][4], ob[2][4];
#pragma unroll
    for (int mt = 0; mt < 2; mt++) {
      lacc_a[mt] = fz; lacc_b[mt] = fz;
#pragma unroll
      for (int dn = 0; dn < 4; dn++) { oa[mt][dn] = fz; ob[mt][dn] = fz; }
    }

#pragma unroll
    for (int t = 0; t < 8; ++t) {
      const int sc = t * 64;

      // ---- K fragments ONCE (8 reads), shared by both chains ----
      bf16x8 kf[2][4];
#pragma unroll
      for (int kk = 0; kk < 2; kk++)
#pragma unroll
        for (int sn = 0; sn < 4; sn++) {
          const int row = sc + sn * 16 + fr;
          const int byte = row * 128 + ((((kk << 2) | fhi) ^ (fr & 7)) << 4);
          kf[kk][sn] = *(const bf16x8*)((const char*)&Ks[0] + byte);
        }

      // ---- QK chain A ----
      f32x4 sa[2][4];
#pragma unroll
      for (int mt = 0; mt < 2; mt++)
#pragma unroll
        for (int sn = 0; sn < 4; sn++) sa[mt][sn] = fz;
      __builtin_amdgcn_s_setprio(1);
#pragma unroll
      for (int kk = 0; kk < 2; kk++)
#pragma unroll
        for (int sn = 0; sn < 4; sn++)
#pragma unroll
          for (int mt = 0; mt < 2; mt++)
            sa[mt][sn] = __builtin_amdgcn_mfma_f32_16x16x32_bf16(kf[kk][sn], qfa[mt][kk], sa[mt][sn], 0, 0, 0);
      __builtin_amdgcn_s_setprio(0);

      float4 mv4[4];
#pragma unroll
      for (int sn = 0; sn < 4; sn++)
        mv4[sn] = *(const float4*)&mrow[sc + sn * 16 + fhi * 4];

      // ---- SM_A + Pwrite_A ----
#pragma unroll
      for (int mt = 0; mt < 2; mt++) {
        const int qrow = mt * 16 + fr;
#pragma unroll
        for (int sn = 0; sn < 4; sn++) {
          const float e0 = EXP2F(fmaf(sa[mt][sn][0], LOG2E, ((const float*)&mv4[sn])[0]));
          const float e1 = EXP2F(fmaf(sa[mt][sn][1], LOG2E, ((const float*)&mv4[sn])[1]));
          const float e2 = EXP2F(fmaf(sa[mt][sn][2], LOG2E, ((const float*)&mv4[sn])[2]));
          const float e3 = EXP2F(fmaf(sa[mt][sn][3], LOG2E, ((const float*)&mv4[sn])[3]));
          int byte = qrow * 128 + sn * 32 + fhi * 8;
          byte ^= (qrow & 7) << 4;
          uint2 pk;
          pk.x = pack_bf2(e0, e1);
          pk.y = pack_bf2(e2, e3);
          *(uint2*)((char*)Pw + byte) = pk;
        }
      }
      asm volatile("s_waitcnt lgkmcnt(0)" ::: "memory");

      // ---- V fragments ONCE (8 reads), shared by both chains ----
      bf16x8 vv[2][4];
#pragma unroll
      for (int kk = 0; kk < 2; kk++)
#pragma unroll
        for (int dn = 0; dn < 4; dn++) {
          const int row = dn * 16 + fr;
          const int byte = row * 1024 +
              (((sc >> 3) + ((((kk << 2) | fhi) ^ (fr & 7)))) << 4);
          vv[kk][dn] = *(const bf16x8*)((const char*)&Vs[0] + byte);
        }

      // ---- PV_A + ones ----
      __builtin_amdgcn_s_setprio(1);
#pragma unroll
      for (int kk = 0; kk < 2; kk++)
#pragma unroll
        for (int mt = 0; mt < 2; mt++) {
          int byte = (mt * 16 + fr) * 128 + kk * 64 + fhi * 16;
          byte ^= (fr & 7) << 4;
          const bf16x8 pa = *(const bf16x8*)((char*)Pw + byte);
#pragma unroll
          for (int dn = 0; dn < 4; dn++)
            oa[mt][dn] = __builtin_amdgcn_mfma_f32_16x16x32_bf16(pa, vv[kk][dn], oa[mt][dn], 0, 0, 0);
          lacc_a[mt] = __builtin_amdgcn_mfma_f32_16x16x32_bf16(pa, onesf, lacc_a[mt], 0, 0, 0);
        }
      __builtin_amdgcn_s_setprio(0);

      // ---- QK chain B (kf reused; no LDS reads) ----
      f32x4 sb[2][4];
#pragma unroll
      for (int mt = 0; mt < 2; mt++)
#pragma unroll
        for (int sn = 0; sn < 4; sn++) sb[mt][sn] = fz;
      __builtin_amdgcn_s_setprio(1);
#pragma unroll
      for (int kk = 0; kk < 2; kk++)
#pragma unroll
        for (int sn = 0; sn < 4; sn++)
#pragma unroll
          for (int mt = 0; mt < 2; mt++)
            sb[mt][sn] = __builtin_amdgcn_mfma_f32_16x16x32_bf16(kf[kk][sn], qfb[mt][kk], sb[mt][sn], 0, 0, 0);
      __builtin_amdgcn_s_setprio(0);

      // ---- SM_B + Pwrite_B (P buffer reuse; same-wave LDS in-order) ----
#pragma unroll
      for (int mt = 0; mt < 2; mt++) {
        const int qrow = mt * 16 + fr;
#pragma unroll
        for (int sn = 0; sn < 4; sn++) {
          const float e0 = EXP2F(fmaf(sb[mt][sn][0], LOG2E, ((const float*)&mv4[sn])[0]));
          const float e1 = EXP2F(fmaf(sb[mt][sn][1], LOG2E, ((const float*)&mv4[sn])[1]));
          const float e2 = EXP2F(fmaf(sb[mt][sn][2], LOG2E, ((const float*)&mv4[sn])[2]));
          const float e3 = EXP2F(fmaf(sb[mt][sn][3], LOG2E, ((const float*)&mv4[sn])[3]));
          int byte = qrow * 128 + sn * 32 + fhi * 8;
          byte ^= (qrow & 7) << 4;
          uint2 pk;
          pk.x = pack_bf2(e0, e1);
          pk.y = pack_bf2(e2, e3);
          *(uint2*)((char*)Pw + byte) = pk;
        }
      }
      asm volatile("s_waitcnt lgkmcnt(0)" ::: "memory");

      // ---- PV_B + ones (vv reused; no V LDS reads) ----
      __builtin_amdgcn_s_setprio(1);
#pragma unroll
      for (int kk = 0; kk < 2; kk++)
#pragma unroll
        for (int mt = 0; mt < 2; mt++) {
          int byte = (mt * 16 + fr) * 128 + kk * 64 + fhi * 16;
          byte ^= (fr & 7) << 4;
          const bf16x8 pa = *(const bf16x8*)((char*)Pw + byte);
#pragma unroll
          for (int dn = 0; dn < 4; dn++)
            ob[mt][dn] = __builtin_amdgcn_mfma_f32_16x16x32_bf16(pa, vv[kk][dn], ob[mt][dn], 0, 0, 0);
          lacc_b[mt] = __builtin_amdgcn_mfma_f32_16x16x32_bf16(pa, onesf, lacc_b[mt], 0, 0, 0);
        }
      __builtin_amdgcn_s_setprio(0);
    }

    // ---- epilogues: lacc rows match o_acc rows; no shuffles ----
#pragma unroll
    for (int mt = 0; mt < 2; mt++) {
      float loa[4], lob[4];
#pragma unroll
      for (int r = 0; r < 4; r++) {
        loa[r] = RCPF(lacc_a[mt][r]);
        lob[r] = RCPF(lacc_b[mt][r]);
      }
#pragma unroll
      for (int dn = 0; dn < 4; dn++)
#pragma unroll
        for (int r = 0; r < 4; r++) {
          const int rowa = rowbase_a + mt * 16 + fhi * 4 + r;
          O[(size_t)rowa * DIMC + h * 64 + dn * 16 + fr] = f2bf(oa[mt][dn][r] * loa[r]);
          const int rowb = rowbase_b + mt * 16 + fhi * 4 + r;
          O[(size_t)rowb * DIMC + h * 64 + dn * 16 + fr] = f2bf(ob[mt][dn][r] * lob[r]);
        }
    }
  }
}

// ---------------- launch ----------------

extern "C" void kernel_launch(void* const* d_in, const int* in_sizes, int n_in,
                              void* d_out, int out_size, void* d_ws, size_t ws_size,
                              hipStream_t stream) {
  const float* x      = (const float*)d_in[0];
  const float* ctx    = (const float*)d_in[1];
  const int*   cmask  = (const int*)d_in[2];
  const float* q_w    = (const float*)d_in[3];
  const float* q_b    = (const float*)d_in[4];
  const float* kv_w   = (const float*)d_in[5];
  const float* kv_b   = (const float*)d_in[6];
  const float* proj_w = (const float*)d_in[7];
  const float* proj_b = (const float*)d_in[8];
  float* out = (float*)d_out;

  char* ws = (char*)d_ws;
  size_t off = 0;
  auto alloc = [&](size_t bytes) {
    void* p = ws + off;
    off += (bytes + 255) & ~(size_t)255;
    return p;
  };
  u16* x_bf   = (u16*)alloc((size_t)16384 * 1024 * 2);
  u16* ctx_bf = (u16*)alloc((size_t)2048 * 1024 * 2);
  u16* qwT    = (u16*)alloc((size_t)1024 * 1024 * 2);
  u16* kvwT   = (u16*)alloc((size_t)2048 * 1024 * 2);
  u16* pwT    = (u16*)alloc((size_t)1024 * 1024 * 2);
  u16* Qb     = (u16*)alloc((size_t)16384 * 1024 * 2);
  u16* Kbuf   = (u16*)alloc((size_t)64 * 512 * 64 * 2);
  u16* VTbuf  = (u16*)alloc((size_t)64 * 64 * 512 * 2);
  u16* Ob     = (u16*)alloc((size_t)16384 * 1024 * 2);
  float* maskf = (float*)alloc((size_t)NB * NS * 4);

  // all preprocessing in one launch
  prep_kernel<<<6664, 256, 0, stream>>>(x, ctx, cmask, q_w, kv_w, proj_w,
                                        x_bf, ctx_bf, qwT, kvwT, pwT, maskf);

  // Q = (x @ q_w + q_b) * 0.125  (bf16 out, attention scale folded)
  gemm256<0><<<256, 512, 0, stream>>>(x_bf, qwT, q_b, Qb, 16384, 1024, 1024);
  // KV = ctx @ kv_w + kv_b  (scatter to K / V^T) -- 128^2
  gemm_kv<<<dim3(16, 16), 256, 0, stream>>>(ctx_bf, kvwT, kv_b, Kbuf, VTbuf, 2048, 2048, 1024);
  // attention (dual-chain, shared K/V register fragments)
  attn_kernel<<<256, 512, 0, stream>>>(Qb, Kbuf, VTbuf, maskf, Ob);
  // out = O @ proj_w + proj_b (f32)
  gemm256<2><<<256, 512, 0, stream>>>(Ob, pwT, proj_b, out, 16384, 1024, 1024);
}

// Round 20
// 170.435 us; speedup vs baseline: 1.0984x; 1.0234x over previous
//
#include <hip/hip_runtime.h>
#include <hip/hip_bf16.h>

typedef __attribute__((ext_vector_type(8))) short bf16x8;
typedef __attribute__((ext_vector_type(4))) float f32x4;
typedef unsigned short u16;

#define DIMC 1024
#define NHEAD 16
#define HDIM 64
#define NB 4
#define NQ 4096
#define NS 512

#define LOG2E 1.44269504f

#if __has_builtin(__builtin_amdgcn_exp2f)
#define EXP2F(x) __builtin_amdgcn_exp2f(x)
#else
#define EXP2F(x) __expf(0.69314718f * (x))
#endif

#if __has_builtin(__builtin_amdgcn_rcpf)
#define RCPF(x) __builtin_amdgcn_rcpf(x)
#else
#define RCPF(x) (1.0f / (x))
#endif

__device__ __forceinline__ u16 f2bf(float f) {
  __hip_bfloat16 h = __float2bfloat16(f);
  return *reinterpret_cast<u16*>(&h);
}

__device__ __forceinline__ unsigned pack_bf2(float a, float b) {
  __hip_bfloat162 h2 = __float22bfloat162_rn(make_float2(a, b));
  return *reinterpret_cast<unsigned*>(&h2);
}

__device__ __forceinline__ void gload_lds16(const void* g, void* s) {
  __builtin_amdgcn_global_load_lds(
      (const __attribute__((address_space(1))) void*)g,
      (__attribute__((address_space(3))) void*)s, 16, 0, 0);
}

// ---------------- fused preprocessing kernel ----------------

__device__ __forceinline__ void cvt_body(const float* __restrict__ in,
                                         u16* __restrict__ out, int base, int nblk,
                                         int n4) {
  const int stride = nblk * 256;
  for (int i = base * 256 + threadIdx.x; i < n4; i += stride) {
    float4 v = *(const float4*)(in + (size_t)i * 4);
    ushort4 o;
    o.x = f2bf(v.x); o.y = f2bf(v.y); o.z = f2bf(v.z); o.w = f2bf(v.w);
    *(ushort4*)(out + (size_t)i * 4) = o;
  }
}

__global__ void prep_kernel(const float* __restrict__ x, const float* __restrict__ ctx,
                            const int* __restrict__ cmask,
                            const float* __restrict__ q_w, const float* __restrict__ kv_w,
                            const float* __restrict__ proj_w,
                            u16* __restrict__ x_bf, u16* __restrict__ ctx_bf,
                            u16* __restrict__ qwT, u16* __restrict__ kvwT,
                            u16* __restrict__ pwT, float* __restrict__ maskf) {
  __shared__ float t[32][33];
  const int bid = blockIdx.x;
  if (bid < 2048) {
    cvt_body(x, x_bf, bid, 2048, 16777216 / 4);
    return;
  }
  if (bid < 2560) {
    cvt_body(ctx, ctx_bf, bid - 2048, 512, 2097152 / 4);
    return;
  }
  if (bid >= 6656) {
    const int i = (bid - 6656) * 256 + threadIdx.x;
    if (i < NB * NS) maskf[i] = cmask[i] ? -1e30f : 0.0f;
    return;
  }
  // transpose jobs: W [K][N] f32 -> WT [N][K] bf16
  const float* W;
  u16* WT;
  int K, N, local;
  if (bid < 3584) {
    W = q_w; WT = qwT; K = 1024; N = 1024; local = bid - 2560;
  } else if (bid < 5632) {
    W = kv_w; WT = kvwT; K = 1024; N = 2048; local = bid - 3584;
  } else {
    W = proj_w; WT = pwT; K = 1024; N = 1024; local = bid - 5632;
  }
  const int nbx = N >> 5;
  const int bx = (local % nbx) * 32;
  const int by = (local / nbx) * 32;
  const int tx = threadIdx.x & 31, ty = threadIdx.x >> 5;  // ty 0..7
#pragma unroll
  for (int i = 0; i < 32; i += 8)
    t[ty + i][tx] = W[(size_t)(by + ty + i) * N + bx + tx];
  __syncthreads();
#pragma unroll
  for (int i = 0; i < 32; i += 8)
    WT[(size_t)(bx + ty + i) * K + by + tx] = f2bf(t[tx][ty + i]);
}

// ---------------- 128-tile bf16 GEMM v20 (KV scatter): BK=64, dbuf, 1 bar/step --
// Mini-gemm256: 128B XOR-swizzled LDS rows (conflict-free ds_read_b128, same
// involution), double-buffered, single vmcnt(0)+barrier per K-step (17 vs 64
// barriers), 32 MFMA/step. Staging: pass p covers rows p*32 + (tid>>3),
// linear dest = p*4096 + w*1024 + lane*16 B (wave-uniform + lane*16),
// global chunk (tid&7)^(row&7) -- mirror of the verified gemm256 scheme.

__launch_bounds__(256)
__global__ void gemm_kv(const u16* __restrict__ A, const u16* __restrict__ BT,
                        const float* __restrict__ bias, u16* __restrict__ Kout,
                        u16* __restrict__ VTout, int M, int N, int K) {
  __shared__ __align__(16) u16 As[2][8192];  // 2 x 16KB: [128 rows][64 k]
  __shared__ __align__(16) u16 Bs[2][8192];
  const int tid = threadIdx.x;
  const int w = tid >> 6, l = tid & 63;
  const int wr = w >> 1, wc = w & 1;
  const int fr = l & 15, fhi = l >> 4;

  const int nwg = gridDim.x * gridDim.y;
  const int o = blockIdx.y * gridDim.x + blockIdx.x;
  const int tIdx = (o & 7) * (nwg >> 3) + (o >> 3);
  const int m0 = (tIdx / gridDim.x) * 128;
  const int n0 = (tIdx % gridDim.x) * 128;

  const f32x4 fz = {0.f, 0.f, 0.f, 0.f};
  f32x4 acc[4][4];
#pragma unroll
  for (int mt = 0; mt < 4; mt++)
#pragma unroll
    for (int nt = 0; nt < 4; nt++) acc[mt][nt] = fz;

  // staging addressing
  const int rowoff = tid >> 3;                      // 0..31
  const int gchunk = (tid & 7) ^ (rowoff & 7);      // row&7 == rowoff&7 (p*32 = 0 mod 8)
  const u16* Abase = A + (size_t)(m0 + rowoff) * K + gchunk * 8;
  const u16* Bbase = BT + (size_t)(n0 + rowoff) * K + gchunk * 8;
  const int ldsoff = w * 512;                       // element offset; pass adds p*2048

  const int KT = K >> 6;  // 16 steps

  // prologue: stage tile 0 into buffer 0
#pragma unroll
  for (int p = 0; p < 4; ++p) {
    gload_lds16(Abase + (size_t)(p * 32) * K, &As[0][p * 2048 + ldsoff]);
    gload_lds16(Bbase + (size_t)(p * 32) * K, &Bs[0][p * 2048 + ldsoff]);
  }
  asm volatile("s_waitcnt vmcnt(0)" ::: "memory");
  __builtin_amdgcn_s_barrier();

  int nb = 0;
  for (int kt = 0; kt < KT; ++kt) {
    const int knext = (kt + 1) << 6;
    const bool more = (kt + 1) < KT;
    // stage next tile (no barrier needed before: writes go to nb^1)
    if (more) {
#pragma unroll
      for (int p = 0; p < 4; ++p) {
        gload_lds16(Abase + (size_t)(p * 32) * K + knext, &As[nb ^ 1][p * 2048 + ldsoff]);
        gload_lds16(Bbase + (size_t)(p * 32) * K + knext, &Bs[nb ^ 1][p * 2048 + ldsoff]);
      }
    }
#pragma unroll
    for (int kk = 0; kk < 2; ++kk) {
      const int ch = ((kk << 2) | fhi) ^ (fr & 7);
      bf16x8 a[4], b[4];
#pragma unroll
      for (int t = 0; t < 4; t++) {
        const int ra = wr * 64 + t * 16 + fr;
        a[t] = *(const bf16x8*)((const char*)&As[nb][0] + ra * 128 + ch * 16);
        const int rb = wc * 64 + t * 16 + fr;
        b[t] = *(const bf16x8*)((const char*)&Bs[nb][0] + rb * 128 + ch * 16);
      }
      __builtin_amdgcn_s_setprio(1);
#pragma unroll
      for (int mt = 0; mt < 4; mt++)
#pragma unroll
        for (int nt = 0; nt < 4; nt++)
          acc[mt][nt] = __builtin_amdgcn_mfma_f32_16x16x32_bf16(a[mt], b[nt], acc[mt][nt], 0, 0, 0);
      __builtin_amdgcn_s_setprio(0);
    }
    // single per-step sync: staged loads landed + all waves done with nb
    asm volatile("s_waitcnt vmcnt(0)" ::: "memory");
    __builtin_amdgcn_s_barrier();
    nb ^= 1;
  }

#pragma unroll
  for (int mt = 0; mt < 4; mt++) {
#pragma unroll
    for (int nt = 0; nt < 4; nt++) {
      const int col = n0 + wc * 64 + nt * 16 + fr;
      const float bv = bias[col];
#pragma unroll
      for (int r = 0; r < 4; r++) {
        const int row = m0 + wr * 64 + mt * 16 + fhi * 4 + r;
        const float v = acc[mt][nt][r] + bv;
        const int b = row >> 9, s = row & 511;
        if (col < 1024) {
          const int h = col >> 6, d = col & 63;
          Kout[(((size_t)(b * 16 + h)) * 512 + s) * 64 + d] = f2bf(v);
        } else {
          const int c2 = col - 1024;
          const int h = c2 >> 6, d = c2 & 63;
          VTout[(((size_t)(b * 16 + h)) * 64 + d) * 512 + s] = f2bf(v);
        }
      }
    }
  }
}

// ---------------- 256-tile bf16 GEMM (r19-verified: barrier-free tile body) ----

template<int MODE>
__launch_bounds__(512, 1)
__global__ void gemm256(const u16* __restrict__ A, const u16* __restrict__ BT,
                        const float* __restrict__ bias, void* __restrict__ C0,
                        int M, int N, int K) {
  __shared__ __align__(16) u16 As[2][16384];
  __shared__ __align__(16) u16 Bs[2][16384];
  const int tid = threadIdx.x;
  const int w = tid >> 6, l = tid & 63;
  const int wm = w >> 2, wn = w & 3;
  const int fr = l & 15, fhi = l >> 4;

  const int nblk = gridDim.x;
  const int nN = N >> 8;
  const int o = blockIdx.x;
  const int tIdx = (o & 7) * (nblk >> 3) + (o >> 3);
  const int m0 = (tIdx / nN) << 8;
  const int n0 = (tIdx % nN) << 8;

  const int rowoff = tid >> 3;
  const int gchunk = (tid & 7) ^ (rowoff & 7);
  const u16* Abase = A + (size_t)(m0 + rowoff) * K + gchunk * 8;
  const u16* Bbase = BT + (size_t)(n0 + rowoff) * K + gchunk * 8;
  const int ldsoff = w * 512;

  const f32x4 fz = {0.f, 0.f, 0.f, 0.f};
  f32x4 acc[2][4][4];
#pragma unroll
  for (int mh = 0; mh < 2; mh++)
#pragma unroll
    for (int m = 0; m < 4; m++)
#pragma unroll
      for (int n = 0; n < 4; n++) acc[mh][m][n] = fz;

  const int KT = K >> 6;

#pragma unroll
  for (int p = 0; p < 4; ++p) {
    gload_lds16(Abase + (size_t)(p * 64) * K, &As[0][p * 4096 + ldsoff]);
    gload_lds16(Bbase + (size_t)(p * 64) * K, &Bs[0][p * 4096 + ldsoff]);
  }
  asm volatile("s_waitcnt vmcnt(0)" ::: "memory");
  __builtin_amdgcn_s_barrier();

  int nb = 0;
  for (int kt = 0; kt < KT; ++kt) {
    const int knext = (kt + 1) << 6;
    const bool more = (kt + 1) < KT;
#pragma unroll
    for (int p = 0; p < 4; ++p) {
      const int mh = p >> 1, kk = p & 1;
      const int ch = ((kk << 2) | fhi) ^ (fr & 7);
      bf16x8 af[4], bfr[4];
#pragma unroll
      for (int m = 0; m < 4; ++m) {
        const int row = wm * 128 + mh * 64 + m * 16 + fr;
        af[m] = *(const bf16x8*)((const char*)&As[nb][0] + row * 128 + ch * 16);
      }
#pragma unroll
      for (int n = 0; n < 4; ++n) {
        const int row = wn * 64 + n * 16 + fr;
        bfr[n] = *(const bf16x8*)((const char*)&Bs[nb][0] + row * 128 + ch * 16);
      }
      if (more) {
        gload_lds16(Abase + (size_t)(p * 64) * K + knext, &As[nb ^ 1][p * 4096 + ldsoff]);
        gload_lds16(Bbase + (size_t)(p * 64) * K + knext, &Bs[nb ^ 1][p * 4096 + ldsoff]);
      }
      __builtin_amdgcn_s_setprio(1);
#pragma unroll
      for (int m = 0; m < 4; ++m)
#pragma unroll
        for (int n = 0; n < 4; ++n)
          acc[mh][m][n] = __builtin_amdgcn_mfma_f32_16x16x32_bf16(af[m], bfr[n], acc[mh][m][n], 0, 0, 0);
      __builtin_amdgcn_s_setprio(0);
    }
    asm volatile("s_waitcnt vmcnt(0)" ::: "memory");
    __builtin_amdgcn_s_barrier();
    nb ^= 1;
  }

#pragma unroll
  for (int mh = 0; mh < 2; ++mh)
#pragma unroll
    for (int m = 0; m < 4; ++m)
#pragma unroll
      for (int n = 0; n < 4; ++n) {
        const int col = n0 + wn * 64 + n * 16 + fr;
        const float bv = bias[col];
#pragma unroll
        for (int r = 0; r < 4; ++r) {
          const int row = m0 + wm * 128 + mh * 64 + m * 16 + fhi * 4 + r;
          const float v = acc[mh][m][n][r] + bv;
          if (MODE == 0)
            ((u16*)C0)[(size_t)row * N + col] = f2bf(v * 0.125f);
          else
            ((float*)C0)[(size_t)row * N + col] = v;
        }
      }
}

// ---------------- fused attention v18 (verified, 50.3us) ----------------
__launch_bounds__(512, 2)
__global__ void attn_kernel(const u16* __restrict__ Q, const u16* __restrict__ Kb,
                            const u16* __restrict__ VT, const float* __restrict__ maskf,
                            u16* __restrict__ O) {
  __shared__ __align__(16) u16 Ks[512 * 64];
  __shared__ __align__(16) u16 Vs[64 * 512];
  __shared__ __align__(16) u16 Ps[8][2048];
  const int tid = threadIdx.x, w = tid >> 6, l = tid & 63;
  const int fr = l & 15, fhi = l >> 4;

  const int rid = blockIdx.x;
  const int orig = ((rid & 7) << 5) + (rid >> 3);
  const int bh = orig >> 2, qc = orig & 3;
  const int b = bh >> 4, h = bh & 15;

  const u16* Kg = Kb + (size_t)bh * NS * HDIM;
  const u16* Vg = VT + (size_t)bh * HDIM * NS;
  const float* mrow = maskf + b * NS;

#pragma unroll
  for (int it = 0; it < 8; ++it) {
    const int slot = it * 512 + tid;
    const int r = slot >> 3, c3 = slot & 7;
    const int gc = c3 ^ (r & 7);
    gload_lds16(Kg + (size_t)r * HDIM + gc * 8, &Ks[slot * 8]);
  }
#pragma unroll
  for (int it = 0; it < 8; ++it) {
    const int slot = it * 512 + tid;
    const int r = slot >> 6, c6 = slot & 63;
    const int gc = c6 ^ (r & 7);
    gload_lds16(Vg + (size_t)r * NS + gc * 8, &Vs[slot * 8]);
  }
  asm volatile("s_waitcnt vmcnt(0)" ::: "memory");
  __syncthreads();

  u16* Pw = Ps[w];
  const f32x4 fz = {0.f, 0.f, 0.f, 0.f};

  bf16x8 onesf;
#pragma unroll
  for (int i = 0; i < 8; ++i) onesf[i] = (short)0x3F80;

#pragma unroll 1
  for (int qt2 = 0; qt2 < 2; ++qt2) {
    const int rowbase_a = b * NQ + qc * 1024 + w * 128 + qt2 * 64;
    const int rowbase_b = rowbase_a + 32;

    bf16x8 qfa[2][2], qfb[2][2];
#pragma unroll
    for (int mt = 0; mt < 2; mt++)
#pragma unroll
      for (int kk = 0; kk < 2; kk++) {
        qfa[mt][kk] = *(const bf16x8*)&Q[(size_t)(rowbase_a + mt * 16 + fr) * DIMC +
                                         h * 64 + kk * 32 + fhi * 8];
        qfb[mt][kk] = *(const bf16x8*)&Q[(size_t)(rowbase_b + mt * 16 + fr) * DIMC +
                                         h * 64 + kk * 32 + fhi * 8];
      }

    f32x4 lacc_a[2], lacc_b[2];
    f32x4 oa[2][4], ob[2][4];
#pragma unroll
    for (int mt = 0; mt < 2; mt++) {
      lacc_a[mt] = fz; lacc_b[mt] = fz;
#pragma unroll
      for (int dn = 0; dn < 4; dn++) { oa[mt][dn] = fz; ob[mt][dn] = fz; }
    }

#pragma unroll
    for (int t = 0; t < 8; ++t) {
      const int sc = t * 64;

      bf16x8 kf[2][4];
#pragma unroll
      for (int kk = 0; kk < 2; kk++)
#pragma unroll
        for (int sn = 0; sn < 4; sn++) {
          const int row = sc + sn * 16 + fr;
          const int byte = row * 128 + ((((kk << 2) | fhi) ^ (fr & 7)) << 4);
          kf[kk][sn] = *(const bf16x8*)((const char*)&Ks[0] + byte);
        }

      f32x4 sa[2][4];
#pragma unroll
      for (int mt = 0; mt < 2; mt++)
#pragma unroll
        for (int sn = 0; sn < 4; sn++) sa[mt][sn] = fz;
      __builtin_amdgcn_s_setprio(1);
#pragma unroll
      for (int kk = 0; kk < 2; kk++)
#pragma unroll
        for (int sn = 0; sn < 4; sn++)
#pragma unroll
          for (int mt = 0; mt < 2; mt++)
            sa[mt][sn] = __builtin_amdgcn_mfma_f32_16x16x32_bf16(kf[kk][sn], qfa[mt][kk], sa[mt][sn], 0, 0, 0);
      __builtin_amdgcn_s_setprio(0);

      float4 mv4[4];
#pragma unroll
      for (int sn = 0; sn < 4; sn++)
        mv4[sn] = *(const float4*)&mrow[sc + sn * 16 + fhi * 4];

#pragma unroll
      for (int mt = 0; mt < 2; mt++) {
        const int qrow = mt * 16 + fr;
#pragma unroll
        for (int sn = 0; sn < 4; sn++) {
          const float e0 = EXP2F(fmaf(sa[mt][sn][0], LOG2E, ((const float*)&mv4[sn])[0]));
          const float e1 = EXP2F(fmaf(sa[mt][sn][1], LOG2E, ((const float*)&mv4[sn])[1]));
          const float e2 = EXP2F(fmaf(sa[mt][sn][2], LOG2E, ((const float*)&mv4[sn])[2]));
          const float e3 = EXP2F(fmaf(sa[mt][sn][3], LOG2E, ((const float*)&mv4[sn])[3]));
          int byte = qrow * 128 + sn * 32 + fhi * 8;
          byte ^= (qrow & 7) << 4;
          uint2 pk;
          pk.x = pack_bf2(e0, e1);
          pk.y = pack_bf2(e2, e3);
          *(uint2*)((char*)Pw + byte) = pk;
        }
      }
      asm volatile("s_waitcnt lgkmcnt(0)" ::: "memory");

      bf16x8 vv[2][4];
#pragma unroll
      for (int kk = 0; kk < 2; kk++)
#pragma unroll
        for (int dn = 0; dn < 4; dn++) {
          const int row = dn * 16 + fr;
          const int byte = row * 1024 +
              (((sc >> 3) + ((((kk << 2) | fhi) ^ (fr & 7)))) << 4);
          vv[kk][dn] = *(const bf16x8*)((const char*)&Vs[0] + byte);
        }

      __builtin_amdgcn_s_setprio(1);
#pragma unroll
      for (int kk = 0; kk < 2; kk++)
#pragma unroll
        for (int mt = 0; mt < 2; mt++) {
          int byte = (mt * 16 + fr) * 128 + kk * 64 + fhi * 16;
          byte ^= (fr & 7) << 4;
          const bf16x8 pa = *(const bf16x8*)((char*)Pw + byte);
#pragma unroll
          for (int dn = 0; dn < 4; dn++)
            oa[mt][dn] = __builtin_amdgcn_mfma_f32_16x16x32_bf16(pa, vv[kk][dn], oa[mt][dn], 0, 0, 0);
          lacc_a[mt] = __builtin_amdgcn_mfma_f32_16x16x32_bf16(pa, onesf, lacc_a[mt], 0, 0, 0);
        }
      __builtin_amdgcn_s_setprio(0);

      f32x4 sb[2][4];
#pragma unroll
      for (int mt = 0; mt < 2; mt++)
#pragma unroll
        for (int sn = 0; sn < 4; sn++) sb[mt][sn] = fz;
      __builtin_amdgcn_s_setprio(1);
#pragma unroll
      for (int kk = 0; kk < 2; kk++)
#pragma unroll
        for (int sn = 0; sn < 4; sn++)
#pragma unroll
          for (int mt = 0; mt < 2; mt++)
            sb[mt][sn] = __builtin_amdgcn_mfma_f32_16x16x32_bf16(kf[kk][sn], qfb[mt][kk], sb[mt][sn], 0, 0, 0);
      __builtin_amdgcn_s_setprio(0);

#pragma unroll
      for (int mt = 0; mt < 2; mt++) {
        const int qrow = mt * 16 + fr;
#pragma unroll
        for (int sn = 0; sn < 4; sn++) {
          const float e0 = EXP2F(fmaf(sb[mt][sn][0], LOG2E, ((const float*)&mv4[sn])[0]));
          const float e1 = EXP2F(fmaf(sb[mt][sn][1], LOG2E, ((const float*)&mv4[sn])[1]));
          const float e2 = EXP2F(fmaf(sb[mt][sn][2], LOG2E, ((const float*)&mv4[sn])[2]));
          const float e3 = EXP2F(fmaf(sb[mt][sn][3], LOG2E, ((const float*)&mv4[sn])[3]));
          int byte = qrow * 128 + sn * 32 + fhi * 8;
          byte ^= (qrow & 7) << 4;
          uint2 pk;
          pk.x = pack_bf2(e0, e1);
          pk.y = pack_bf2(e2, e3);
          *(uint2*)((char*)Pw + byte) = pk;
        }
      }
      asm volatile("s_waitcnt lgkmcnt(0)" ::: "memory");

      __builtin_amdgcn_s_setprio(1);
#pragma unroll
      for (int kk = 0; kk < 2; kk++)
#pragma unroll
        for (int mt = 0; mt < 2; mt++) {
          int byte = (mt * 16 + fr) * 128 + kk * 64 + fhi * 16;
          byte ^= (fr & 7) << 4;
          const bf16x8 pa = *(const bf16x8*)((char*)Pw + byte);
#pragma unroll
          for (int dn = 0; dn < 4; dn++)
            ob[mt][dn] = __builtin_amdgcn_mfma_f32_16x16x32_bf16(pa, vv[kk][dn], ob[mt][dn], 0, 0, 0);
          lacc_b[mt] = __builtin_amdgcn_mfma_f32_16x16x32_bf16(pa, onesf, lacc_b[mt], 0, 0, 0);
        }
      __builtin_amdgcn_s_setprio(0);
    }

#pragma unroll
    for (int mt = 0; mt < 2; mt++) {
      float loa[4], lob[4];
#pragma unroll
      for (int r = 0; r < 4; r++) {
        loa[r] = RCPF(lacc_a[mt][r]);
        lob[r] = RCPF(lacc_b[mt][r]);
      }
#pragma unroll
      for (int dn = 0; dn < 4; dn++)
#pragma unroll
        for (int r = 0; r < 4; r++) {
          const int rowa = rowbase_a + mt * 16 + fhi * 4 + r;
          O[(size_t)rowa * DIMC + h * 64 + dn * 16 + fr] = f2bf(oa[mt][dn][r] * loa[r]);
          const int rowb = rowbase_b + mt * 16 + fhi * 4 + r;
          O[(size_t)rowb * DIMC + h * 64 + dn * 16 + fr] = f2bf(ob[mt][dn][r] * lob[r]);
        }
    }
  }
}

// ---------------- launch ----------------

extern "C" void kernel_launch(void* const* d_in, const int* in_sizes, int n_in,
                              void* d_out, int out_size, void* d_ws, size_t ws_size,
                              hipStream_t stream) {
  const float* x      = (const float*)d_in[0];
  const float* ctx    = (const float*)d_in[1];
  const int*   cmask  = (const int*)d_in[2];
  const float* q_w    = (const float*)d_in[3];
  const float* q_b    = (const float*)d_in[4];
  const float* kv_w   = (const float*)d_in[5];
  const float* kv_b   = (const float*)d_in[6];
  const float* proj_w = (const float*)d_in[7];
  const float* proj_b = (const float*)d_in[8];
  float* out = (float*)d_out;

  char* ws = (char*)d_ws;
  size_t off = 0;
  auto alloc = [&](size_t bytes) {
    void* p = ws + off;
    off += (bytes + 255) & ~(size_t)255;
    return p;
  };
  u16* x_bf   = (u16*)alloc((size_t)16384 * 1024 * 2);
  u16* ctx_bf = (u16*)alloc((size_t)2048 * 1024 * 2);
  u16* qwT    = (u16*)alloc((size_t)1024 * 1024 * 2);
  u16* kvwT   = (u16*)alloc((size_t)2048 * 1024 * 2);
  u16* pwT    = (u16*)alloc((size_t)1024 * 1024 * 2);
  u16* Qb     = (u16*)alloc((size_t)16384 * 1024 * 2);
  u16* Kbuf   = (u16*)alloc((size_t)64 * 512 * 64 * 2);
  u16* VTbuf  = (u16*)alloc((size_t)64 * 64 * 512 * 2);
  u16* Ob     = (u16*)alloc((size_t)16384 * 1024 * 2);
  float* maskf = (float*)alloc((size_t)NB * NS * 4);

  // all preprocessing in one launch
  prep_kernel<<<6664, 256, 0, stream>>>(x, ctx, cmask, q_w, kv_w, proj_w,
                                        x_bf, ctx_bf, qwT, kvwT, pwT, maskf);

  // Q = (x @ q_w + q_b) * 0.125  (bf16 out, attention scale folded)
  gemm256<0><<<256, 512, 0, stream>>>(x_bf, qwT, q_b, Qb, 16384, 1024, 1024);
  // KV = ctx @ kv_w + kv_b  (scatter to K / V^T) -- modernized 128^2
  gemm_kv<<<dim3(16, 16), 256, 0, stream>>>(ctx_bf, kvwT, kv_b, Kbuf, VTbuf, 2048, 2048, 1024);
  // attention (dual-chain, shared K/V register fragments)
  attn_kernel<<<256, 512, 0, stream>>>(Qb, Kbuf, VTbuf, maskf, Ob);
  // out = O @ proj_w + proj_b (f32)
  gemm256<2><<<256, 512, 0, stream>>>(Ob, pwT, proj_b, out, 16384, 1024, 1024);
}

// Round 21
// 161.958 us; speedup vs baseline: 1.1559x; 1.0523x over previous
//
#include <hip/hip_runtime.h>
#include <hip/hip_bf16.h>

typedef __attribute__((ext_vector_type(8))) short bf16x8;
typedef __attribute__((ext_vector_type(4))) float f32x4;
typedef unsigned short u16;

#define DIMC 1024
#define NHEAD 16
#define HDIM 64
#define NB 4
#define NQ 4096
#define NS 512

#define LOG2E 1.44269504f

#if __has_builtin(__builtin_amdgcn_exp2f)
#define EXP2F(x) __builtin_amdgcn_exp2f(x)
#else
#define EXP2F(x) __expf(0.69314718f * (x))
#endif

#if __has_builtin(__builtin_amdgcn_rcpf)
#define RCPF(x) __builtin_amdgcn_rcpf(x)
#else
#define RCPF(x) (1.0f / (x))
#endif

__device__ __forceinline__ u16 f2bf(float f) {
  __hip_bfloat16 h = __float2bfloat16(f);
  return *reinterpret_cast<u16*>(&h);
}

__device__ __forceinline__ unsigned pack_bf2(float a, float b) {
  __hip_bfloat162 h2 = __float22bfloat162_rn(make_float2(a, b));
  return *reinterpret_cast<unsigned*>(&h2);
}

__device__ __forceinline__ void gload_lds16(const void* g, void* s) {
  __builtin_amdgcn_global_load_lds(
      (const __attribute__((address_space(1))) void*)g,
      (__attribute__((address_space(3))) void*)s, 16, 0, 0);
}

// ---------------- fused preprocessing kernel ----------------

__device__ __forceinline__ void cvt_body(const float* __restrict__ in,
                                         u16* __restrict__ out, int base, int nblk,
                                         int n4) {
  const int stride = nblk * 256;
  for (int i = base * 256 + threadIdx.x; i < n4; i += stride) {
    float4 v = *(const float4*)(in + (size_t)i * 4);
    ushort4 o;
    o.x = f2bf(v.x); o.y = f2bf(v.y); o.z = f2bf(v.z); o.w = f2bf(v.w);
    *(ushort4*)(out + (size_t)i * 4) = o;
  }
}

__global__ void prep_kernel(const float* __restrict__ x, const float* __restrict__ ctx,
                            const int* __restrict__ cmask,
                            const float* __restrict__ q_w, const float* __restrict__ kv_w,
                            const float* __restrict__ proj_w,
                            u16* __restrict__ x_bf, u16* __restrict__ ctx_bf,
                            u16* __restrict__ qwT, u16* __restrict__ kvwT,
                            u16* __restrict__ pwT, float* __restrict__ maskf) {
  __shared__ float t[32][33];
  const int bid = blockIdx.x;
  if (bid < 2048) {
    cvt_body(x, x_bf, bid, 2048, 16777216 / 4);
    return;
  }
  if (bid < 2560) {
    cvt_body(ctx, ctx_bf, bid - 2048, 512, 2097152 / 4);
    return;
  }
  if (bid >= 6656) {
    const int i = (bid - 6656) * 256 + threadIdx.x;
    if (i < NB * NS) maskf[i] = cmask[i] ? -1e30f : 0.0f;
    return;
  }
  // transpose jobs: W [K][N] f32 -> WT [N][K] bf16
  const float* W;
  u16* WT;
  int K, N, local;
  if (bid < 3584) {
    W = q_w; WT = qwT; K = 1024; N = 1024; local = bid - 2560;
  } else if (bid < 5632) {
    W = kv_w; WT = kvwT; K = 1024; N = 2048; local = bid - 3584;
  } else {
    W = proj_w; WT = pwT; K = 1024; N = 1024; local = bid - 5632;
  }
  const int nbx = N >> 5;
  const int bx = (local % nbx) * 32;
  const int by = (local / nbx) * 32;
  const int tx = threadIdx.x & 31, ty = threadIdx.x >> 5;  // ty 0..7
#pragma unroll
  for (int i = 0; i < 32; i += 8)
    t[ty + i][tx] = W[(size_t)(by + ty + i) * N + bx + tx];
  __syncthreads();
#pragma unroll
  for (int i = 0; i < 32; i += 8)
    WT[(size_t)(bx + ty + i) * K + by + tx] = f2bf(t[tx][ty + i]);
}

// ---------------- fused Q-proj (256^2) + KV-proj (128^2) dispatch ----------------
// Blocks 0..255: gemm256 MODE-0 body (verified r19 schedule; nblk hardcoded 256).
// Blocks 256..511: gemm_kv re-tiled for 512 threads (8 waves 2m x 4n, per-wave
// 64x32 output acc[4][2]); LDS aliases the gemm path's As/Bs (kv needs 64KB).
// No cross-path dependency; kv blocks fill CUs as Q-proj blocks retire.

__launch_bounds__(512, 1)
__global__ void gemm_qkv(const u16* __restrict__ A, const u16* __restrict__ BT,
                         const float* __restrict__ bias, u16* __restrict__ Qout,
                         const u16* __restrict__ Akv, const u16* __restrict__ BTkv,
                         const float* __restrict__ biaskv, u16* __restrict__ Kout,
                         u16* __restrict__ VTout) {
  __shared__ __align__(16) u16 As[2][16384];
  __shared__ __align__(16) u16 Bs[2][16384];
  const int tid = threadIdx.x;
  const int w = tid >> 6, l = tid & 63;
  const int fr = l & 15, fhi = l >> 4;
  const f32x4 fz = {0.f, 0.f, 0.f, 0.f};

  if (blockIdx.x < 256) {
    // ================= Q-proj: 256^2 tile, K=1024, M=16384, N=1024 ==========
    const int K = 1024, N = 1024;
    const int wm = w >> 2, wn = w & 3;
    const int nN = N >> 8;  // 4
    const int o = blockIdx.x;
    const int tIdx = (o & 7) * 32 + (o >> 3);   // nblk = 256
    const int m0 = (tIdx / nN) << 8;
    const int n0 = (tIdx % nN) << 8;

    const int rowoff = tid >> 3;
    const int gchunk = (tid & 7) ^ (rowoff & 7);
    const u16* Abase = A + (size_t)(m0 + rowoff) * K + gchunk * 8;
    const u16* Bbase = BT + (size_t)(n0 + rowoff) * K + gchunk * 8;
    const int ldsoff = w * 512;

    f32x4 acc[2][4][4];
#pragma unroll
    for (int mh = 0; mh < 2; mh++)
#pragma unroll
      for (int m = 0; m < 4; m++)
#pragma unroll
        for (int n = 0; n < 4; n++) acc[mh][m][n] = fz;

    const int KT = K >> 6;

#pragma unroll
    for (int p = 0; p < 4; ++p) {
      gload_lds16(Abase + (size_t)(p * 64) * K, &As[0][p * 4096 + ldsoff]);
      gload_lds16(Bbase + (size_t)(p * 64) * K, &Bs[0][p * 4096 + ldsoff]);
    }
    asm volatile("s_waitcnt vmcnt(0)" ::: "memory");
    __builtin_amdgcn_s_barrier();

    int nb = 0;
    for (int kt = 0; kt < KT; ++kt) {
      const int knext = (kt + 1) << 6;
      const bool more = (kt + 1) < KT;
#pragma unroll
      for (int p = 0; p < 4; ++p) {
        const int mh = p >> 1, kk = p & 1;
        const int ch = ((kk << 2) | fhi) ^ (fr & 7);
        bf16x8 af[4], bfr[4];
#pragma unroll
        for (int m = 0; m < 4; ++m) {
          const int row = wm * 128 + mh * 64 + m * 16 + fr;
          af[m] = *(const bf16x8*)((const char*)&As[nb][0] + row * 128 + ch * 16);
        }
#pragma unroll
        for (int n = 0; n < 4; ++n) {
          const int row = wn * 64 + n * 16 + fr;
          bfr[n] = *(const bf16x8*)((const char*)&Bs[nb][0] + row * 128 + ch * 16);
        }
        if (more) {
          gload_lds16(Abase + (size_t)(p * 64) * K + knext, &As[nb ^ 1][p * 4096 + ldsoff]);
          gload_lds16(Bbase + (size_t)(p * 64) * K + knext, &Bs[nb ^ 1][p * 4096 + ldsoff]);
        }
        __builtin_amdgcn_s_setprio(1);
#pragma unroll
        for (int m = 0; m < 4; ++m)
#pragma unroll
          for (int n = 0; n < 4; ++n)
            acc[mh][m][n] = __builtin_amdgcn_mfma_f32_16x16x32_bf16(af[m], bfr[n], acc[mh][m][n], 0, 0, 0);
        __builtin_amdgcn_s_setprio(0);
      }
      asm volatile("s_waitcnt vmcnt(0)" ::: "memory");
      __builtin_amdgcn_s_barrier();
      nb ^= 1;
    }

#pragma unroll
    for (int mh = 0; mh < 2; ++mh)
#pragma unroll
      for (int m = 0; m < 4; ++m)
#pragma unroll
        for (int n = 0; n < 4; ++n) {
          const int col = n0 + wn * 64 + n * 16 + fr;
          const float bv = bias[col];
#pragma unroll
          for (int r = 0; r < 4; ++r) {
            const int row = m0 + wm * 128 + mh * 64 + m * 16 + fhi * 4 + r;
            Qout[(size_t)row * N + col] = f2bf((acc[mh][m][n][r] + bv) * 0.125f);
          }
        }
  } else {
    // ================= KV-proj: 128^2 tile, K=1024, M=2048, N=2048 ==========
    // 8 waves as 2(m) x 4(n); per-wave 64x32 output -> acc[4][2].
    const int K = 1024;
    const int wm = w >> 2, wn = w & 3;
    const int o = blockIdx.x - 256;                 // 0..255
    const int tIdx = (o & 7) * 32 + (o >> 3);       // bijective (256 % 8 == 0)
    const int m0 = (tIdx >> 4) * 128;               // /16
    const int n0 = (tIdx & 15) * 128;               // %16

    // LDS alias: kv buffers [2][8192] u16 inside As / Bs
    u16* kvA = &As[0][0];
    u16* kvB = &Bs[0][0];

    f32x4 acc[4][2];
#pragma unroll
    for (int mt = 0; mt < 4; mt++)
#pragma unroll
      for (int nt = 0; nt < 2; nt++) acc[mt][nt] = fz;

    // staging: pass p covers rows p*64 + (tid>>3); chunk (tid&7)^(row&7)
    const int rowoff = tid >> 3;                    // 0..63
    const int gchunk = (tid & 7) ^ (rowoff & 7);
    const u16* Abase = Akv + (size_t)(m0 + rowoff) * K + gchunk * 8;
    const u16* Bbase = BTkv + (size_t)(n0 + rowoff) * K + gchunk * 8;
    const int ldsoff = w * 512;                     // elements within a pass

    const int KT = K >> 6;  // 16

#pragma unroll
    for (int p = 0; p < 2; ++p) {
      gload_lds16(Abase + (size_t)(p * 64) * K, &kvA[p * 4096 + ldsoff]);
      gload_lds16(Bbase + (size_t)(p * 64) * K, &kvB[p * 4096 + ldsoff]);
    }
    asm volatile("s_waitcnt vmcnt(0)" ::: "memory");
    __builtin_amdgcn_s_barrier();

    int nb = 0;
    for (int kt = 0; kt < KT; ++kt) {
      const int knext = (kt + 1) << 6;
      const bool more = (kt + 1) < KT;
      if (more) {
#pragma unroll
        for (int p = 0; p < 2; ++p) {
          gload_lds16(Abase + (size_t)(p * 64) * K + knext, &kvA[(nb ^ 1) * 8192 + p * 4096 + ldsoff]);
          gload_lds16(Bbase + (size_t)(p * 64) * K + knext, &kvB[(nb ^ 1) * 8192 + p * 4096 + ldsoff]);
        }
      }
#pragma unroll
      for (int kk = 0; kk < 2; ++kk) {
        const int ch = ((kk << 2) | fhi) ^ (fr & 7);
        bf16x8 a[4], b[2];
#pragma unroll
        for (int mt = 0; mt < 4; mt++) {
          const int ra = wm * 64 + mt * 16 + fr;
          a[mt] = *(const bf16x8*)((const char*)kvA + nb * 16384 + ra * 128 + ch * 16);
        }
#pragma unroll
        for (int nt = 0; nt < 2; nt++) {
          const int rb = wn * 32 + nt * 16 + fr;
          b[nt] = *(const bf16x8*)((const char*)kvB + nb * 16384 + rb * 128 + ch * 16);
        }
        __builtin_amdgcn_s_setprio(1);
#pragma unroll
        for (int mt = 0; mt < 4; mt++)
#pragma unroll
          for (int nt = 0; nt < 2; nt++)
            acc[mt][nt] = __builtin_amdgcn_mfma_f32_16x16x32_bf16(a[mt], b[nt], acc[mt][nt], 0, 0, 0);
        __builtin_amdgcn_s_setprio(0);
      }
      asm volatile("s_waitcnt vmcnt(0)" ::: "memory");
      __builtin_amdgcn_s_barrier();
      nb ^= 1;
    }

#pragma unroll
    for (int mt = 0; mt < 4; mt++) {
#pragma unroll
      for (int nt = 0; nt < 2; nt++) {
        const int col = n0 + wn * 32 + nt * 16 + fr;
        const float bv = biaskv[col];
#pragma unroll
        for (int r = 0; r < 4; r++) {
          const int row = m0 + wm * 64 + mt * 16 + fhi * 4 + r;
          const float v = acc[mt][nt][r] + bv;
          const int b = row >> 9, s = row & 511;
          if (col < 1024) {
            const int hh = col >> 6, d = col & 63;
            Kout[(((size_t)(b * 16 + hh)) * 512 + s) * 64 + d] = f2bf(v);
          } else {
            const int c2 = col - 1024;
            const int hh = c2 >> 6, d = c2 & 63;
            VTout[(((size_t)(b * 16 + hh)) * 64 + d) * 512 + s] = f2bf(v);
          }
        }
      }
    }
  }
}

// ---------------- 256-tile bf16 GEMM (r19-verified: barrier-free tile body) ----
// Used for the final out-projection only (MODE 2, f32 out).

template<int MODE>
__launch_bounds__(512, 1)
__global__ void gemm256(const u16* __restrict__ A, const u16* __restrict__ BT,
                        const float* __restrict__ bias, void* __restrict__ C0,
                        int M, int N, int K) {
  __shared__ __align__(16) u16 As[2][16384];
  __shared__ __align__(16) u16 Bs[2][16384];
  const int tid = threadIdx.x;
  const int w = tid >> 6, l = tid & 63;
  const int wm = w >> 2, wn = w & 3;
  const int fr = l & 15, fhi = l >> 4;

  const int nblk = gridDim.x;
  const int nN = N >> 8;
  const int o = blockIdx.x;
  const int tIdx = (o & 7) * (nblk >> 3) + (o >> 3);
  const int m0 = (tIdx / nN) << 8;
  const int n0 = (tIdx % nN) << 8;

  const int rowoff = tid >> 3;
  const int gchunk = (tid & 7) ^ (rowoff & 7);
  const u16* Abase = A + (size_t)(m0 + rowoff) * K + gchunk * 8;
  const u16* Bbase = BT + (size_t)(n0 + rowoff) * K + gchunk * 8;
  const int ldsoff = w * 512;

  const f32x4 fz = {0.f, 0.f, 0.f, 0.f};
  f32x4 acc[2][4][4];
#pragma unroll
  for (int mh = 0; mh < 2; mh++)
#pragma unroll
    for (int m = 0; m < 4; m++)
#pragma unroll
      for (int n = 0; n < 4; n++) acc[mh][m][n] = fz;

  const int KT = K >> 6;

#pragma unroll
  for (int p = 0; p < 4; ++p) {
    gload_lds16(Abase + (size_t)(p * 64) * K, &As[0][p * 4096 + ldsoff]);
    gload_lds16(Bbase + (size_t)(p * 64) * K, &Bs[0][p * 4096 + ldsoff]);
  }
  asm volatile("s_waitcnt vmcnt(0)" ::: "memory");
  __builtin_amdgcn_s_barrier();

  int nb = 0;
  for (int kt = 0; kt < KT; ++kt) {
    const int knext = (kt + 1) << 6;
    const bool more = (kt + 1) < KT;
#pragma unroll
    for (int p = 0; p < 4; ++p) {
      const int mh = p >> 1, kk = p & 1;
      const int ch = ((kk << 2) | fhi) ^ (fr & 7);
      bf16x8 af[4], bfr[4];
#pragma unroll
      for (int m = 0; m < 4; ++m) {
        const int row = wm * 128 + mh * 64 + m * 16 + fr;
        af[m] = *(const bf16x8*)((const char*)&As[nb][0] + row * 128 + ch * 16);
      }
#pragma unroll
      for (int n = 0; n < 4; ++n) {
        const int row = wn * 64 + n * 16 + fr;
        bfr[n] = *(const bf16x8*)((const char*)&Bs[nb][0] + row * 128 + ch * 16);
      }
      if (more) {
        gload_lds16(Abase + (size_t)(p * 64) * K + knext, &As[nb ^ 1][p * 4096 + ldsoff]);
        gload_lds16(Bbase + (size_t)(p * 64) * K + knext, &Bs[nb ^ 1][p * 4096 + ldsoff]);
      }
      __builtin_amdgcn_s_setprio(1);
#pragma unroll
      for (int m = 0; m < 4; ++m)
#pragma unroll
        for (int n = 0; n < 4; ++n)
          acc[mh][m][n] = __builtin_amdgcn_mfma_f32_16x16x32_bf16(af[m], bfr[n], acc[mh][m][n], 0, 0, 0);
      __builtin_amdgcn_s_setprio(0);
    }
    asm volatile("s_waitcnt vmcnt(0)" ::: "memory");
    __builtin_amdgcn_s_barrier();
    nb ^= 1;
  }

#pragma unroll
  for (int mh = 0; mh < 2; ++mh)
#pragma unroll
    for (int m = 0; m < 4; ++m)
#pragma unroll
      for (int n = 0; n < 4; ++n) {
        const int col = n0 + wn * 64 + n * 16 + fr;
        const float bv = bias[col];
#pragma unroll
        for (int r = 0; r < 4; ++r) {
          const int row = m0 + wm * 128 + mh * 64 + m * 16 + fhi * 4 + r;
          const float v = acc[mh][m][n][r] + bv;
          if (MODE == 0)
            ((u16*)C0)[(size_t)row * N + col] = f2bf(v * 0.125f);
          else
            ((float*)C0)[(size_t)row * N + col] = v;
        }
      }
}

// ---------------- fused attention v18 (verified, 50.3us) ----------------
__launch_bounds__(512, 2)
__global__ void attn_kernel(const u16* __restrict__ Q, const u16* __restrict__ Kb,
                            const u16* __restrict__ VT, const float* __restrict__ maskf,
                            u16* __restrict__ O) {
  __shared__ __align__(16) u16 Ks[512 * 64];
  __shared__ __align__(16) u16 Vs[64 * 512];
  __shared__ __align__(16) u16 Ps[8][2048];
  const int tid = threadIdx.x, w = tid >> 6, l = tid & 63;
  const int fr = l & 15, fhi = l >> 4;

  const int rid = blockIdx.x;
  const int orig = ((rid & 7) << 5) + (rid >> 3);
  const int bh = orig >> 2, qc = orig & 3;
  const int b = bh >> 4, h = bh & 15;

  const u16* Kg = Kb + (size_t)bh * NS * HDIM;
  const u16* Vg = VT + (size_t)bh * HDIM * NS;
  const float* mrow = maskf + b * NS;

#pragma unroll
  for (int it = 0; it < 8; ++it) {
    const int slot = it * 512 + tid;
    const int r = slot >> 3, c3 = slot & 7;
    const int gc = c3 ^ (r & 7);
    gload_lds16(Kg + (size_t)r * HDIM + gc * 8, &Ks[slot * 8]);
  }
#pragma unroll
  for (int it = 0; it < 8; ++it) {
    const int slot = it * 512 + tid;
    const int r = slot >> 6, c6 = slot & 63;
    const int gc = c6 ^ (r & 7);
    gload_lds16(Vg + (size_t)r * NS + gc * 8, &Vs[slot * 8]);
  }
  asm volatile("s_waitcnt vmcnt(0)" ::: "memory");
  __syncthreads();

  u16* Pw = Ps[w];
  const f32x4 fz = {0.f, 0.f, 0.f, 0.f};

  bf16x8 onesf;
#pragma unroll
  for (int i = 0; i < 8; ++i) onesf[i] = (short)0x3F80;

#pragma unroll 1
  for (int qt2 = 0; qt2 < 2; ++qt2) {
    const int rowbase_a = b * NQ + qc * 1024 + w * 128 + qt2 * 64;
    const int rowbase_b = rowbase_a + 32;

    bf16x8 qfa[2][2], qfb[2][2];
#pragma unroll
    for (int mt = 0; mt < 2; mt++)
#pragma unroll
      for (int kk = 0; kk < 2; kk++) {
        qfa[mt][kk] = *(const bf16x8*)&Q[(size_t)(rowbase_a + mt * 16 + fr) * DIMC +
                                         h * 64 + kk * 32 + fhi * 8];
        qfb[mt][kk] = *(const bf16x8*)&Q[(size_t)(rowbase_b + mt * 16 + fr) * DIMC +
                                         h * 64 + kk * 32 + fhi * 8];
      }

    f32x4 lacc_a[2], lacc_b[2];
    f32x4 oa[2][4], ob[2][4];
#pragma unroll
    for (int mt = 0; mt < 2; mt++) {
      lacc_a[mt] = fz; lacc_b[mt] = fz;
#pragma unroll
      for (int dn = 0; dn < 4; dn++) { oa[mt][dn] = fz; ob[mt][dn] = fz; }
    }

#pragma unroll
    for (int t = 0; t < 8; ++t) {
      const int sc = t * 64;

      bf16x8 kf[2][4];
#pragma unroll
      for (int kk = 0; kk < 2; kk++)
#pragma unroll
        for (int sn = 0; sn < 4; sn++) {
          const int row = sc + sn * 16 + fr;
          const int byte = row * 128 + ((((kk << 2) | fhi) ^ (fr & 7)) << 4);
          kf[kk][sn] = *(const bf16x8*)((const char*)&Ks[0] + byte);
        }

      f32x4 sa[2][4];
#pragma unroll
      for (int mt = 0; mt < 2; mt++)
#pragma unroll
        for (int sn = 0; sn < 4; sn++) sa[mt][sn] = fz;
      __builtin_amdgcn_s_setprio(1);
#pragma unroll
      for (int kk = 0; kk < 2; kk++)
#pragma unroll
        for (int sn = 0; sn < 4; sn++)
#pragma unroll
          for (int mt = 0; mt < 2; mt++)
            sa[mt][sn] = __builtin_amdgcn_mfma_f32_16x16x32_bf16(kf[kk][sn], qfa[mt][kk], sa[mt][sn], 0, 0, 0);
      __builtin_amdgcn_s_setprio(0);

      float4 mv4[4];
#pragma unroll
      for (int sn = 0; sn < 4; sn++)
        mv4[sn] = *(const float4*)&mrow[sc + sn * 16 + fhi * 4];

#pragma unroll
      for (int mt = 0; mt < 2; mt++) {
        const int qrow = mt * 16 + fr;
#pragma unroll
        for (int sn = 0; sn < 4; sn++) {
          const float e0 = EXP2F(fmaf(sa[mt][sn][0], LOG2E, ((const float*)&mv4[sn])[0]));
          const float e1 = EXP2F(fmaf(sa[mt][sn][1], LOG2E, ((const float*)&mv4[sn])[1]));
          const float e2 = EXP2F(fmaf(sa[mt][sn][2], LOG2E, ((const float*)&mv4[sn])[2]));
          const float e3 = EXP2F(fmaf(sa[mt][sn][3], LOG2E, ((const float*)&mv4[sn])[3]));
          int byte = qrow * 128 + sn * 32 + fhi * 8;
          byte ^= (qrow & 7) << 4;
          uint2 pk;
          pk.x = pack_bf2(e0, e1);
          pk.y = pack_bf2(e2, e3);
          *(uint2*)((char*)Pw + byte) = pk;
        }
      }
      asm volatile("s_waitcnt lgkmcnt(0)" ::: "memory");

      bf16x8 vv[2][4];
#pragma unroll
      for (int kk = 0; kk < 2; kk++)
#pragma unroll
        for (int dn = 0; dn < 4; dn++) {
          const int row = dn * 16 + fr;
          const int byte = row * 1024 +
              (((sc >> 3) + ((((kk << 2) | fhi) ^ (fr & 7)))) << 4);
          vv[kk][dn] = *(const bf16x8*)((const char*)&Vs[0] + byte);
        }

      __builtin_amdgcn_s_setprio(1);
#pragma unroll
      for (int kk = 0; kk < 2; kk++)
#pragma unroll
        for (int mt = 0; mt < 2; mt++) {
          int byte = (mt * 16 + fr) * 128 + kk * 64 + fhi * 16;
          byte ^= (fr & 7) << 4;
          const bf16x8 pa = *(const bf16x8*)((char*)Pw + byte);
#pragma unroll
          for (int dn = 0; dn < 4; dn++)
            oa[mt][dn] = __builtin_amdgcn_mfma_f32_16x16x32_bf16(pa, vv[kk][dn], oa[mt][dn], 0, 0, 0);
          lacc_a[mt] = __builtin_amdgcn_mfma_f32_16x16x32_bf16(pa, onesf, lacc_a[mt], 0, 0, 0);
        }
      __builtin_amdgcn_s_setprio(0);

      f32x4 sb[2][4];
#pragma unroll
      for (int mt = 0; mt < 2; mt++)
#pragma unroll
        for (int sn = 0; sn < 4; sn++) sb[mt][sn] = fz;
      __builtin_amdgcn_s_setprio(1);
#pragma unroll
      for (int kk = 0; kk < 2; kk++)
#pragma unroll
        for (int sn = 0; sn < 4; sn++)
#pragma unroll
          for (int mt = 0; mt < 2; mt++)
            sb[mt][sn] = __builtin_amdgcn_mfma_f32_16x16x32_bf16(kf[kk][sn], qfb[mt][kk], sb[mt][sn], 0, 0, 0);
      __builtin_amdgcn_s_setprio(0);

#pragma unroll
      for (int mt = 0; mt < 2; mt++) {
        const int qrow = mt * 16 + fr;
#pragma unroll
        for (int sn = 0; sn < 4; sn++) {
          const float e0 = EXP2F(fmaf(sb[mt][sn][0], LOG2E, ((const float*)&mv4[sn])[0]));
          const float e1 = EXP2F(fmaf(sb[mt][sn][1], LOG2E, ((const float*)&mv4[sn])[1]));
          const float e2 = EXP2F(fmaf(sb[mt][sn][2], LOG2E, ((const float*)&mv4[sn])[2]));
          const float e3 = EXP2F(fmaf(sb[mt][sn][3], LOG2E, ((const float*)&mv4[sn])[3]));
          int byte = qrow * 128 + sn * 32 + fhi * 8;
          byte ^= (qrow & 7) << 4;
          uint2 pk;
          pk.x = pack_bf2(e0, e1);
          pk.y = pack_bf2(e2, e3);
          *(uint2*)((char*)Pw + byte) = pk;
        }
      }
      asm volatile("s_waitcnt lgkmcnt(0)" ::: "memory");

      __builtin_amdgcn_s_setprio(1);
#pragma unroll
      for (int kk = 0; kk < 2; kk++)
#pragma unroll
        for (int mt = 0; mt < 2; mt++) {
          int byte = (mt * 16 + fr) * 128 + kk * 64 + fhi * 16;
          byte ^= (fr & 7) << 4;
          const bf16x8 pa = *(const bf16x8*)((char*)Pw + byte);
#pragma unroll
          for (int dn = 0; dn < 4; dn++)
            ob[mt][dn] = __builtin_amdgcn_mfma_f32_16x16x32_bf16(pa, vv[kk][dn], ob[mt][dn], 0, 0, 0);
          lacc_b[mt] = __builtin_amdgcn_mfma_f32_16x16x32_bf16(pa, onesf, lacc_b[mt], 0, 0, 0);
        }
      __builtin_amdgcn_s_setprio(0);
    }

#pragma unroll
    for (int mt = 0; mt < 2; mt++) {
      float loa[4], lob[4];
#pragma unroll
      for (int r = 0; r < 4; r++) {
        loa[r] = RCPF(lacc_a[mt][r]);
        lob[r] = RCPF(lacc_b[mt][r]);
      }
#pragma unroll
      for (int dn = 0; dn < 4; dn++)
#pragma unroll
        for (int r = 0; r < 4; r++) {
          const int rowa = rowbase_a + mt * 16 + fhi * 4 + r;
          O[(size_t)rowa * DIMC + h * 64 + dn * 16 + fr] = f2bf(oa[mt][dn][r] * loa[r]);
          const int rowb = rowbase_b + mt * 16 + fhi * 4 + r;
          O[(size_t)rowb * DIMC + h * 64 + dn * 16 + fr] = f2bf(ob[mt][dn][r] * lob[r]);
        }
    }
  }
}

// ---------------- launch ----------------

extern "C" void kernel_launch(void* const* d_in, const int* in_sizes, int n_in,
                              void* d_out, int out_size, void* d_ws, size_t ws_size,
                              hipStream_t stream) {
  const float* x      = (const float*)d_in[0];
  const float* ctx    = (const float*)d_in[1];
  const int*   cmask  = (const int*)d_in[2];
  const float* q_w    = (const float*)d_in[3];
  const float* q_b    = (const float*)d_in[4];
  const float* kv_w   = (const float*)d_in[5];
  const float* kv_b   = (const float*)d_in[6];
  const float* proj_w = (const float*)d_in[7];
  const float* proj_b = (const float*)d_in[8];
  float* out = (float*)d_out;

  char* ws = (char*)d_ws;
  size_t off = 0;
  auto alloc = [&](size_t bytes) {
    void* p = ws + off;
    off += (bytes + 255) & ~(size_t)255;
    return p;
  };
  u16* x_bf   = (u16*)alloc((size_t)16384 * 1024 * 2);
  u16* ctx_bf = (u16*)alloc((size_t)2048 * 1024 * 2);
  u16* qwT    = (u16*)alloc((size_t)1024 * 1024 * 2);
  u16* kvwT   = (u16*)alloc((size_t)2048 * 1024 * 2);
  u16* pwT    = (u16*)alloc((size_t)1024 * 1024 * 2);
  u16* Qb     = (u16*)alloc((size_t)16384 * 1024 * 2);
  u16* Kbuf   = (u16*)alloc((size_t)64 * 512 * 64 * 2);
  u16* VTbuf  = (u16*)alloc((size_t)64 * 64 * 512 * 2);
  u16* Ob     = (u16*)alloc((size_t)16384 * 1024 * 2);
  float* maskf = (float*)alloc((size_t)NB * NS * 4);

  // all preprocessing in one launch
  prep_kernel<<<6664, 256, 0, stream>>>(x, ctx, cmask, q_w, kv_w, proj_w,
                                        x_bf, ctx_bf, qwT, kvwT, pwT, maskf);

  // Q-proj (blocks 0..255) + KV-proj (blocks 256..511), fused dispatch
  gemm_qkv<<<512, 512, 0, stream>>>(x_bf, qwT, q_b, Qb,
                                    ctx_bf, kvwT, kv_b, Kbuf, VTbuf);
  // attention (dual-chain, shared K/V register fragments)
  attn_kernel<<<256, 512, 0, stream>>>(Qb, Kbuf, VTbuf, maskf, Ob);
  // out = O @ proj_w + proj_b (f32)
  gemm256<2><<<256, 512, 0, stream>>>(Ob, pwT, proj_b, out, 16384, 1024, 1024);
}

// Round 23
// 161.929 us; speedup vs baseline: 1.1561x; 1.0002x over previous
//
#include <hip/hip_runtime.h>
#include <hip/hip_bf16.h>

typedef __attribute__((ext_vector_type(8))) short bf16x8;
typedef __attribute__((ext_vector_type(4))) float f32x4;
typedef unsigned short u16;

#define DIMC 1024
#define NHEAD 16
#define HDIM 64
#define NB 4
#define NQ 4096
#define NS 512

#define LOG2E 1.44269504f

#if __has_builtin(__builtin_amdgcn_exp2f)
#define EXP2F(x) __builtin_amdgcn_exp2f(x)
#else
#define EXP2F(x) __expf(0.69314718f * (x))
#endif

#if __has_builtin(__builtin_amdgcn_rcpf)
#define RCPF(x) __builtin_amdgcn_rcpf(x)
#else
#define RCPF(x) (1.0f / (x))
#endif

__device__ __forceinline__ u16 f2bf(float f) {
  __hip_bfloat16 h = __float2bfloat16(f);
  return *reinterpret_cast<u16*>(&h);
}

__device__ __forceinline__ unsigned pack_bf2(float a, float b) {
  __hip_bfloat162 h2 = __float22bfloat162_rn(make_float2(a, b));
  return *reinterpret_cast<unsigned*>(&h2);
}

__device__ __forceinline__ void gload_lds16(const void* g, void* s) {
  __builtin_amdgcn_global_load_lds(
      (const __attribute__((address_space(1))) void*)g,
      (__attribute__((address_space(3))) void*)s, 16, 0, 0);
}

// ---------------- fused preprocessing kernel ----------------

__device__ __forceinline__ void cvt_body(const float* __restrict__ in,
                                         u16* __restrict__ out, int base, int nblk,
                                         int n4) {
  const int stride = nblk * 256;
  for (int i = base * 256 + threadIdx.x; i < n4; i += stride) {
    float4 v = *(const float4*)(in + (size_t)i * 4);
    ushort4 o;
    o.x = f2bf(v.x); o.y = f2bf(v.y); o.z = f2bf(v.z); o.w = f2bf(v.w);
    *(ushort4*)(out + (size_t)i * 4) = o;
  }
}

__global__ void prep_kernel(const float* __restrict__ x, const float* __restrict__ ctx,
                            const int* __restrict__ cmask,
                            const float* __restrict__ q_w, const float* __restrict__ kv_w,
                            const float* __restrict__ proj_w,
                            u16* __restrict__ x_bf, u16* __restrict__ ctx_bf,
                            u16* __restrict__ qwT, u16* __restrict__ kvwT,
                            u16* __restrict__ pwT, float* __restrict__ maskf) {
  __shared__ float t[32][33];
  const int bid = blockIdx.x;
  if (bid < 2048) {
    cvt_body(x, x_bf, bid, 2048, 16777216 / 4);
    return;
  }
  if (bid < 2560) {
    cvt_body(ctx, ctx_bf, bid - 2048, 512, 2097152 / 4);
    return;
  }
  if (bid >= 6656) {
    const int i = (bid - 6656) * 256 + threadIdx.x;
    if (i < NB * NS) maskf[i] = cmask[i] ? -1e30f : 0.0f;
    return;
  }
  const float* W;
  u16* WT;
  int K, N, local;
  if (bid < 3584) {
    W = q_w; WT = qwT; K = 1024; N = 1024; local = bid - 2560;
  } else if (bid < 5632) {
    W = kv_w; WT = kvwT; K = 1024; N = 2048; local = bid - 3584;
  } else {
    W = proj_w; WT = pwT; K = 1024; N = 1024; local = bid - 5632;
  }
  const int nbx = N >> 5;
  const int bx = (local % nbx) * 32;
  const int by = (local / nbx) * 32;
  const int tx = threadIdx.x & 31, ty = threadIdx.x >> 5;
#pragma unroll
  for (int i = 0; i < 32; i += 8)
    t[ty + i][tx] = W[(size_t)(by + ty + i) * N + bx + tx];
  __syncthreads();
#pragma unroll
  for (int i = 0; i < 32; i += 8)
    WT[(size_t)(bx + ty + i) * K + by + tx] = f2bf(t[tx][ty + i]);
}

// ======== BK=32 triple-buffered 256^2 GEMM body (counted-vmcnt pipeline) =====
// Depth-2 prefetch: stage tile kt+2 while reading tile kt. The data for tile
// kt+1 was issued one FULL tile earlier by EVERY wave, so each wave's own
// vmcnt(4) (4 newest = kt+2's loads) proves its kt+1 contribution landed;
// the barrier collects all waves -> all-waves visibility WITHOUT a drain.
// (r14's depth-1 counted vmcnt was invalid; this is the sound form.)
// Swizzle (64B rows): stage global chunk (tid&3)^((tid>>3)&3) -> linear LDS;
// read chunk fhi^((row>>1)&3). LDS 3 x 16KB x 2 = 96KB.

__device__ __forceinline__ void gemm_bk32_body(
    const u16* __restrict__ A, const u16* __restrict__ BT,
    int m0, int n0, int tid, int wm, int wn, int fr, int fhi,
    u16 (*As)[8192], u16 (*Bs)[8192], f32x4 acc[2][4][4]) {
  const int K = 1024;
  const int srow = tid >> 2;
  const int gch = (tid & 3) ^ ((tid >> 3) & 3);
  const u16* Abase = A + (size_t)(m0 + srow) * K + gch * 8;
  const u16* Bbase = BT + (size_t)(n0 + srow) * K + gch * 8;
  const int dst0 = tid * 8;
  const int KT = K >> 5;  // 32

  // prologue: stage tiles 0 and 1
  gload_lds16(Abase, &As[0][dst0]);
  gload_lds16(Abase + (size_t)128 * K, &As[0][dst0 + 4096]);
  gload_lds16(Bbase, &Bs[0][dst0]);
  gload_lds16(Bbase + (size_t)128 * K, &Bs[0][dst0 + 4096]);
  gload_lds16(Abase + 32, &As[1][dst0]);
  gload_lds16(Abase + (size_t)128 * K + 32, &As[1][dst0 + 4096]);
  gload_lds16(Bbase + 32, &Bs[1][dst0]);
  gload_lds16(Bbase + (size_t)128 * K + 32, &Bs[1][dst0 + 4096]);
  asm volatile("s_waitcnt vmcnt(4)" ::: "memory");
  __builtin_amdgcn_s_barrier();

  int cur = 0;
  for (int kt = 0; kt < KT; ++kt) {
    bf16x8 af[8], bfr[4];
#pragma unroll
    for (int m = 0; m < 8; ++m) {
      const int row = wm * 128 + m * 16 + fr;
      const int byte = row * 64 + ((fhi ^ ((row >> 1) & 3)) << 4);
      af[m] = *(const bf16x8*)((const char*)&As[cur][0] + byte);
    }
#pragma unroll
    for (int n = 0; n < 4; ++n) {
      const int row = wn * 64 + n * 16 + fr;
      const int byte = row * 64 + ((fhi ^ ((row >> 1) & 3)) << 4);
      bfr[n] = *(const bf16x8*)((const char*)&Bs[cur][0] + byte);
    }
    const bool stg = (kt + 2) < KT;
    if (stg) {
      int nb2 = cur + 2; if (nb2 >= 3) nb2 -= 3;
      const int kof = (kt + 2) << 5;
      gload_lds16(Abase + kof, &As[nb2][dst0]);
      gload_lds16(Abase + (size_t)128 * K + kof, &As[nb2][dst0 + 4096]);
      gload_lds16(Bbase + kof, &Bs[nb2][dst0]);
      gload_lds16(Bbase + (size_t)128 * K + kof, &Bs[nb2][dst0 + 4096]);
    }
    __builtin_amdgcn_s_setprio(1);
#pragma unroll
    for (int m = 0; m < 8; ++m)
#pragma unroll
      for (int n = 0; n < 4; ++n)
        acc[m >> 2][m & 3][n] = __builtin_amdgcn_mfma_f32_16x16x32_bf16(
            af[m], bfr[n], acc[m >> 2][m & 3][n], 0, 0, 0);
    __builtin_amdgcn_s_setprio(0);
    if (stg) { asm volatile("s_waitcnt vmcnt(4)" ::: "memory"); }
    else     { asm volatile("s_waitcnt vmcnt(0)" ::: "memory"); }
    __builtin_amdgcn_s_barrier();
    ++cur; if (cur == 3) cur = 0;
  }
}

// ---------------- fused Q-proj + KV-proj dispatch ----------------
// Blocks 0..255: Q-proj via BK=32 triple-buffer body (96KB LDS).
// Blocks 256..511: KV-proj 128^2 (r20-verified), aliasing As/Bs storage.

__launch_bounds__(512, 1)
__global__ void gemm_qkv(const u16* __restrict__ A, const u16* __restrict__ BT,
                         const float* __restrict__ bias, u16* __restrict__ Qout,
                         const u16* __restrict__ Akv, const u16* __restrict__ BTkv,
                         const float* __restrict__ biaskv, u16* __restrict__ Kout,
                         u16* __restrict__ VTout) {
  __shared__ __align__(16) u16 As[3][8192];
  __shared__ __align__(16) u16 Bs[3][8192];
  const int tid = threadIdx.x;
  const int w = tid >> 6, l = tid & 63;
  const int fr = l & 15, fhi = l >> 4;
  const f32x4 fz = {0.f, 0.f, 0.f, 0.f};

  if (blockIdx.x < 256) {
    const int wm = w >> 2, wn = w & 3;
    const int o = blockIdx.x;
    const int tIdx = (o & 7) * 32 + (o >> 3);   // nblk = 256
    const int m0 = (tIdx >> 2) << 8;            // nN = 4
    const int n0 = (tIdx & 3) << 8;

    f32x4 acc[2][4][4];
#pragma unroll
    for (int mh = 0; mh < 2; mh++)
#pragma unroll
      for (int m = 0; m < 4; m++)
#pragma unroll
        for (int n = 0; n < 4; n++) acc[mh][m][n] = fz;

    gemm_bk32_body(A, BT, m0, n0, tid, wm, wn, fr, fhi, As, Bs, acc);

#pragma unroll
    for (int mh = 0; mh < 2; ++mh)
#pragma unroll
      for (int m = 0; m < 4; ++m)
#pragma unroll
        for (int n = 0; n < 4; ++n) {
          const int col = n0 + wn * 64 + n * 16 + fr;
          const float bv = bias[col];
#pragma unroll
          for (int r = 0; r < 4; ++r) {
            const int row = m0 + wm * 128 + mh * 64 + m * 16 + fhi * 4 + r;
            Qout[(size_t)row * 1024 + col] = f2bf((acc[mh][m][n][r] + bv) * 0.125f);
          }
        }
  } else {
    // ================= KV-proj: 128^2 tile, BK=64, dbuf (r20-verified) ======
    const int K = 1024;
    const int wm = w >> 2, wn = w & 3;
    const int o = blockIdx.x - 256;
    const int tIdx = (o & 7) * 32 + (o >> 3);
    const int m0 = (tIdx >> 4) * 128;
    const int n0 = (tIdx & 15) * 128;

    f32x4 acc[4][2];
#pragma unroll
    for (int mt = 0; mt < 4; mt++)
#pragma unroll
      for (int nt = 0; nt < 2; nt++) acc[mt][nt] = fz;

    const int rowoff = tid >> 3;
    const int gchunk = (tid & 7) ^ (rowoff & 7);
    const u16* Abase = Akv + (size_t)(m0 + rowoff) * K + gchunk * 8;
    const u16* Bbase = BTkv + (size_t)(n0 + rowoff) * K + gchunk * 8;
    const int ldsoff = w * 512;

    const int KT = K >> 6;

#pragma unroll
    for (int p = 0; p < 2; ++p) {
      gload_lds16(Abase + (size_t)(p * 64) * K, &As[0][p * 4096 + ldsoff]);
      gload_lds16(Bbase + (size_t)(p * 64) * K, &Bs[0][p * 4096 + ldsoff]);
    }
    asm volatile("s_waitcnt vmcnt(0)" ::: "memory");
    __builtin_amdgcn_s_barrier();

    int nb = 0;
    for (int kt = 0; kt < KT; ++kt) {
      const int knext = (kt + 1) << 6;
      const bool more = (kt + 1) < KT;
      if (more) {
#pragma unroll
        for (int p = 0; p < 2; ++p) {
          gload_lds16(Abase + (size_t)(p * 64) * K + knext, &As[nb ^ 1][p * 4096 + ldsoff]);
          gload_lds16(Bbase + (size_t)(p * 64) * K + knext, &Bs[nb ^ 1][p * 4096 + ldsoff]);
        }
      }
#pragma unroll
      for (int kk = 0; kk < 2; ++kk) {
        const int ch = ((kk << 2) | fhi) ^ (fr & 7);
        bf16x8 a[4], b[2];
#pragma unroll
        for (int mt = 0; mt < 4; mt++) {
          const int ra = wm * 64 + mt * 16 + fr;
          a[mt] = *(const bf16x8*)((const char*)&As[nb][0] + ra * 128 + ch * 16);
        }
#pragma unroll
        for (int nt = 0; nt < 2; nt++) {
          const int rb = wn * 32 + nt * 16 + fr;
          b[nt] = *(const bf16x8*)((const char*)&Bs[nb][0] + rb * 128 + ch * 16);
        }
        __builtin_amdgcn_s_setprio(1);
#pragma unroll
        for (int mt = 0; mt < 4; mt++)
#pragma unroll
          for (int nt = 0; nt < 2; nt++)
            acc[mt][nt] = __builtin_amdgcn_mfma_f32_16x16x32_bf16(a[mt], b[nt], acc[mt][nt], 0, 0, 0);
        __builtin_amdgcn_s_setprio(0);
      }
      asm volatile("s_waitcnt vmcnt(0)" ::: "memory");
      __builtin_amdgcn_s_barrier();
      nb ^= 1;
    }

#pragma unroll
    for (int mt = 0; mt < 4; mt++) {
#pragma unroll
      for (int nt = 0; nt < 2; nt++) {
        const int col = n0 + wn * 32 + nt * 16 + fr;
        const float bv = biaskv[col];
#pragma unroll
        for (int r = 0; r < 4; r++) {
          const int row = m0 + wm * 64 + mt * 16 + fhi * 4 + r;
          const float v = acc[mt][nt][r] + bv;
          const int b = row >> 9, s = row & 511;
          if (col < 1024) {
            const int hh = col >> 6, d = col & 63;
            Kout[(((size_t)(b * 16 + hh)) * 512 + s) * 64 + d] = f2bf(v);
          } else {
            const int c2 = col - 1024;
            const int hh = c2 >> 6, d = c2 & 63;
            VTout[(((size_t)(b * 16 + hh)) * 64 + d) * 512 + s] = f2bf(v);
          }
        }
      }
    }
  }
}

// ---------------- out-projection: BK=32 triple-buffer, f32 out ----------------

__launch_bounds__(512, 1)
__global__ void gemm_out(const u16* __restrict__ A, const u16* __restrict__ BT,
                         const float* __restrict__ bias, float* __restrict__ C0) {
  __shared__ __align__(16) u16 As[3][8192];
  __shared__ __align__(16) u16 Bs[3][8192];
  const int tid = threadIdx.x;
  const int w = tid >> 6, l = tid & 63;
  const int wm = w >> 2, wn = w & 3;
  const int fr = l & 15, fhi = l >> 4;
  const f32x4 fz = {0.f, 0.f, 0.f, 0.f};

  const int o = blockIdx.x;
  const int tIdx = (o & 7) * 32 + (o >> 3);   // nblk = 256
  const int m0 = (tIdx >> 2) << 8;            // nN = 4
  const int n0 = (tIdx & 3) << 8;

  f32x4 acc[2][4][4];
#pragma unroll
  for (int mh = 0; mh < 2; mh++)
#pragma unroll
    for (int m = 0; m < 4; m++)
#pragma unroll
      for (int n = 0; n < 4; n++) acc[mh][m][n] = fz;

  gemm_bk32_body(A, BT, m0, n0, tid, wm, wn, fr, fhi, As, Bs, acc);

#pragma unroll
  for (int mh = 0; mh < 2; ++mh)
#pragma unroll
    for (int m = 0; m < 4; ++m)
#pragma unroll
      for (int n = 0; n < 4; ++n) {
        const int col = n0 + wn * 64 + n * 16 + fr;
        const float bv = bias[col];
#pragma unroll
        for (int r = 0; r < 4; ++r) {
          const int row = m0 + wm * 128 + mh * 64 + m * 16 + fhi * 4 + r;
          C0[(size_t)row * 1024 + col] = acc[mh][m][n][r] + bv;
        }
      }
}

// ---------------- fused attention v18 (verified, 50.3us) ----------------
__launch_bounds__(512, 2)
__global__ void attn_kernel(const u16* __restrict__ Q, const u16* __restrict__ Kb,
                            const u16* __restrict__ VT, const float* __restrict__ maskf,
                            u16* __restrict__ O) {
  __shared__ __align__(16) u16 Ks[512 * 64];
  __shared__ __align__(16) u16 Vs[64 * 512];
  __shared__ __align__(16) u16 Ps[8][2048];
  const int tid = threadIdx.x, w = tid >> 6, l = tid & 63;
  const int fr = l & 15, fhi = l >> 4;

  const int rid = blockIdx.x;
  const int orig = ((rid & 7) << 5) + (rid >> 3);
  const int bh = orig >> 2, qc = orig & 3;
  const int b = bh >> 4, h = bh & 15;

  const u16* Kg = Kb + (size_t)bh * NS * HDIM;
  const u16* Vg = VT + (size_t)bh * HDIM * NS;
  const float* mrow = maskf + b * NS;

#pragma unroll
  for (int it = 0; it < 8; ++it) {
    const int slot = it * 512 + tid;
    const int r = slot >> 3, c3 = slot & 7;
    const int gc = c3 ^ (r & 7);
    gload_lds16(Kg + (size_t)r * HDIM + gc * 8, &Ks[slot * 8]);
  }
#pragma unroll
  for (int it = 0; it < 8; ++it) {
    const int slot = it * 512 + tid;
    const int r = slot >> 6, c6 = slot & 63;
    const int gc = c6 ^ (r & 7);
    gload_lds16(Vg + (size_t)r * NS + gc * 8, &Vs[slot * 8]);
  }
  asm volatile("s_waitcnt vmcnt(0)" ::: "memory");
  __syncthreads();

  u16* Pw = Ps[w];
  const f32x4 fz = {0.f, 0.f, 0.f, 0.f};

  bf16x8 onesf;
#pragma unroll
  for (int i = 0; i < 8; ++i) onesf[i] = (short)0x3F80;

#pragma unroll 1
  for (int qt2 = 0; qt2 < 2; ++qt2) {
    const int rowbase_a = b * NQ + qc * 1024 + w * 128 + qt2 * 64;
    const int rowbase_b = rowbase_a + 32;

    bf16x8 qfa[2][2], qfb[2][2];
#pragma unroll
    for (int mt = 0; mt < 2; mt++)
#pragma unroll
      for (int kk = 0; kk < 2; kk++) {
        qfa[mt][kk] = *(const bf16x8*)&Q[(size_t)(rowbase_a + mt * 16 + fr) * DIMC +
                                         h * 64 + kk * 32 + fhi * 8];
        qfb[mt][kk] = *(const bf16x8*)&Q[(size_t)(rowbase_b + mt * 16 + fr) * DIMC +
                                         h * 64 + kk * 32 + fhi * 8];
      }

    f32x4 lacc_a[2], lacc_b[2];
    f32x4 oa[2][4], ob[2][4];
#pragma unroll
    for (int mt = 0; mt < 2; mt++) {
      lacc_a[mt] = fz; lacc_b[mt] = fz;
#pragma unroll
      for (int dn = 0; dn < 4; dn++) { oa[mt][dn] = fz; ob[mt][dn] = fz; }
    }

#pragma unroll
    for (int t = 0; t < 8; ++t) {
      const int sc = t * 64;

      bf16x8 kf[2][4];
#pragma unroll
      for (int kk = 0; kk < 2; kk++)
#pragma unroll
        for (int sn = 0; sn < 4; sn++) {
          const int row = sc + sn * 16 + fr;
          const int byte = row * 128 + ((((kk << 2) | fhi) ^ (fr & 7)) << 4);
          kf[kk][sn] = *(const bf16x8*)((const char*)&Ks[0] + byte);
        }

      f32x4 sa[2][4];
#pragma unroll
      for (int mt = 0; mt < 2; mt++)
#pragma unroll
        for (int sn = 0; sn < 4; sn++) sa[mt][sn] = fz;
      __builtin_amdgcn_s_setprio(1);
#pragma unroll
      for (int kk = 0; kk < 2; kk++)
#pragma unroll
        for (int sn = 0; sn < 4; sn++)
#pragma unroll
          for (int mt = 0; mt < 2; mt++)
            sa[mt][sn] = __builtin_amdgcn_mfma_f32_16x16x32_bf16(kf[kk][sn], qfa[mt][kk], sa[mt][sn], 0, 0, 0);
      __builtin_amdgcn_s_setprio(0);

      float4 mv4[4];
#pragma unroll
      for (int sn = 0; sn < 4; sn++)
        mv4[sn] = *(const float4*)&mrow[sc + sn * 16 + fhi * 4];

#pragma unroll
      for (int mt = 0; mt < 2; mt++) {
        const int qrow = mt * 16 + fr;
#pragma unroll
        for (int sn = 0; sn < 4; sn++) {
          const float e0 = EXP2F(fmaf(sa[mt][sn][0], LOG2E, ((const float*)&mv4[sn])[0]));
          const float e1 = EXP2F(fmaf(sa[mt][sn][1], LOG2E, ((const float*)&mv4[sn])[1]));
          const float e2 = EXP2F(fmaf(sa[mt][sn][2], LOG2E, ((const float*)&mv4[sn])[2]));
          const float e3 = EXP2F(fmaf(sa[mt][sn][3], LOG2E, ((const float*)&mv4[sn])[3]));
          int byte = qrow * 128 + sn * 32 + fhi * 8;
          byte ^= (qrow & 7) << 4;
          uint2 pk;
          pk.x = pack_bf2(e0, e1);
          pk.y = pack_bf2(e2, e3);
          *(uint2*)((char*)Pw + byte) = pk;
        }
      }
      asm volatile("s_waitcnt lgkmcnt(0)" ::: "memory");

      bf16x8 vv[2][4];
#pragma unroll
      for (int kk = 0; kk < 2; kk++)
#pragma unroll
        for (int dn = 0; dn < 4; dn++) {
          const int row = dn * 16 + fr;
          const int byte = row * 1024 +
              (((sc >> 3) + ((((kk << 2) | fhi) ^ (fr & 7)))) << 4);
          vv[kk][dn] = *(const bf16x8*)((const char*)&Vs[0] + byte);
        }

      __builtin_amdgcn_s_setprio(1);
#pragma unroll
      for (int kk = 0; kk < 2; kk++)
#pragma unroll
        for (int mt = 0; mt < 2; mt++) {
          int byte = (mt * 16 + fr) * 128 + kk * 64 + fhi * 16;
          byte ^= (fr & 7) << 4;
          const bf16x8 pa = *(const bf16x8*)((char*)Pw + byte);
#pragma unroll
          for (int dn = 0; dn < 4; dn++)
            oa[mt][dn] = __builtin_amdgcn_mfma_f32_16x16x32_bf16(pa, vv[kk][dn], oa[mt][dn], 0, 0, 0);
          lacc_a[mt] = __builtin_amdgcn_mfma_f32_16x16x32_bf16(pa, onesf, lacc_a[mt], 0, 0, 0);
        }
      __builtin_amdgcn_s_setprio(0);

      f32x4 sb[2][4];
#pragma unroll
      for (int mt = 0; mt < 2; mt++)
#pragma unroll
        for (int sn = 0; sn < 4; sn++) sb[mt][sn] = fz;
      __builtin_amdgcn_s_setprio(1);
#pragma unroll
      for (int kk = 0; kk < 2; kk++)
#pragma unroll
        for (int sn = 0; sn < 4; sn++)
#pragma unroll
          for (int mt = 0; mt < 2; mt++)
            sb[mt][sn] = __builtin_amdgcn_mfma_f32_16x16x32_bf16(kf[kk][sn], qfb[mt][kk], sb[mt][sn], 0, 0, 0);
      __builtin_amdgcn_s_setprio(0);

#pragma unroll
      for (int mt = 0; mt < 2; mt++) {
        const int qrow = mt * 16 + fr;
#pragma unroll
        for (int sn = 0; sn < 4; sn++) {
          const float e0 = EXP2F(fmaf(sb[mt][sn][0], LOG2E, ((const float*)&mv4[sn])[0]));
          const float e1 = EXP2F(fmaf(sb[mt][sn][1], LOG2E, ((const float*)&mv4[sn])[1]));
          const float e2 = EXP2F(fmaf(sb[mt][sn][2], LOG2E, ((const float*)&mv4[sn])[2]));
          const float e3 = EXP2F(fmaf(sb[mt][sn][3], LOG2E, ((const float*)&mv4[sn])[3]));
          int byte = qrow * 128 + sn * 32 + fhi * 8;
          byte ^= (qrow & 7) << 4;
          uint2 pk;
          pk.x = pack_bf2(e0, e1);
          pk.y = pack_bf2(e2, e3);
          *(uint2*)((char*)Pw + byte) = pk;
        }
      }
      asm volatile("s_waitcnt lgkmcnt(0)" ::: "memory");

      __builtin_amdgcn_s_setprio(1);
#pragma unroll
      for (int kk = 0; kk < 2; kk++)
#pragma unroll
        for (int mt = 0; mt < 2; mt++) {
          int byte = (mt * 16 + fr) * 128 + kk * 64 + fhi * 16;
          byte ^= (fr & 7) << 4;
          const bf16x8 pa = *(const bf16x8*)((char*)Pw + byte);
#pragma unroll
          for (int dn = 0; dn < 4; dn++)
            ob[mt][dn] = __builtin_amdgcn_mfma_f32_16x16x32_bf16(pa, vv[kk][dn], ob[mt][dn], 0, 0, 0);
          lacc_b[mt] = __builtin_amdgcn_mfma_f32_16x16x32_bf16(pa, onesf, lacc_b[mt], 0, 0, 0);
        }
      __builtin_amdgcn_s_setprio(0);
    }

#pragma unroll
    for (int mt = 0; mt < 2; mt++) {
      float loa[4], lob[4];
#pragma unroll
      for (int r = 0; r < 4; r++) {
        loa[r] = RCPF(lacc_a[mt][r]);
        lob[r] = RCPF(lacc_b[mt][r]);
      }
#pragma unroll
      for (int dn = 0; dn < 4; dn++)
#pragma unroll
        for (int r = 0; r < 4; r++) {
          const int rowa = rowbase_a + mt * 16 + fhi * 4 + r;
          O[(size_t)rowa * DIMC + h * 64 + dn * 16 + fr] = f2bf(oa[mt][dn][r] * loa[r]);
          const int rowb = rowbase_b + mt * 16 + fhi * 4 + r;
          O[(size_t)rowb * DIMC + h * 64 + dn * 16 + fr] = f2bf(ob[mt][dn][r] * lob[r]);
        }
    }
  }
}

// ---------------- launch ----------------

extern "C" void kernel_launch(void* const* d_in, const int* in_sizes, int n_in,
                              void* d_out, int out_size, void* d_ws, size_t ws_size,
                              hipStream_t stream) {
  const float* x      = (const float*)d_in[0];
  const float* ctx    = (const float*)d_in[1];
  const int*   cmask  = (const int*)d_in[2];
  const float* q_w    = (const float*)d_in[3];
  const float* q_b    = (const float*)d_in[4];
  const float* kv_w   = (const float*)d_in[5];
  const float* kv_b   = (const float*)d_in[6];
  const float* proj_w = (const float*)d_in[7];
  const float* proj_b = (const float*)d_in[8];
  float* out = (float*)d_out;

  char* ws = (char*)d_ws;
  size_t off = 0;
  auto alloc = [&](size_t bytes) {
    void* p = ws + off;
    off += (bytes + 255) & ~(size_t)255;
    return p;
  };
  u16* x_bf   = (u16*)alloc((size_t)16384 * 1024 * 2);
  u16* ctx_bf = (u16*)alloc((size_t)2048 * 1024 * 2);
  u16* qwT    = (u16*)alloc((size_t)1024 * 1024 * 2);
  u16* kvwT   = (u16*)alloc((size_t)2048 * 1024 * 2);
  u16* pwT    = (u16*)alloc((size_t)1024 * 1024 * 2);
  u16* Qb     = (u16*)alloc((size_t)16384 * 1024 * 2);
  u16* Kbuf   = (u16*)alloc((size_t)64 * 512 * 64 * 2);
  u16* VTbuf  = (u16*)alloc((size_t)64 * 64 * 512 * 2);
  u16* Ob     = (u16*)alloc((size_t)16384 * 1024 * 2);
  float* maskf = (float*)alloc((size_t)NB * NS * 4);

  // all preprocessing in one launch
  prep_kernel<<<6664, 256, 0, stream>>>(x, ctx, cmask, q_w, kv_w, proj_w,
                                        x_bf, ctx_bf, qwT, kvwT, pwT, maskf);

  // Q-proj (blocks 0..255, BK=32 pipelined) + KV-proj (blocks 256..511)
  gemm_qkv<<<512, 512, 0, stream>>>(x_bf, qwT, q_b, Qb,
                                    ctx_bf, kvwT, kv_b, Kbuf, VTbuf);
  // attention (dual-chain, shared K/V register fragments)
  attn_kernel<<<256, 512, 0, stream>>>(Qb, Kbuf, VTbuf, maskf, Ob);
  // out = O @ proj_w + proj_b (f32), BK=32 pipelined
  gemm_out<<<256, 512, 0, stream>>>(Ob, pwT, proj_b, out);
}